// Round 19
// baseline (1896.854 us; speedup 1.0000x reference)
//
#include <hip/hip_runtime.h>
#include <hip/hip_bf16.h>

// ---------------- problem constants ----------------
// B=32, S=512, D=512, K=2048; N = B*S = 16384. d_out is FLOAT32.
// r19 = r18 with conv restructured: A-tile (136-row window of packed xp)
// staged ONCE per 32-K chunk and reused across all taps (tap-independent
// zero mask at batch edges). Accumulation reorder = proven-safe f32 class.
// All else r18-verbatim.

#define GF_BIAS 1
#define GF_RELU 2
#define GF_ADD  4
#define GF_POS  8
#define GF_ACC  16

typedef _Float16 f16x8 __attribute__((ext_vector_type(8)));
typedef float    f32x4 __attribute__((ext_vector_type(4)));

static constexpr long long O_QUANT = 0LL;
static constexpr long long O_LOSS  = 8388608LL;
static constexpr long long O_IDX   = 8388609LL;
static constexpr long long O_HASH  = 8404993LL;
static constexpr long long O_REG   = 9453569LL;
static constexpr long long O_END   = 43008001LL;

static constexpr long long W_XP    = 0LL;
static constexpr long long W_CT    = 8388608LL;
static constexpr long long W_PROJ  = 16777216LL;
static constexpr long long W_VW    = 25165824LL;
static constexpr long long W_HREG  = 33554432LL;
static constexpr long long W_T     = 34078720LL;
static constexpr long long W_IDX   = 34209792LL;
static constexpr long long W_ASUM  = 34226176LL;
static constexpr long long W_CBB   = 34258944LL;
static constexpr long long W_LPART = 34263040LL;
static constexpr long long W_PBV   = 34271232LL;
static constexpr long long W_PBI   = 34336768LL;
static constexpr long long W_END   = 34402304LL;

__device__ __forceinline__ unsigned int pack_hl(float x)
{
    _Float16 h = (_Float16)x;
    float hf = (float)h;
    _Float16 l = (_Float16)(x - hf);
    unsigned short hb = __builtin_bit_cast(unsigned short, h);
    unsigned short lb = __builtin_bit_cast(unsigned short, l);
    return (unsigned int)hb | ((unsigned int)lb << 16);
}

__device__ __forceinline__ void split2(float x, unsigned short& h, unsigned short& l)
{
    _Float16 hf = (_Float16)x;
    _Float16 lf = (_Float16)(x - (float)hf);
    h = __builtin_bit_cast(unsigned short, hf);
    l = __builtin_bit_cast(unsigned short, lf);
}

// ---------------- split xp in place ------------------------------------------
__global__ __launch_bounds__(256)
void split_xp_r19(float* __restrict__ xp)
{
    long long i = (long long)blockIdx.x*256 + threadIdx.x;
    float x = xp[i];
    ((unsigned int*)xp)[i] = pack_hl(x);
}

template<int KT>
__global__ __launch_bounds__(256)
void conv_w_tr_r19(const float* __restrict__ w, unsigned int* __restrict__ wt)
{
    long long i = (long long)blockIdx.x*256 + threadIdx.x;
    int o  = (int)(i / (512*KT));
    int rem= (int)(i % (512*KT));
    int t  = rem >> 9;
    int ii = rem & 511;
    wt[i] = pack_hl(w[(long long)o*512*KT + (long long)ii*KT + t]);
}

// ---------------- conv via f16x3 MFMA: A staged once per K-chunk -------------
template<int KT>
__global__ __launch_bounds__(256)
void conv_mfma_r19(const unsigned int* __restrict__ xphl,
                   const unsigned int* __restrict__ wthl,
                   const float* __restrict__ bias, float* __restrict__ outp)
{
    constexpr int PAD = KT / 2;
    __shared__ unsigned short Ah[136][40];
    __shared__ unsigned short Al[136][40];
    __shared__ unsigned short Bh[128][40];
    __shared__ unsigned short Bl[128][40];
    const int tid  = threadIdx.x;
    const int lane = tid & 63;
    const int wave = tid >> 6;
    const int wm = (wave >> 1) * 64, wn = (wave & 1) * 64;
    const int bm = blockIdx.x * 128, bn = blockIdx.y * 128;
    const int l15 = lane & 15;
    const int lk8 = (lane >> 4) * 8;
    const int rbase = (lane >> 4) * 4;
    const int sb = bm & 511;    // block's offset within its batch

    f32x4 acc[4][4];
    #pragma unroll
    for (int i=0;i<4;i++)
        #pragma unroll
        for (int j=0;j<4;j++)
            acc[i][j] = (f32x4){0.f,0.f,0.f,0.f};

    for (int i0 = 0; i0 < 512; i0 += 32) {
        __syncthreads();   // prior iteration's A/B readers done
        // stage A window: 136 rows (xp rows bm-4 .. bm+131), tap-independent
        // zero mask: row valid iff sb + row - 4 in [0, 512)
        for (int sl = tid; sl < 136*8; sl += 256) {
            const int row = sl >> 3, c = sl & 7;
            const int srow = sb + row - 4;
            uint4 v = make_uint4(0u,0u,0u,0u);
            if (srow >= 0 && srow < 512)
                v = *(const uint4*)(xphl + (long long)(bm + row - 4)*512 + i0 + c*4);
            Ah[row][c*4+0] = (unsigned short)(v.x & 0xffff);
            Ah[row][c*4+1] = (unsigned short)(v.y & 0xffff);
            Ah[row][c*4+2] = (unsigned short)(v.z & 0xffff);
            Ah[row][c*4+3] = (unsigned short)(v.w & 0xffff);
            Al[row][c*4+0] = (unsigned short)(v.x >> 16);
            Al[row][c*4+1] = (unsigned short)(v.y >> 16);
            Al[row][c*4+2] = (unsigned short)(v.z >> 16);
            Al[row][c*4+3] = (unsigned short)(v.w >> 16);
        }
        for (int t = 0; t < KT; ++t) {
            // stage B for this tap (barrier below also covers A on t==0)
            for (int sl = tid; sl < 128*8; sl += 256) {
                const int row = sl >> 3, c = sl & 7;
                uint4 v = *(const uint4*)(wthl + (long long)(bn + row)*(KT*512) + t*512 + i0 + c*4);
                Bh[row][c*4+0] = (unsigned short)(v.x & 0xffff);
                Bh[row][c*4+1] = (unsigned short)(v.y & 0xffff);
                Bh[row][c*4+2] = (unsigned short)(v.z & 0xffff);
                Bh[row][c*4+3] = (unsigned short)(v.w & 0xffff);
                Bl[row][c*4+0] = (unsigned short)(v.x >> 16);
                Bl[row][c*4+1] = (unsigned short)(v.y >> 16);
                Bl[row][c*4+2] = (unsigned short)(v.z >> 16);
                Bl[row][c*4+3] = (unsigned short)(v.w >> 16);
            }
            __syncthreads();
            const int tofs = t - PAD + 4;
            f16x8 ah[4], al[4], bh[4], bl[4];
            #pragma unroll
            for (int mi = 0; mi < 4; ++mi) {
                ah[mi] = *(const f16x8*)(&Ah[wm + mi*16 + l15 + tofs][lk8]);
                al[mi] = *(const f16x8*)(&Al[wm + mi*16 + l15 + tofs][lk8]);
            }
            #pragma unroll
            for (int nj = 0; nj < 4; ++nj) {
                bh[nj] = *(const f16x8*)(&Bh[wn + nj*16 + l15][lk8]);
                bl[nj] = *(const f16x8*)(&Bl[wn + nj*16 + l15][lk8]);
            }
            #pragma unroll
            for (int mi = 0; mi < 4; ++mi)
                #pragma unroll
                for (int nj = 0; nj < 4; ++nj) {
                    acc[mi][nj] = __builtin_amdgcn_mfma_f32_16x16x32_f16(ah[mi], bh[nj], acc[mi][nj], 0, 0, 0);
                    acc[mi][nj] = __builtin_amdgcn_mfma_f32_16x16x32_f16(ah[mi], bl[nj], acc[mi][nj], 0, 0, 0);
                    acc[mi][nj] = __builtin_amdgcn_mfma_f32_16x16x32_f16(al[mi], bh[nj], acc[mi][nj], 0, 0, 0);
                }
            if (t + 1 < KT) __syncthreads();   // B overwrite safety (A stable)
        }
    }
    #pragma unroll
    for (int mi = 0; mi < 4; ++mi) {
        #pragma unroll
        for (int nj = 0; nj < 4; ++nj) {
            const int col = bn + wn + nj*16 + l15;
            const float bcol = bias[col];
            #pragma unroll
            for (int r = 0; r < 4; ++r) {
                const int row = bm + wm + mi*16 + rbase + r;
                float v = acc[mi][nj][r] + bcol;
                outp[(long long)row*512 + col] = fmaxf(v, 0.0f);
            }
        }
    }
}

// ---------------- generic GEMM via f16x3 MFMA (r18 verbatim) -----------------
template<int FLAGS>
__global__ __launch_bounds__(256)
void gemm_mfma_r19(const float* __restrict__ A, const float* __restrict__ Bm,
                   const float* __restrict__ bias, const float* __restrict__ pos,
                   const float* __restrict__ addsrc, float* __restrict__ C,
                   int Kdim, int lda, int ldb, int ldc)
{
    __shared__ unsigned short Ah[128][56];
    __shared__ unsigned short Al[128][56];
    __shared__ unsigned short Bh[128][56];
    __shared__ unsigned short Bl[128][56];
    const int tid  = threadIdx.x;
    const int lane = tid & 63;
    const int wave = tid >> 6;
    const int wm = (wave >> 1) * 64, wn = (wave & 1) * 64;
    const int bm = blockIdx.x * 128, bn = blockIdx.y * 128;
    const int l15 = lane & 15;
    const int lk8 = (lane >> 4) * 8;
    const int rbase = (lane >> 4) * 4;
    const int cg   = tid & 7;
    const int rw0  = tid >> 3;

    f32x4 acc[4][4];
    #pragma unroll
    for (int i=0;i<4;i++)
        #pragma unroll
        for (int j=0;j<4;j++)
            acc[i][j] = (f32x4){0.f,0.f,0.f,0.f};

    for (int k0 = 0; k0 < Kdim; k0 += 32) {
        float4 fa[4], fb[4];
        #pragma unroll
        for (int q = 0; q < 4; ++q) {
            const int row = rw0 + q*32;
            fa[q] = *(const float4*)(A  + (long long)(bm + row)*lda + k0 + cg*4);
            fb[q] = *(const float4*)(Bm + (long long)(bn + row)*ldb + k0 + cg*4);
        }
        __syncthreads();
        #pragma unroll
        for (int q = 0; q < 4; ++q) {
            const int row = rw0 + q*32;
            ushort4 ah_, al_, bh_, bl_;
            split2(fa[q].x, ah_.x, al_.x);
            split2(fa[q].y, ah_.y, al_.y);
            split2(fa[q].z, ah_.z, al_.z);
            split2(fa[q].w, ah_.w, al_.w);
            split2(fb[q].x, bh_.x, bl_.x);
            split2(fb[q].y, bh_.y, bl_.y);
            split2(fb[q].z, bh_.z, bl_.z);
            split2(fb[q].w, bh_.w, bl_.w);
            *(ushort4*)(&Ah[row][cg*4]) = ah_;
            *(ushort4*)(&Al[row][cg*4]) = al_;
            *(ushort4*)(&Bh[row][cg*4]) = bh_;
            *(ushort4*)(&Bl[row][cg*4]) = bl_;
        }
        __syncthreads();
        f16x8 ah[4], al[4], bh[4], bl[4];
        #pragma unroll
        for (int mi = 0; mi < 4; ++mi) {
            ah[mi] = *(const f16x8*)(&Ah[wm + mi*16 + l15][lk8]);
            al[mi] = *(const f16x8*)(&Al[wm + mi*16 + l15][lk8]);
        }
        #pragma unroll
        for (int nj = 0; nj < 4; ++nj) {
            bh[nj] = *(const f16x8*)(&Bh[wn + nj*16 + l15][lk8]);
            bl[nj] = *(const f16x8*)(&Bl[wn + nj*16 + l15][lk8]);
        }
        #pragma unroll
        for (int mi = 0; mi < 4; ++mi)
            #pragma unroll
            for (int nj = 0; nj < 4; ++nj) {
                acc[mi][nj] = __builtin_amdgcn_mfma_f32_16x16x32_f16(ah[mi], bh[nj], acc[mi][nj], 0, 0, 0);
                acc[mi][nj] = __builtin_amdgcn_mfma_f32_16x16x32_f16(ah[mi], bl[nj], acc[mi][nj], 0, 0, 0);
                acc[mi][nj] = __builtin_amdgcn_mfma_f32_16x16x32_f16(al[mi], bh[nj], acc[mi][nj], 0, 0, 0);
            }
    }
    #pragma unroll
    for (int mi = 0; mi < 4; ++mi) {
        #pragma unroll
        for (int nj = 0; nj < 4; ++nj) {
            const int col = bn + wn + nj*16 + l15;
            #pragma unroll
            for (int r = 0; r < 4; ++r) {
                const int row = bm + wm + mi*16 + rbase + r;
                float v = acc[mi][nj][r];
                if constexpr (FLAGS & GF_BIAS) v += bias[col];
                if constexpr (FLAGS & GF_POS)  v += pos[(long long)(row & 511)*512 + col];
                if constexpr (FLAGS & GF_ADD)  v += addsrc[(long long)row*ldc + col];
                if constexpr (FLAGS & GF_ACC)  v += C[(long long)row*ldc + col];
                if constexpr (FLAGS & GF_RELU) v = fmaxf(v, 0.0f);
                C[(long long)row*ldc + col] = v;
            }
        }
    }
}

// ---------------- fused attention via f16x3 MFMA (r18 verbatim) --------------
__global__ __launch_bounds__(256)
void attn_mfma_r19(const float* __restrict__ Qbuf, const float* __restrict__ Kbuf,
                   const float* __restrict__ Vbuf, float* __restrict__ att)
{
    __shared__ unsigned short Qh[64][68];
    __shared__ unsigned short Ql[64][68];
    __shared__ unsigned short Kh[64][68];
    __shared__ unsigned short Kl[64][68];
    __shared__ unsigned short Vh[64][68];
    __shared__ unsigned short Vl[64][68];
    const int tid  = threadIdx.x;
    const int lane = tid & 63;
    const int wave = tid >> 6;
    const int l15  = lane & 15;
    const int lq   = lane >> 4;
    const int lq8  = lq * 8;
    const int bid = blockIdx.x;
    const int qt = bid & 7, h = (bid >> 3) & 7, b = bid >> 6;
    const int row0 = b*512 + qt*64;

    #pragma unroll
    for (int u = 0; u < 16; ++u) {
        int e = u*256 + tid;
        int r = e >> 6, c = e & 63;
        float q = Qbuf[(long long)(row0 + r)*512 + h*64 + c] * 0.125f;
        unsigned short hs, ls;
        split2(q, hs, ls);
        Qh[r][c] = hs; Ql[r][c] = ls;
    }

    float m[4], l[4];
    f32x4 accO[4];
    #pragma unroll
    for (int r=0;r<4;r++){ m[r] = -1e30f; l[r] = 0.f; }
    #pragma unroll
    for (int j=0;j<4;j++) accO[j] = (f32x4){0.f,0.f,0.f,0.f};

    for (int kv = 0; kv < 512; kv += 64) {
        __syncthreads();
        #pragma unroll
        for (int u = 0; u < 16; ++u) {
            int e = u*256 + tid;
            int r = e >> 6, c = e & 63;
            float kvf = Kbuf[(long long)(b*512 + kv + r)*512 + h*64 + c];
            float vvf = Vbuf[(long long)(b*512 + kv + r)*512 + h*64 + c];
            unsigned short hs, ls;
            split2(kvf, hs, ls);
            Kh[r][c] = hs; Kl[r][c] = ls;
            split2(vvf, hs, ls);
            Vh[c][r] = hs; Vl[c][r] = ls;
        }
        __syncthreads();
        f32x4 accS[4];
        #pragma unroll
        for (int j=0;j<4;j++) accS[j] = (f32x4){0.f,0.f,0.f,0.f};
        #pragma unroll
        for (int ks = 0; ks < 2; ++ks) {
            f16x8 qh = *(const f16x8*)(&Qh[wave*16 + l15][ks*32 + lq8]);
            f16x8 ql = *(const f16x8*)(&Ql[wave*16 + l15][ks*32 + lq8]);
            #pragma unroll
            for (int nj = 0; nj < 4; ++nj) {
                f16x8 kh = *(const f16x8*)(&Kh[nj*16 + l15][ks*32 + lq8]);
                f16x8 kl = *(const f16x8*)(&Kl[nj*16 + l15][ks*32 + lq8]);
                accS[nj] = __builtin_amdgcn_mfma_f32_16x16x32_f16(qh, kh, accS[nj], 0, 0, 0);
                accS[nj] = __builtin_amdgcn_mfma_f32_16x16x32_f16(qh, kl, accS[nj], 0, 0, 0);
                accS[nj] = __builtin_amdgcn_mfma_f32_16x16x32_f16(ql, kh, accS[nj], 0, 0, 0);
            }
        }
        #pragma unroll
        for (int r = 0; r < 4; ++r) {
            float tm = fmaxf(fmaxf(accS[0][r], accS[1][r]), fmaxf(accS[2][r], accS[3][r]));
            #pragma unroll
            for (int msk = 1; msk < 16; msk <<= 1) tm = fmaxf(tm, __shfl_xor(tm, msk, 64));
            float mn = fmaxf(m[r], tm);
            float scale = expf(m[r] - mn);
            float rs = 0.f;
            #pragma unroll
            for (int nj = 0; nj < 4; ++nj) {
                float p = expf(accS[nj][r] - mn);
                accS[nj][r] = p;
                rs += p;
            }
            #pragma unroll
            for (int msk = 1; msk < 16; msk <<= 1) rs += __shfl_xor(rs, msk, 64);
            l[r] = l[r]*scale + rs;
            m[r] = mn;
            #pragma unroll
            for (int nj = 0; nj < 4; ++nj) accO[nj][r] *= scale;
        }
        __syncthreads();
        #pragma unroll
        for (int r = 0; r < 4; ++r)
            #pragma unroll
            for (int nj = 0; nj < 4; ++nj) {
                unsigned short hs, ls;
                split2(accS[nj][r], hs, ls);
                Kh[wave*16 + lq*4 + r][nj*16 + l15] = hs;
                Kl[wave*16 + lq*4 + r][nj*16 + l15] = ls;
            }
        __syncthreads();
        #pragma unroll
        for (int ks = 0; ks < 2; ++ks) {
            f16x8 ph = *(const f16x8*)(&Kh[wave*16 + l15][ks*32 + lq8]);
            f16x8 pl = *(const f16x8*)(&Kl[wave*16 + l15][ks*32 + lq8]);
            #pragma unroll
            for (int nj = 0; nj < 4; ++nj) {
                f16x8 vh = *(const f16x8*)(&Vh[nj*16 + l15][ks*32 + lq8]);
                f16x8 vl = *(const f16x8*)(&Vl[nj*16 + l15][ks*32 + lq8]);
                accO[nj] = __builtin_amdgcn_mfma_f32_16x16x32_f16(ph, vh, accO[nj], 0, 0, 0);
                accO[nj] = __builtin_amdgcn_mfma_f32_16x16x32_f16(ph, vl, accO[nj], 0, 0, 0);
                accO[nj] = __builtin_amdgcn_mfma_f32_16x16x32_f16(pl, vh, accO[nj], 0, 0, 0);
            }
        }
    }
    #pragma unroll
    for (int nj = 0; nj < 4; ++nj)
        #pragma unroll
        for (int r = 0; r < 4; ++r) {
            const int row = row0 + wave*16 + lq*4 + r;
            att[(long long)row*512 + h*64 + nj*16 + l15] = accO[nj][r] / l[r];
        }
}

// ---------------- row sum of squares (f64) -----------------------------------
__global__ __launch_bounds__(256)
void row_sumsq_r19(const float* __restrict__ X, double* __restrict__ outp)
{
    const int row  = blockIdx.x*4 + (threadIdx.x >> 6);
    const int lane = threadIdx.x & 63;
    double s = 0.0;
    #pragma unroll
    for (int u = 0; u < 8; ++u) {
        float v = X[(long long)row*512 + lane + u*64];
        s += (double)v * (double)v;
    }
    #pragma unroll
    for (int msk = 32; msk; msk >>= 1) s += __shfl_xor(s, msk, 64);
    if (lane == 0) outp[row] = s;
}

// ---------------- VQ argmin via f16x3 MFMA (r18 verbatim) --------------------
__global__ __launch_bounds__(256)
void vq_argmin_mfma_r19(const float* __restrict__ enc, const float* __restrict__ cb,
                        const double* __restrict__ Asum, const double* __restrict__ cbB,
                        float* __restrict__ pbv, int* __restrict__ pbi)
{
    __shared__ unsigned int smem[14336];
    unsigned short* AhP = (unsigned short*)smem;
    unsigned short* AlP = AhP + 128*56;
    unsigned short* BhP = AlP + 128*56;
    unsigned short* BlP = BhP + 128*56;
    float* bvsP = (float*)smem;
    int*   bisP = (int*)(smem + 4096);

    const int tid  = threadIdx.x;
    const int lane = tid & 63;
    const int wave = tid >> 6;
    const int wm = (wave >> 1) * 64, wn = (wave & 1) * 64;
    const int bm = blockIdx.x * 128;
    const int l15 = lane & 15;
    const int lk8 = (lane >> 4) * 8;
    const int rbase = (lane >> 4) * 4;
    const int cg   = tid & 7;
    const int rw0  = tid >> 3;

    float bestv[16]; int besti[16];
    #pragma unroll
    for (int g = 0; g < 16; ++g) { bestv[g] = 3.0e38f; besti[g] = 2048; }

    for (int nb = 0; nb < 4; ++nb) {
        const int ct0 = blockIdx.y * 512 + nb * 128;
        f32x4 acc[4][4];
        #pragma unroll
        for (int i=0;i<4;i++)
            #pragma unroll
            for (int j=0;j<4;j++)
                acc[i][j] = (f32x4){0.f,0.f,0.f,0.f};

        for (int k0 = 0; k0 < 512; k0 += 32) {
            float4 fa[4], fb[4];
            #pragma unroll
            for (int q = 0; q < 4; ++q) {
                const int row = rw0 + q*32;
                fa[q] = *(const float4*)(enc + (long long)(bm + row)*512 + k0 + cg*4);
                fb[q] = *(const float4*)(cb  + (long long)(ct0 + row)*512 + k0 + cg*4);
            }
            __syncthreads();
            #pragma unroll
            for (int q = 0; q < 4; ++q) {
                const int row = rw0 + q*32;
                ushort4 ah_, al_, bh_, bl_;
                split2(fa[q].x, ah_.x, al_.x);
                split2(fa[q].y, ah_.y, al_.y);
                split2(fa[q].z, ah_.z, al_.z);
                split2(fa[q].w, ah_.w, al_.w);
                split2(fb[q].x * 2048.0f, bh_.x, bl_.x);
                split2(fb[q].y * 2048.0f, bh_.y, bl_.y);
                split2(fb[q].z * 2048.0f, bh_.z, bl_.z);
                split2(fb[q].w * 2048.0f, bh_.w, bl_.w);
                *(ushort4*)(&AhP[row*56 + cg*4]) = ah_;
                *(ushort4*)(&AlP[row*56 + cg*4]) = al_;
                *(ushort4*)(&BhP[row*56 + cg*4]) = bh_;
                *(ushort4*)(&BlP[row*56 + cg*4]) = bl_;
            }
            __syncthreads();
            f16x8 ah[4], al[4], bh[4], bl[4];
            #pragma unroll
            for (int mi = 0; mi < 4; ++mi) {
                ah[mi] = *(const f16x8*)(&AhP[(wm + mi*16 + l15)*56 + lk8]);
                al[mi] = *(const f16x8*)(&AlP[(wm + mi*16 + l15)*56 + lk8]);
            }
            #pragma unroll
            for (int nj = 0; nj < 4; ++nj) {
                bh[nj] = *(const f16x8*)(&BhP[(wn + nj*16 + l15)*56 + lk8]);
                bl[nj] = *(const f16x8*)(&BlP[(wn + nj*16 + l15)*56 + lk8]);
            }
            #pragma unroll
            for (int mi = 0; mi < 4; ++mi)
                #pragma unroll
                for (int nj = 0; nj < 4; ++nj) {
                    acc[mi][nj] = __builtin_amdgcn_mfma_f32_16x16x32_f16(ah[mi], bh[nj], acc[mi][nj], 0, 0, 0);
                    acc[mi][nj] = __builtin_amdgcn_mfma_f32_16x16x32_f16(ah[mi], bl[nj], acc[mi][nj], 0, 0, 0);
                    acc[mi][nj] = __builtin_amdgcn_mfma_f32_16x16x32_f16(al[mi], bh[nj], acc[mi][nj], 0, 0, 0);
                }
        }
        #pragma unroll
        for (int mi = 0; mi < 4; ++mi) {
            #pragma unroll
            for (int r = 0; r < 4; ++r) {
                const int g = mi*4 + r;
                const float anf = (float)Asum[bm + wm + mi*16 + rbase + r];
                #pragma unroll
                for (int nj = 0; nj < 4; ++nj) {
                    const int col = ct0 + wn + nj*16 + l15;
                    const float bf = (float)cbB[col];
                    const float s1 = anf + bf;
                    const float dot = acc[mi][nj][r] * (1.0f/2048.0f);
                    const float df  = 2.0f * dot;
                    const float qd  = s1 - df;
                    if (qd < bestv[g] || (qd == bestv[g] && col < besti[g])) {
                        bestv[g] = qd; besti[g] = col;
                    }
                }
            }
        }
    }
    __syncthreads();
    #pragma unroll
    for (int mi = 0; mi < 4; ++mi)
        #pragma unroll
        for (int r = 0; r < 4; ++r) {
            const int row  = wm + mi*16 + rbase + r;
            const int slot = (wave & 1)*16 + l15;
            bvsP[row*32 + slot] = bestv[mi*4 + r];
            bisP[row*32 + slot] = besti[mi*4 + r];
        }
    __syncthreads();
    if (tid < 128) {
        float bv = bvsP[tid*32]; int bi = bisP[tid*32];
        #pragma unroll
        for (int s = 1; s < 32; ++s) {
            float v = bvsP[tid*32 + s]; int ii = bisP[tid*32 + s];
            if (v < bv || (v == bv && ii < bi)) { bv = v; bi = ii; }
        }
        pbv[(long long)blockIdx.y*16384 + bm + tid] = bv;
        pbi[(long long)blockIdx.y*16384 + bm + tid] = bi;
    }
}

__global__ __launch_bounds__(256)
void vq_reduce_r19(const float* __restrict__ pbv, const int* __restrict__ pbi,
                   int* __restrict__ idxout)
{
    int n = blockIdx.x*256 + threadIdx.x;
    if (n >= 16384) return;
    float bv = pbv[n]; int bi = pbi[n];
    #pragma unroll
    for (int q = 1; q < 4; ++q) {
        float v = pbv[q*16384 + n]; int ii = pbi[q*16384 + n];
        if (v < bv || (v == bv && ii < bi)) { bv = v; bi = ii; }
    }
    idxout[n] = bi & 2047;
}

// ---------------- vq loss ----------------------------------------------------
__global__ __launch_bounds__(256)
void vq_loss_partial_r19(const float* __restrict__ enc, const float* __restrict__ cb,
                         const int* __restrict__ idxp, double* __restrict__ part)
{
    __shared__ double red[4];
    const int row  = blockIdx.x*4 + (threadIdx.x >> 6);
    const int lane = threadIdx.x & 63;
    const int ci = idxp[row] & 2047;
    double s = 0.0;
    #pragma unroll
    for (int u = 0; u < 8; ++u) {
        int d = lane + u*64;
        double dv = (double)cb[(long long)ci*512 + d] - (double)enc[(long long)row*512 + d];
        s += dv * dv;
    }
    #pragma unroll
    for (int msk = 32; msk; msk >>= 1) s += __shfl_xor(s, msk, 64);
    if (lane == 0) red[threadIdx.x >> 6] = s;
    __syncthreads();
    if (threadIdx.x == 0)
        part[blockIdx.x] = red[0] + red[1] + red[2] + red[3];
}

// ---------------- regime f32 GEMM (small) ------------------------------------
template<int FLAGS>
__global__ __launch_bounds__(256)
void gemm_bt_r19(const float* __restrict__ A, const float* __restrict__ Bm,
                 const float* __restrict__ bias, const float* __restrict__ pos,
                 const float* __restrict__ addsrc, float* __restrict__ C,
                 int Kdim, int lda, int ldb, int ldc)
{
    __shared__ float As[16][132];
    __shared__ float Bs[16][132];
    const int tid = threadIdx.x;
    const int tx = tid & 15, ty = tid >> 4;
    const int bm = blockIdx.x * 128, bn = blockIdx.y * 128;
    const int r0 = tid >> 2;
    const int kg = (tid & 3) << 2;
    const float* Arow0 = A  + (long long)(bm + r0) * lda + kg;
    const float* Arow1 = A  + (long long)(bm + r0 + 64) * lda + kg;
    const float* Brow0 = Bm + (long long)(bn + r0) * ldb + kg;
    const float* Brow1 = Bm + (long long)(bn + r0 + 64) * ldb + kg;

    float acc[8][8] = {};
    for (int k0 = 0; k0 < Kdim; k0 += 16) {
        float4 a0 = *(const float4*)(Arow0 + k0);
        float4 a1 = *(const float4*)(Arow1 + k0);
        float4 b0 = *(const float4*)(Brow0 + k0);
        float4 b1 = *(const float4*)(Brow1 + k0);
        __syncthreads();
        As[kg+0][r0]=a0.x; As[kg+1][r0]=a0.y; As[kg+2][r0]=a0.z; As[kg+3][r0]=a0.w;
        As[kg+0][r0+64]=a1.x; As[kg+1][r0+64]=a1.y; As[kg+2][r0+64]=a1.z; As[kg+3][r0+64]=a1.w;
        Bs[kg+0][r0]=b0.x; Bs[kg+1][r0]=b0.y; Bs[kg+2][r0]=b0.z; Bs[kg+3][r0]=b0.w;
        Bs[kg+0][r0+64]=b1.x; Bs[kg+1][r0+64]=b1.y; Bs[kg+2][r0+64]=b1.z; Bs[kg+3][r0+64]=b1.w;
        __syncthreads();
        #pragma unroll
        for (int kk = 0; kk < 16; ++kk) {
            float a[8], b[8];
            #pragma unroll
            for (int i=0;i<8;i++) a[i] = As[kk][ty*8+i];
            #pragma unroll
            for (int j=0;j<4;j++) b[j]   = Bs[kk][tx*4+j];
            #pragma unroll
            for (int j=0;j<4;j++) b[4+j] = Bs[kk][64+tx*4+j];
            #pragma unroll
            for (int i=0;i<8;i++)
                #pragma unroll
                for (int j=0;j<8;j++)
                    acc[i][j] = fmaf(a[i], b[j], acc[i][j]);
        }
    }
    #pragma unroll
    for (int i=0;i<8;i++){
        const int row = bm + ty*8 + i;
        #pragma unroll
        for (int j=0;j<8;j++){
            const int col = bn + ((j < 4) ? (tx*4 + j) : (64 + tx*4 + (j-4)));
            float v = acc[i][j];
            if constexpr (FLAGS & GF_BIAS) v += bias[col];
            if constexpr (FLAGS & GF_POS)  v += pos[(long long)(row & 511)*512 + col];
            if constexpr (FLAGS & GF_ADD)  v += addsrc[(long long)row*ldc + col];
            if constexpr (FLAGS & GF_ACC)  v += C[(long long)row*ldc + col];
            if constexpr (FLAGS & GF_RELU) v = fmaxf(v, 0.0f);
            C[(long long)row*ldc + col] = v;
        }
    }
}

// ---------------- regime softmax ---------------------------------------------
__global__ __launch_bounds__(256)
void softmax_rows_r19(float* __restrict__ R)
{
    const int row = blockIdx.x;
    const int tid = threadIdx.x;
    __shared__ float  redf[256];
    __shared__ double redd[256];
    float* p = R + (long long)row * 2048;
    float mx = -1e30f;
    for (int c = tid; c < 2048; c += 256) mx = fmaxf(mx, p[c]);
    redf[tid] = mx; __syncthreads();
    for (int s2 = 128; s2; s2 >>= 1) { if (tid < s2) redf[tid] = fmaxf(redf[tid], redf[tid+s2]); __syncthreads(); }
    mx = redf[0];
    double sum = 0.0;
    for (int c = tid; c < 2048; c += 256) { float e = expf(p[c] - mx); p[c] = e; sum += e; }
    redd[tid] = sum; __syncthreads();
    for (int s2 = 128; s2; s2 >>= 1) { if (tid < s2) redd[tid] += redd[tid+s2]; __syncthreads(); }
    double tot = redd[0];
    for (int c = tid; c < 2048; c += 256) p[c] = (float)((double)p[c] / tot);
}

// ---------------- hash table -------------------------------------------------
__global__ __launch_bounds__(256)
void hash_table_r19(const float* __restrict__ cb, const float* __restrict__ hw,
                    float* __restrict__ T)
{
    const int k = blockIdx.x*4 + (threadIdx.x >> 6);
    const int j = threadIdx.x & 63;
    double s = 0.0;
    for (int d = 0; d < 512; ++d)
        s += (double)cb[(long long)k*512 + d] * (double)hw[(long long)j*512 + d];
    T[(long long)k*64 + j] = (s > 0.0) ? 1.0f : 0.0f;
}

// ---------------- output writers ---------------------------------------------
__global__ void write_loss_r19(const double* __restrict__ part,
                               float* __restrict__ out)
{
    __shared__ double red[256];
    double s = 0.0;
    for (int i = threadIdx.x; i < 4096; i += 256) s += part[i];
    red[threadIdx.x] = s; __syncthreads();
    for (int s2 = 128; s2; s2 >>= 1) {
        if (threadIdx.x < s2) red[threadIdx.x] += red[threadIdx.x + s2];
        __syncthreads();
    }
    if (threadIdx.x == 0)
        out[O_LOSS] = (float)(1.25 * red[0] / 8388608.0);
}

__global__ __launch_bounds__(256)
void write_regime_r19(const float* __restrict__ R, const int* __restrict__ idxp,
                      float* __restrict__ out)
{
    long long i = (long long)blockIdx.x*256 + threadIdx.x;
    if (i >= 33554432LL) return;
    int n = (int)(i >> 11), c = (int)(i & 2047);
    int ci = idxp[n] & 2047;
    out[O_REG + i] = R[(long long)ci*2048 + c];
}

__global__ __launch_bounds__(256)
void write_hash_r19(const float* __restrict__ T, const int* __restrict__ idxp,
                    float* __restrict__ out)
{
    long long i = (long long)blockIdx.x*256 + threadIdx.x;
    if (i >= 1048576LL) return;
    int n = (int)(i >> 6), j = (int)(i & 63);
    int ci = idxp[n] & 2047;
    out[O_HASH + i] = T[(long long)ci*64 + j];
}

__global__ __launch_bounds__(256)
void write_idx_r19(const int* __restrict__ idxp, float* __restrict__ out)
{
    int n = blockIdx.x*256 + threadIdx.x;
    if (n >= 16384) return;
    out[O_IDX + n] = (float)(idxp[n] & 2047);
}

__global__ __launch_bounds__(256)
void write_quant_r19(const float* __restrict__ cb, const int* __restrict__ idxp,
                     float* __restrict__ out)
{
    long long i = (long long)blockIdx.x*256 + threadIdx.x;
    if (i >= 8388608LL) return;
    int n = (int)(i >> 9), d = (int)(i & 511);
    int ci = idxp[n] & 2047;
    out[O_QUANT + i] = cb[(long long)ci*512 + d];
}

// ---------------- launcher ----------------------------------------------------
extern "C" void kernel_launch(void* const* d_in, const int* in_sizes, int n_in,
                              void* d_out, int out_size, void* d_ws, size_t ws_size,
                              hipStream_t stream)
{
    (void)in_sizes; (void)n_in; (void)out_size;
    const float* market = (const float*)d_in[0];
    const float* W_in   = (const float*)d_in[1];
    const float* b_in   = (const float*)d_in[2];
    const float* pos    = (const float*)d_in[3];
    const float* c3w = (const float*)d_in[4];  const float* c3b = (const float*)d_in[5];
    const float* c5w = (const float*)d_in[6];  const float* c5b = (const float*)d_in[7];
    const float* c7w = (const float*)d_in[8];  const float* c7b = (const float*)d_in[9];
    const float* c9w = (const float*)d_in[10]; const float* c9b = (const float*)d_in[11];
    const float* msw = (const float*)d_in[12]; const float* msb = (const float*)d_in[13];
    const float* inw = (const float*)d_in[14]; const float* inb = (const float*)d_in[15];
    const float* aow = (const float*)d_in[16]; const float* aob = (const float*)d_in[17];
    const float* cb  = (const float*)d_in[18]; const float* hw  = (const float*)d_in[19];
    const float* r1w = (const float*)d_in[20]; const float* r1b = (const float*)d_in[21];
    const float* r2w = (const float*)d_in[22]; const float* r2b = (const float*)d_in[23];

    if (ws_size < (size_t)W_END * sizeof(float)) return;

    float* ws    = (float*)d_ws;
    float* xp    = ws + W_XP;
    float* convt = ws + W_CT;
    float* projp = ws + W_PROJ;
    unsigned int* wt3 = (unsigned int*)(ws + W_VW);
    unsigned int* wt5 = wt3 + 512*512*3;
    unsigned int* wt7 = wt5 + 512*512*5;
    unsigned int* wt9 = wt7 + 512*512*7;
    float* Vbufp = ws + W_VW;
    float* hregp = ws + W_HREG;
    float* Tp    = ws + W_T;
    int*    idxp  = (int*)(ws + W_IDX);
    double* asump = (double*)(ws + W_ASUM);
    double* cbbp  = (double*)(ws + W_CBB);
    double* lpart = (double*)(ws + W_LPART);
    float*  pbvp  = ws + W_PBV;
    int*    pbip  = (int*)(ws + W_PBI);

    float* out = (float*)d_out;

    float* Qbufp = xp;
    float* attp  = xp;
    float* Kbufp = convt;
    float* encp  = convt;
    float* Rp    = projp;

    const unsigned int* xpu = (const unsigned int*)xp;

    conv_w_tr_r19<3><<<3072, 256, 0, stream>>>(c3w, wt3);
    conv_w_tr_r19<5><<<5120, 256, 0, stream>>>(c5w, wt5);
    conv_w_tr_r19<7><<<7168, 256, 0, stream>>>(c7w, wt7);
    conv_w_tr_r19<9><<<9216, 256, 0, stream>>>(c9w, wt9);

    const dim3 gT(128, 4);

    gemm_mfma_r19<GF_BIAS|GF_POS><<<gT, 256, 0, stream>>>(market, W_in, b_in, pos, nullptr, xp, 512, 512, 512, 512);
    split_xp_r19<<<32768, 256, 0, stream>>>(xp);

    conv_mfma_r19<3><<<gT, 256, 0, stream>>>(xpu, wt3, c3b, convt);
    gemm_mfma_r19<GF_BIAS><<<gT, 256, 0, stream>>>(convt, msw + 0*512, msb, nullptr, nullptr, projp, 512, 512, 2048, 512);
    conv_mfma_r19<5><<<gT, 256, 0, stream>>>(xpu, wt5, c5b, convt);
    gemm_mfma_r19<GF_ACC><<<gT, 256, 0, stream>>>(convt, msw + 1*512, nullptr, nullptr, nullptr, projp, 512, 512, 2048, 512);
    conv_mfma_r19<7><<<gT, 256, 0, stream>>>(xpu, wt7, c7b, convt);
    gemm_mfma_r19<GF_ACC><<<gT, 256, 0, stream>>>(convt, msw + 2*512, nullptr, nullptr, nullptr, projp, 512, 512, 2048, 512);
    conv_mfma_r19<9><<<gT, 256, 0, stream>>>(xpu, wt9, c9b, convt);
    gemm_mfma_r19<GF_ACC><<<gT, 256, 0, stream>>>(convt, msw + 3*512, nullptr, nullptr, nullptr, projp, 512, 512, 2048, 512);

    gemm_mfma_r19<GF_BIAS><<<gT, 256, 0, stream>>>(projp, inw + 512*512,  inb + 512,  nullptr, nullptr, Kbufp, 512, 512, 512, 512);
    gemm_mfma_r19<GF_BIAS><<<gT, 256, 0, stream>>>(projp, inw + 1024*512, inb + 1024, nullptr, nullptr, Vbufp, 512, 512, 512, 512);
    gemm_mfma_r19<GF_BIAS><<<gT, 256, 0, stream>>>(projp, inw,            inb,        nullptr, nullptr, Qbufp, 512, 512, 512, 512);

    attn_mfma_r19<<<2048, 256, 0, stream>>>(Qbufp, Kbufp, Vbufp, attp);

    gemm_mfma_r19<GF_BIAS|GF_ADD><<<gT, 256, 0, stream>>>(attp, aow, aob, nullptr, projp, encp, 512, 512, 512, 512);

    // VQ
    row_sumsq_r19<<<4096, 256, 0, stream>>>(encp, asump);
    row_sumsq_r19<<<512,  256, 0, stream>>>(cb, cbbp);
    vq_argmin_mfma_r19<<<dim3(128, 4), 256, 0, stream>>>(encp, cb, asump, cbbp, pbvp, pbip);
    vq_reduce_r19<<<64, 256, 0, stream>>>(pbvp, pbip, idxp);
    vq_loss_partial_r19<<<4096, 256, 0, stream>>>(encp, cb, idxp, lpart);

    // regime tables
    gemm_bt_r19<GF_BIAS|GF_RELU><<<dim3(16, 2),  256, 0, stream>>>(cb, r1w, r1b, nullptr, nullptr, hregp, 512, 512, 512, 256);
    gemm_bt_r19<GF_BIAS><<<dim3(16, 16), 256, 0, stream>>>(hregp, r2w, r2b, nullptr, nullptr, Rp, 256, 256, 256, 2048);
    softmax_rows_r19<<<2048, 256, 0, stream>>>(Rp);
    hash_table_r19<<<512, 256, 0, stream>>>(cb, hw, Tp);

    // outputs
    write_loss_r19<<<1, 256, 0, stream>>>(lpart, out);
    write_regime_r19<<<131072, 256, 0, stream>>>(Rp, idxp, out);
    write_hash_r19<<<4096, 256, 0, stream>>>(Tp, idxp, out);
    write_idx_r19<<<64, 256, 0, stream>>>(idxp, out);
    write_quant_r19<<<32768, 256, 0, stream>>>(cb, idxp, out);
}

// Round 20
// 1558.495 us; speedup vs baseline: 1.2171x; 1.2171x over previous
//
#include <hip/hip_runtime.h>
#include <hip/hip_bf16.h>

// ---------------- problem constants ----------------
// B=32, S=512, D=512, K=2048; N = B*S = 16384. d_out is FLOAT32.
// r20 = r19 (A-tile hoisted across taps) + register double-buffered B staging:
// B(t+1) loads issue before the MFMA(t) phase, hiding global latency.
// Accumulation order identical to r19 (passed, absmax 1.0).
// write_idx folded into vq_reduce. All else r18/r19-verbatim.

#define GF_BIAS 1
#define GF_RELU 2
#define GF_ADD  4
#define GF_POS  8
#define GF_ACC  16

typedef _Float16 f16x8 __attribute__((ext_vector_type(8)));
typedef float    f32x4 __attribute__((ext_vector_type(4)));

static constexpr long long O_QUANT = 0LL;
static constexpr long long O_LOSS  = 8388608LL;
static constexpr long long O_IDX   = 8388609LL;
static constexpr long long O_HASH  = 8404993LL;
static constexpr long long O_REG   = 9453569LL;
static constexpr long long O_END   = 43008001LL;

static constexpr long long W_XP    = 0LL;
static constexpr long long W_CT    = 8388608LL;
static constexpr long long W_PROJ  = 16777216LL;
static constexpr long long W_VW    = 25165824LL;
static constexpr long long W_HREG  = 33554432LL;
static constexpr long long W_T     = 34078720LL;
static constexpr long long W_IDX   = 34209792LL;
static constexpr long long W_ASUM  = 34226176LL;
static constexpr long long W_CBB   = 34258944LL;
static constexpr long long W_LPART = 34263040LL;
static constexpr long long W_PBV   = 34271232LL;
static constexpr long long W_PBI   = 34336768LL;
static constexpr long long W_END   = 34402304LL;

__device__ __forceinline__ unsigned int pack_hl(float x)
{
    _Float16 h = (_Float16)x;
    float hf = (float)h;
    _Float16 l = (_Float16)(x - hf);
    unsigned short hb = __builtin_bit_cast(unsigned short, h);
    unsigned short lb = __builtin_bit_cast(unsigned short, l);
    return (unsigned int)hb | ((unsigned int)lb << 16);
}

__device__ __forceinline__ void split2(float x, unsigned short& h, unsigned short& l)
{
    _Float16 hf = (_Float16)x;
    _Float16 lf = (_Float16)(x - (float)hf);
    h = __builtin_bit_cast(unsigned short, hf);
    l = __builtin_bit_cast(unsigned short, lf);
}

// ---------------- split xp in place ------------------------------------------
__global__ __launch_bounds__(256)
void split_xp_r20(float* __restrict__ xp)
{
    long long i = (long long)blockIdx.x*256 + threadIdx.x;
    float x = xp[i];
    ((unsigned int*)xp)[i] = pack_hl(x);
}

template<int KT>
__global__ __launch_bounds__(256)
void conv_w_tr_r20(const float* __restrict__ w, unsigned int* __restrict__ wt)
{
    long long i = (long long)blockIdx.x*256 + threadIdx.x;
    int o  = (int)(i / (512*KT));
    int rem= (int)(i % (512*KT));
    int t  = rem >> 9;
    int ii = rem & 511;
    wt[i] = pack_hl(w[(long long)o*512*KT + (long long)ii*KT + t]);
}

// ---------------- conv via f16x3 MFMA: A hoisted + B reg-double-buffered -----
template<int KT>
__global__ __launch_bounds__(256)
void conv_mfma_r20(const unsigned int* __restrict__ xphl,
                   const unsigned int* __restrict__ wthl,
                   const float* __restrict__ bias, float* __restrict__ outp)
{
    constexpr int PAD = KT / 2;
    __shared__ unsigned short Ah[136][40];
    __shared__ unsigned short Al[136][40];
    __shared__ unsigned short Bh[128][40];
    __shared__ unsigned short Bl[128][40];
    const int tid  = threadIdx.x;
    const int lane = tid & 63;
    const int wave = tid >> 6;
    const int wm = (wave >> 1) * 64, wn = (wave & 1) * 64;
    const int bm = blockIdx.x * 128, bn = blockIdx.y * 128;
    const int l15 = lane & 15;
    const int lk8 = (lane >> 4) * 8;
    const int rbase = (lane >> 4) * 4;
    const int sb = bm & 511;

    // fixed per-thread B slots: s = tid + q*256; row = s>>3, c = s&7
    const int brow0 = tid >> 3, bc = tid & 7;   // q=0 slot; q adds 32 rows

    f32x4 acc[4][4];
    #pragma unroll
    for (int i=0;i<4;i++)
        #pragma unroll
        for (int j=0;j<4;j++)
            acc[i][j] = (f32x4){0.f,0.f,0.f,0.f};

    for (int i0 = 0; i0 < 512; i0 += 32) {
        __syncthreads();   // prior i0's MFMA readers done (A/B safe to overwrite)
        // stage A window: 136 rows (xp rows bm-4 .. bm+131)
        for (int sl = tid; sl < 136*8; sl += 256) {
            const int row = sl >> 3, c = sl & 7;
            const int srow = sb + row - 4;
            uint4 v = make_uint4(0u,0u,0u,0u);
            if (srow >= 0 && srow < 512)
                v = *(const uint4*)(xphl + (long long)(bm + row - 4)*512 + i0 + c*4);
            Ah[row][c*4+0] = (unsigned short)(v.x & 0xffff);
            Ah[row][c*4+1] = (unsigned short)(v.y & 0xffff);
            Ah[row][c*4+2] = (unsigned short)(v.z & 0xffff);
            Ah[row][c*4+3] = (unsigned short)(v.w & 0xffff);
            Al[row][c*4+0] = (unsigned short)(v.x >> 16);
            Al[row][c*4+1] = (unsigned short)(v.y >> 16);
            Al[row][c*4+2] = (unsigned short)(v.z >> 16);
            Al[row][c*4+3] = (unsigned short)(v.w >> 16);
        }
        // prefetch B(t=0) into registers
        uint4 vb[4];
        #pragma unroll
        for (int q = 0; q < 4; ++q) {
            const int row = brow0 + q*32;
            vb[q] = *(const uint4*)(wthl + (long long)(bn + row)*(KT*512) + 0*512 + i0 + bc*4);
        }
        for (int t = 0; t < KT; ++t) {
            // write B(t) from regs to LDS
            #pragma unroll
            for (int q = 0; q < 4; ++q) {
                const int row = brow0 + q*32;
                Bh[row][bc*4+0] = (unsigned short)(vb[q].x & 0xffff);
                Bh[row][bc*4+1] = (unsigned short)(vb[q].y & 0xffff);
                Bh[row][bc*4+2] = (unsigned short)(vb[q].z & 0xffff);
                Bh[row][bc*4+3] = (unsigned short)(vb[q].w & 0xffff);
                Bl[row][bc*4+0] = (unsigned short)(vb[q].x >> 16);
                Bl[row][bc*4+1] = (unsigned short)(vb[q].y >> 16);
                Bl[row][bc*4+2] = (unsigned short)(vb[q].z >> 16);
                Bl[row][bc*4+3] = (unsigned short)(vb[q].w >> 16);
            }
            // issue loads for B(t+1) BEFORE the MFMA phase (latency hidden)
            if (t + 1 < KT) {
                #pragma unroll
                for (int q = 0; q < 4; ++q) {
                    const int row = brow0 + q*32;
                    vb[q] = *(const uint4*)(wthl + (long long)(bn + row)*(KT*512) + (t+1)*512 + i0 + bc*4);
                }
            }
            __syncthreads();   // A (first tap) and B(t) visible to all
            const int tofs = t - PAD + 4;
            f16x8 ah[4], al[4], bh[4], bl[4];
            #pragma unroll
            for (int mi = 0; mi < 4; ++mi) {
                ah[mi] = *(const f16x8*)(&Ah[wm + mi*16 + l15 + tofs][lk8]);
                al[mi] = *(const f16x8*)(&Al[wm + mi*16 + l15 + tofs][lk8]);
            }
            #pragma unroll
            for (int nj = 0; nj < 4; ++nj) {
                bh[nj] = *(const f16x8*)(&Bh[wn + nj*16 + l15][lk8]);
                bl[nj] = *(const f16x8*)(&Bl[wn + nj*16 + l15][lk8]);
            }
            #pragma unroll
            for (int mi = 0; mi < 4; ++mi)
                #pragma unroll
                for (int nj = 0; nj < 4; ++nj) {
                    acc[mi][nj] = __builtin_amdgcn_mfma_f32_16x16x32_f16(ah[mi], bh[nj], acc[mi][nj], 0, 0, 0);
                    acc[mi][nj] = __builtin_amdgcn_mfma_f32_16x16x32_f16(ah[mi], bl[nj], acc[mi][nj], 0, 0, 0);
                    acc[mi][nj] = __builtin_amdgcn_mfma_f32_16x16x32_f16(al[mi], bh[nj], acc[mi][nj], 0, 0, 0);
                }
            if (t + 1 < KT) __syncthreads();   // B readers done before overwrite
        }
    }
    #pragma unroll
    for (int mi = 0; mi < 4; ++mi) {
        #pragma unroll
        for (int nj = 0; nj < 4; ++nj) {
            const int col = bn + wn + nj*16 + l15;
            const float bcol = bias[col];
            #pragma unroll
            for (int r = 0; r < 4; ++r) {
                const int row = bm + wm + mi*16 + rbase + r;
                float v = acc[mi][nj][r] + bcol;
                outp[(long long)row*512 + col] = fmaxf(v, 0.0f);
            }
        }
    }
}

// ---------------- generic GEMM via f16x3 MFMA (r18 verbatim) -----------------
template<int FLAGS>
__global__ __launch_bounds__(256)
void gemm_mfma_r20(const float* __restrict__ A, const float* __restrict__ Bm,
                   const float* __restrict__ bias, const float* __restrict__ pos,
                   const float* __restrict__ addsrc, float* __restrict__ C,
                   int Kdim, int lda, int ldb, int ldc)
{
    __shared__ unsigned short Ah[128][56];
    __shared__ unsigned short Al[128][56];
    __shared__ unsigned short Bh[128][56];
    __shared__ unsigned short Bl[128][56];
    const int tid  = threadIdx.x;
    const int lane = tid & 63;
    const int wave = tid >> 6;
    const int wm = (wave >> 1) * 64, wn = (wave & 1) * 64;
    const int bm = blockIdx.x * 128, bn = blockIdx.y * 128;
    const int l15 = lane & 15;
    const int lk8 = (lane >> 4) * 8;
    const int rbase = (lane >> 4) * 4;
    const int cg   = tid & 7;
    const int rw0  = tid >> 3;

    f32x4 acc[4][4];
    #pragma unroll
    for (int i=0;i<4;i++)
        #pragma unroll
        for (int j=0;j<4;j++)
            acc[i][j] = (f32x4){0.f,0.f,0.f,0.f};

    for (int k0 = 0; k0 < Kdim; k0 += 32) {
        float4 fa[4], fb[4];
        #pragma unroll
        for (int q = 0; q < 4; ++q) {
            const int row = rw0 + q*32;
            fa[q] = *(const float4*)(A  + (long long)(bm + row)*lda + k0 + cg*4);
            fb[q] = *(const float4*)(Bm + (long long)(bn + row)*ldb + k0 + cg*4);
        }
        __syncthreads();
        #pragma unroll
        for (int q = 0; q < 4; ++q) {
            const int row = rw0 + q*32;
            ushort4 ah_, al_, bh_, bl_;
            split2(fa[q].x, ah_.x, al_.x);
            split2(fa[q].y, ah_.y, al_.y);
            split2(fa[q].z, ah_.z, al_.z);
            split2(fa[q].w, ah_.w, al_.w);
            split2(fb[q].x, bh_.x, bl_.x);
            split2(fb[q].y, bh_.y, bl_.y);
            split2(fb[q].z, bh_.z, bl_.z);
            split2(fb[q].w, bh_.w, bl_.w);
            *(ushort4*)(&Ah[row][cg*4]) = ah_;
            *(ushort4*)(&Al[row][cg*4]) = al_;
            *(ushort4*)(&Bh[row][cg*4]) = bh_;
            *(ushort4*)(&Bl[row][cg*4]) = bl_;
        }
        __syncthreads();
        f16x8 ah[4], al[4], bh[4], bl[4];
        #pragma unroll
        for (int mi = 0; mi < 4; ++mi) {
            ah[mi] = *(const f16x8*)(&Ah[wm + mi*16 + l15][lk8]);
            al[mi] = *(const f16x8*)(&Al[wm + mi*16 + l15][lk8]);
        }
        #pragma unroll
        for (int nj = 0; nj < 4; ++nj) {
            bh[nj] = *(const f16x8*)(&Bh[wn + nj*16 + l15][lk8]);
            bl[nj] = *(const f16x8*)(&Bl[wn + nj*16 + l15][lk8]);
        }
        #pragma unroll
        for (int mi = 0; mi < 4; ++mi)
            #pragma unroll
            for (int nj = 0; nj < 4; ++nj) {
                acc[mi][nj] = __builtin_amdgcn_mfma_f32_16x16x32_f16(ah[mi], bh[nj], acc[mi][nj], 0, 0, 0);
                acc[mi][nj] = __builtin_amdgcn_mfma_f32_16x16x32_f16(ah[mi], bl[nj], acc[mi][nj], 0, 0, 0);
                acc[mi][nj] = __builtin_amdgcn_mfma_f32_16x16x32_f16(al[mi], bh[nj], acc[mi][nj], 0, 0, 0);
            }
    }
    #pragma unroll
    for (int mi = 0; mi < 4; ++mi) {
        #pragma unroll
        for (int nj = 0; nj < 4; ++nj) {
            const int col = bn + wn + nj*16 + l15;
            #pragma unroll
            for (int r = 0; r < 4; ++r) {
                const int row = bm + wm + mi*16 + rbase + r;
                float v = acc[mi][nj][r];
                if constexpr (FLAGS & GF_BIAS) v += bias[col];
                if constexpr (FLAGS & GF_POS)  v += pos[(long long)(row & 511)*512 + col];
                if constexpr (FLAGS & GF_ADD)  v += addsrc[(long long)row*ldc + col];
                if constexpr (FLAGS & GF_ACC)  v += C[(long long)row*ldc + col];
                if constexpr (FLAGS & GF_RELU) v = fmaxf(v, 0.0f);
                C[(long long)row*ldc + col] = v;
            }
        }
    }
}

// ---------------- fused attention via f16x3 MFMA (r18 verbatim) --------------
__global__ __launch_bounds__(256)
void attn_mfma_r20(const float* __restrict__ Qbuf, const float* __restrict__ Kbuf,
                   const float* __restrict__ Vbuf, float* __restrict__ att)
{
    __shared__ unsigned short Qh[64][68];
    __shared__ unsigned short Ql[64][68];
    __shared__ unsigned short Kh[64][68];
    __shared__ unsigned short Kl[64][68];
    __shared__ unsigned short Vh[64][68];
    __shared__ unsigned short Vl[64][68];
    const int tid  = threadIdx.x;
    const int lane = tid & 63;
    const int wave = tid >> 6;
    const int l15  = lane & 15;
    const int lq   = lane >> 4;
    const int lq8  = lq * 8;
    const int bid = blockIdx.x;
    const int qt = bid & 7, h = (bid >> 3) & 7, b = bid >> 6;
    const int row0 = b*512 + qt*64;

    #pragma unroll
    for (int u = 0; u < 16; ++u) {
        int e = u*256 + tid;
        int r = e >> 6, c = e & 63;
        float q = Qbuf[(long long)(row0 + r)*512 + h*64 + c] * 0.125f;
        unsigned short hs, ls;
        split2(q, hs, ls);
        Qh[r][c] = hs; Ql[r][c] = ls;
    }

    float m[4], l[4];
    f32x4 accO[4];
    #pragma unroll
    for (int r=0;r<4;r++){ m[r] = -1e30f; l[r] = 0.f; }
    #pragma unroll
    for (int j=0;j<4;j++) accO[j] = (f32x4){0.f,0.f,0.f,0.f};

    for (int kv = 0; kv < 512; kv += 64) {
        __syncthreads();
        #pragma unroll
        for (int u = 0; u < 16; ++u) {
            int e = u*256 + tid;
            int r = e >> 6, c = e & 63;
            float kvf = Kbuf[(long long)(b*512 + kv + r)*512 + h*64 + c];
            float vvf = Vbuf[(long long)(b*512 + kv + r)*512 + h*64 + c];
            unsigned short hs, ls;
            split2(kvf, hs, ls);
            Kh[r][c] = hs; Kl[r][c] = ls;
            split2(vvf, hs, ls);
            Vh[c][r] = hs; Vl[c][r] = ls;
        }
        __syncthreads();
        f32x4 accS[4];
        #pragma unroll
        for (int j=0;j<4;j++) accS[j] = (f32x4){0.f,0.f,0.f,0.f};
        #pragma unroll
        for (int ks = 0; ks < 2; ++ks) {
            f16x8 qh = *(const f16x8*)(&Qh[wave*16 + l15][ks*32 + lq8]);
            f16x8 ql = *(const f16x8*)(&Ql[wave*16 + l15][ks*32 + lq8]);
            #pragma unroll
            for (int nj = 0; nj < 4; ++nj) {
                f16x8 kh = *(const f16x8*)(&Kh[nj*16 + l15][ks*32 + lq8]);
                f16x8 kl = *(const f16x8*)(&Kl[nj*16 + l15][ks*32 + lq8]);
                accS[nj] = __builtin_amdgcn_mfma_f32_16x16x32_f16(qh, kh, accS[nj], 0, 0, 0);
                accS[nj] = __builtin_amdgcn_mfma_f32_16x16x32_f16(qh, kl, accS[nj], 0, 0, 0);
                accS[nj] = __builtin_amdgcn_mfma_f32_16x16x32_f16(ql, kh, accS[nj], 0, 0, 0);
            }
        }
        #pragma unroll
        for (int r = 0; r < 4; ++r) {
            float tm = fmaxf(fmaxf(accS[0][r], accS[1][r]), fmaxf(accS[2][r], accS[3][r]));
            #pragma unroll
            for (int msk = 1; msk < 16; msk <<= 1) tm = fmaxf(tm, __shfl_xor(tm, msk, 64));
            float mn = fmaxf(m[r], tm);
            float scale = expf(m[r] - mn);
            float rs = 0.f;
            #pragma unroll
            for (int nj = 0; nj < 4; ++nj) {
                float p = expf(accS[nj][r] - mn);
                accS[nj][r] = p;
                rs += p;
            }
            #pragma unroll
            for (int msk = 1; msk < 16; msk <<= 1) rs += __shfl_xor(rs, msk, 64);
            l[r] = l[r]*scale + rs;
            m[r] = mn;
            #pragma unroll
            for (int nj = 0; nj < 4; ++nj) accO[nj][r] *= scale;
        }
        __syncthreads();
        #pragma unroll
        for (int r = 0; r < 4; ++r)
            #pragma unroll
            for (int nj = 0; nj < 4; ++nj) {
                unsigned short hs, ls;
                split2(accS[nj][r], hs, ls);
                Kh[wave*16 + lq*4 + r][nj*16 + l15] = hs;
                Kl[wave*16 + lq*4 + r][nj*16 + l15] = ls;
            }
        __syncthreads();
        #pragma unroll
        for (int ks = 0; ks < 2; ++ks) {
            f16x8 ph = *(const f16x8*)(&Kh[wave*16 + l15][ks*32 + lq8]);
            f16x8 pl = *(const f16x8*)(&Kl[wave*16 + l15][ks*32 + lq8]);
            #pragma unroll
            for (int nj = 0; nj < 4; ++nj) {
                f16x8 vh = *(const f16x8*)(&Vh[nj*16 + l15][ks*32 + lq8]);
                f16x8 vl = *(const f16x8*)(&Vl[nj*16 + l15][ks*32 + lq8]);
                accO[nj] = __builtin_amdgcn_mfma_f32_16x16x32_f16(ph, vh, accO[nj], 0, 0, 0);
                accO[nj] = __builtin_amdgcn_mfma_f32_16x16x32_f16(ph, vl, accO[nj], 0, 0, 0);
                accO[nj] = __builtin_amdgcn_mfma_f32_16x16x32_f16(pl, vh, accO[nj], 0, 0, 0);
            }
        }
    }
    #pragma unroll
    for (int nj = 0; nj < 4; ++nj)
        #pragma unroll
        for (int r = 0; r < 4; ++r) {
            const int row = row0 + wave*16 + lq*4 + r;
            att[(long long)row*512 + h*64 + nj*16 + l15] = accO[nj][r] / l[r];
        }
}

// ---------------- row sum of squares (f64) -----------------------------------
__global__ __launch_bounds__(256)
void row_sumsq_r20(const float* __restrict__ X, double* __restrict__ outp)
{
    const int row  = blockIdx.x*4 + (threadIdx.x >> 6);
    const int lane = threadIdx.x & 63;
    double s = 0.0;
    #pragma unroll
    for (int u = 0; u < 8; ++u) {
        float v = X[(long long)row*512 + lane + u*64];
        s += (double)v * (double)v;
    }
    #pragma unroll
    for (int msk = 32; msk; msk >>= 1) s += __shfl_xor(s, msk, 64);
    if (lane == 0) outp[row] = s;
}

// ---------------- VQ argmin via f16x3 MFMA (r18 verbatim) --------------------
__global__ __launch_bounds__(256)
void vq_argmin_mfma_r20(const float* __restrict__ enc, const float* __restrict__ cb,
                        const double* __restrict__ Asum, const double* __restrict__ cbB,
                        float* __restrict__ pbv, int* __restrict__ pbi)
{
    __shared__ unsigned int smem[14336];
    unsigned short* AhP = (unsigned short*)smem;
    unsigned short* AlP = AhP + 128*56;
    unsigned short* BhP = AlP + 128*56;
    unsigned short* BlP = BhP + 128*56;
    float* bvsP = (float*)smem;
    int*   bisP = (int*)(smem + 4096);

    const int tid  = threadIdx.x;
    const int lane = tid & 63;
    const int wave = tid >> 6;
    const int wm = (wave >> 1) * 64, wn = (wave & 1) * 64;
    const int bm = blockIdx.x * 128;
    const int l15 = lane & 15;
    const int lk8 = (lane >> 4) * 8;
    const int rbase = (lane >> 4) * 4;
    const int cg   = tid & 7;
    const int rw0  = tid >> 3;

    float bestv[16]; int besti[16];
    #pragma unroll
    for (int g = 0; g < 16; ++g) { bestv[g] = 3.0e38f; besti[g] = 2048; }

    for (int nb = 0; nb < 4; ++nb) {
        const int ct0 = blockIdx.y * 512 + nb * 128;
        f32x4 acc[4][4];
        #pragma unroll
        for (int i=0;i<4;i++)
            #pragma unroll
            for (int j=0;j<4;j++)
                acc[i][j] = (f32x4){0.f,0.f,0.f,0.f};

        for (int k0 = 0; k0 < 512; k0 += 32) {
            float4 fa[4], fb[4];
            #pragma unroll
            for (int q = 0; q < 4; ++q) {
                const int row = rw0 + q*32;
                fa[q] = *(const float4*)(enc + (long long)(bm + row)*512 + k0 + cg*4);
                fb[q] = *(const float4*)(cb  + (long long)(ct0 + row)*512 + k0 + cg*4);
            }
            __syncthreads();
            #pragma unroll
            for (int q = 0; q < 4; ++q) {
                const int row = rw0 + q*32;
                ushort4 ah_, al_, bh_, bl_;
                split2(fa[q].x, ah_.x, al_.x);
                split2(fa[q].y, ah_.y, al_.y);
                split2(fa[q].z, ah_.z, al_.z);
                split2(fa[q].w, ah_.w, al_.w);
                split2(fb[q].x * 2048.0f, bh_.x, bl_.x);
                split2(fb[q].y * 2048.0f, bh_.y, bl_.y);
                split2(fb[q].z * 2048.0f, bh_.z, bl_.z);
                split2(fb[q].w * 2048.0f, bh_.w, bl_.w);
                *(ushort4*)(&AhP[row*56 + cg*4]) = ah_;
                *(ushort4*)(&AlP[row*56 + cg*4]) = al_;
                *(ushort4*)(&BhP[row*56 + cg*4]) = bh_;
                *(ushort4*)(&BlP[row*56 + cg*4]) = bl_;
            }
            __syncthreads();
            f16x8 ah[4], al[4], bh[4], bl[4];
            #pragma unroll
            for (int mi = 0; mi < 4; ++mi) {
                ah[mi] = *(const f16x8*)(&AhP[(wm + mi*16 + l15)*56 + lk8]);
                al[mi] = *(const f16x8*)(&AlP[(wm + mi*16 + l15)*56 + lk8]);
            }
            #pragma unroll
            for (int nj = 0; nj < 4; ++nj) {
                bh[nj] = *(const f16x8*)(&BhP[(wn + nj*16 + l15)*56 + lk8]);
                bl[nj] = *(const f16x8*)(&BlP[(wn + nj*16 + l15)*56 + lk8]);
            }
            #pragma unroll
            for (int mi = 0; mi < 4; ++mi)
                #pragma unroll
                for (int nj = 0; nj < 4; ++nj) {
                    acc[mi][nj] = __builtin_amdgcn_mfma_f32_16x16x32_f16(ah[mi], bh[nj], acc[mi][nj], 0, 0, 0);
                    acc[mi][nj] = __builtin_amdgcn_mfma_f32_16x16x32_f16(ah[mi], bl[nj], acc[mi][nj], 0, 0, 0);
                    acc[mi][nj] = __builtin_amdgcn_mfma_f32_16x16x32_f16(al[mi], bh[nj], acc[mi][nj], 0, 0, 0);
                }
        }
        #pragma unroll
        for (int mi = 0; mi < 4; ++mi) {
            #pragma unroll
            for (int r = 0; r < 4; ++r) {
                const int g = mi*4 + r;
                const float anf = (float)Asum[bm + wm + mi*16 + rbase + r];
                #pragma unroll
                for (int nj = 0; nj < 4; ++nj) {
                    const int col = ct0 + wn + nj*16 + l15;
                    const float bf = (float)cbB[col];
                    const float s1 = anf + bf;
                    const float dot = acc[mi][nj][r] * (1.0f/2048.0f);
                    const float df  = 2.0f * dot;
                    const float qd  = s1 - df;
                    if (qd < bestv[g] || (qd == bestv[g] && col < besti[g])) {
                        bestv[g] = qd; besti[g] = col;
                    }
                }
            }
        }
    }
    __syncthreads();
    #pragma unroll
    for (int mi = 0; mi < 4; ++mi)
        #pragma unroll
        for (int r = 0; r < 4; ++r) {
            const int row  = wm + mi*16 + rbase + r;
            const int slot = (wave & 1)*16 + l15;
            bvsP[row*32 + slot] = bestv[mi*4 + r];
            bisP[row*32 + slot] = besti[mi*4 + r];
        }
    __syncthreads();
    if (tid < 128) {
        float bv = bvsP[tid*32]; int bi = bisP[tid*32];
        #pragma unroll
        for (int s = 1; s < 32; ++s) {
            float v = bvsP[tid*32 + s]; int ii = bisP[tid*32 + s];
            if (v < bv || (v == bv && ii < bi)) { bv = v; bi = ii; }
        }
        pbv[(long long)blockIdx.y*16384 + bm + tid] = bv;
        pbi[(long long)blockIdx.y*16384 + bm + tid] = bi;
    }
}

// vq_reduce also writes the idx output (folded write_idx)
__global__ __launch_bounds__(256)
void vq_reduce_r20(const float* __restrict__ pbv, const int* __restrict__ pbi,
                   int* __restrict__ idxout, float* __restrict__ out)
{
    int n = blockIdx.x*256 + threadIdx.x;
    if (n >= 16384) return;
    float bv = pbv[n]; int bi = pbi[n];
    #pragma unroll
    for (int q = 1; q < 4; ++q) {
        float v = pbv[q*16384 + n]; int ii = pbi[q*16384 + n];
        if (v < bv || (v == bv && ii < bi)) { bv = v; bi = ii; }
    }
    int ci = bi & 2047;
    idxout[n] = ci;
    out[O_IDX + n] = (float)ci;
}

// ---------------- vq loss ----------------------------------------------------
__global__ __launch_bounds__(256)
void vq_loss_partial_r20(const float* __restrict__ enc, const float* __restrict__ cb,
                         const int* __restrict__ idxp, double* __restrict__ part)
{
    __shared__ double red[4];
    const int row  = blockIdx.x*4 + (threadIdx.x >> 6);
    const int lane = threadIdx.x & 63;
    const int ci = idxp[row] & 2047;
    double s = 0.0;
    #pragma unroll
    for (int u = 0; u < 8; ++u) {
        int d = lane + u*64;
        double dv = (double)cb[(long long)ci*512 + d] - (double)enc[(long long)row*512 + d];
        s += dv * dv;
    }
    #pragma unroll
    for (int msk = 32; msk; msk >>= 1) s += __shfl_xor(s, msk, 64);
    if (lane == 0) red[threadIdx.x >> 6] = s;
    __syncthreads();
    if (threadIdx.x == 0)
        part[blockIdx.x] = red[0] + red[1] + red[2] + red[3];
}

// ---------------- regime f32 GEMM (small) ------------------------------------
template<int FLAGS>
__global__ __launch_bounds__(256)
void gemm_bt_r20(const float* __restrict__ A, const float* __restrict__ Bm,
                 const float* __restrict__ bias, const float* __restrict__ pos,
                 const float* __restrict__ addsrc, float* __restrict__ C,
                 int Kdim, int lda, int ldb, int ldc)
{
    __shared__ float As[16][132];
    __shared__ float Bs[16][132];
    const int tid = threadIdx.x;
    const int tx = tid & 15, ty = tid >> 4;
    const int bm = blockIdx.x * 128, bn = blockIdx.y * 128;
    const int r0 = tid >> 2;
    const int kg = (tid & 3) << 2;
    const float* Arow0 = A  + (long long)(bm + r0) * lda + kg;
    const float* Arow1 = A  + (long long)(bm + r0 + 64) * lda + kg;
    const float* Brow0 = Bm + (long long)(bn + r0) * ldb + kg;
    const float* Brow1 = Bm + (long long)(bn + r0 + 64) * ldb + kg;

    float acc[8][8] = {};
    for (int k0 = 0; k0 < Kdim; k0 += 16) {
        float4 a0 = *(const float4*)(Arow0 + k0);
        float4 a1 = *(const float4*)(Arow1 + k0);
        float4 b0 = *(const float4*)(Brow0 + k0);
        float4 b1 = *(const float4*)(Brow1 + k0);
        __syncthreads();
        As[kg+0][r0]=a0.x; As[kg+1][r0]=a0.y; As[kg+2][r0]=a0.z; As[kg+3][r0]=a0.w;
        As[kg+0][r0+64]=a1.x; As[kg+1][r0+64]=a1.y; As[kg+2][r0+64]=a1.z; As[kg+3][r0+64]=a1.w;
        Bs[kg+0][r0]=b0.x; Bs[kg+1][r0]=b0.y; Bs[kg+2][r0]=b0.z; Bs[kg+3][r0]=b0.w;
        Bs[kg+0][r0+64]=b1.x; Bs[kg+1][r0+64]=b1.y; Bs[kg+2][r0+64]=b1.z; Bs[kg+3][r0+64]=b1.w;
        __syncthreads();
        #pragma unroll
        for (int kk = 0; kk < 16; ++kk) {
            float a[8], b[8];
            #pragma unroll
            for (int i=0;i<8;i++) a[i] = As[kk][ty*8+i];
            #pragma unroll
            for (int j=0;j<4;j++) b[j]   = Bs[kk][tx*4+j];
            #pragma unroll
            for (int j=0;j<4;j++) b[4+j] = Bs[kk][64+tx*4+j];
            #pragma unroll
            for (int i=0;i<8;i++)
                #pragma unroll
                for (int j=0;j<8;j++)
                    acc[i][j] = fmaf(a[i], b[j], acc[i][j]);
        }
    }
    #pragma unroll
    for (int i=0;i<8;i++){
        const int row = bm + ty*8 + i;
        #pragma unroll
        for (int j=0;j<8;j++){
            const int col = bn + ((j < 4) ? (tx*4 + j) : (64 + tx*4 + (j-4)));
            float v = acc[i][j];
            if constexpr (FLAGS & GF_BIAS) v += bias[col];
            if constexpr (FLAGS & GF_POS)  v += pos[(long long)(row & 511)*512 + col];
            if constexpr (FLAGS & GF_ADD)  v += addsrc[(long long)row*ldc + col];
            if constexpr (FLAGS & GF_ACC)  v += C[(long long)row*ldc + col];
            if constexpr (FLAGS & GF_RELU) v = fmaxf(v, 0.0f);
            C[(long long)row*ldc + col] = v;
        }
    }
}

// ---------------- regime softmax ---------------------------------------------
__global__ __launch_bounds__(256)
void softmax_rows_r20(float* __restrict__ R)
{
    const int row = blockIdx.x;
    const int tid = threadIdx.x;
    __shared__ float  redf[256];
    __shared__ double redd[256];
    float* p = R + (long long)row * 2048;
    float mx = -1e30f;
    for (int c = tid; c < 2048; c += 256) mx = fmaxf(mx, p[c]);
    redf[tid] = mx; __syncthreads();
    for (int s2 = 128; s2; s2 >>= 1) { if (tid < s2) redf[tid] = fmaxf(redf[tid], redf[tid+s2]); __syncthreads(); }
    mx = redf[0];
    double sum = 0.0;
    for (int c = tid; c < 2048; c += 256) { float e = expf(p[c] - mx); p[c] = e; sum += e; }
    redd[tid] = sum; __syncthreads();
    for (int s2 = 128; s2; s2 >>= 1) { if (tid < s2) redd[tid] += redd[tid+s2]; __syncthreads(); }
    double tot = redd[0];
    for (int c = tid; c < 2048; c += 256) p[c] = (float)((double)p[c] / tot);
}

// ---------------- hash table -------------------------------------------------
__global__ __launch_bounds__(256)
void hash_table_r20(const float* __restrict__ cb, const float* __restrict__ hw,
                    float* __restrict__ T)
{
    const int k = blockIdx.x*4 + (threadIdx.x >> 6);
    const int j = threadIdx.x & 63;
    double s = 0.0;
    for (int d = 0; d < 512; ++d)
        s += (double)cb[(long long)k*512 + d] * (double)hw[(long long)j*512 + d];
    T[(long long)k*64 + j] = (s > 0.0) ? 1.0f : 0.0f;
}

// ---------------- output writers ---------------------------------------------
__global__ void write_loss_r20(const double* __restrict__ part,
                               float* __restrict__ out)
{
    __shared__ double red[256];
    double s = 0.0;
    for (int i = threadIdx.x; i < 4096; i += 256) s += part[i];
    red[threadIdx.x] = s; __syncthreads();
    for (int s2 = 128; s2; s2 >>= 1) {
        if (threadIdx.x < s2) red[threadIdx.x] += red[threadIdx.x + s2];
        __syncthreads();
    }
    if (threadIdx.x == 0)
        out[O_LOSS] = (float)(1.25 * red[0] / 8388608.0);
}

__global__ __launch_bounds__(256)
void write_regime_r20(const float* __restrict__ R, const int* __restrict__ idxp,
                      float* __restrict__ out)
{
    long long i = (long long)blockIdx.x*256 + threadIdx.x;
    if (i >= 33554432LL) return;
    int n = (int)(i >> 11), c = (int)(i & 2047);
    int ci = idxp[n] & 2047;
    out[O_REG + i] = R[(long long)ci*2048 + c];
}

__global__ __launch_bounds__(256)
void write_hash_r20(const float* __restrict__ T, const int* __restrict__ idxp,
                    float* __restrict__ out)
{
    long long i = (long long)blockIdx.x*256 + threadIdx.x;
    if (i >= 1048576LL) return;
    int n = (int)(i >> 6), j = (int)(i & 63);
    int ci = idxp[n] & 2047;
    out[O_HASH + i] = T[(long long)ci*64 + j];
}

__global__ __launch_bounds__(256)
void write_quant_r20(const float* __restrict__ cb, const int* __restrict__ idxp,
                     float* __restrict__ out)
{
    long long i = (long long)blockIdx.x*256 + threadIdx.x;
    if (i >= 8388608LL) return;
    int n = (int)(i >> 9), d = (int)(i & 511);
    int ci = idxp[n] & 2047;
    out[O_QUANT + i] = cb[(long long)ci*512 + d];
}

// ---------------- launcher ----------------------------------------------------
extern "C" void kernel_launch(void* const* d_in, const int* in_sizes, int n_in,
                              void* d_out, int out_size, void* d_ws, size_t ws_size,
                              hipStream_t stream)
{
    (void)in_sizes; (void)n_in; (void)out_size;
    const float* market = (const float*)d_in[0];
    const float* W_in   = (const float*)d_in[1];
    const float* b_in   = (const float*)d_in[2];
    const float* pos    = (const float*)d_in[3];
    const float* c3w = (const float*)d_in[4];  const float* c3b = (const float*)d_in[5];
    const float* c5w = (const float*)d_in[6];  const float* c5b = (const float*)d_in[7];
    const float* c7w = (const float*)d_in[8];  const float* c7b = (const float*)d_in[9];
    const float* c9w = (const float*)d_in[10]; const float* c9b = (const float*)d_in[11];
    const float* msw = (const float*)d_in[12]; const float* msb = (const float*)d_in[13];
    const float* inw = (const float*)d_in[14]; const float* inb = (const float*)d_in[15];
    const float* aow = (const float*)d_in[16]; const float* aob = (const float*)d_in[17];
    const float* cb  = (const float*)d_in[18]; const float* hw  = (const float*)d_in[19];
    const float* r1w = (const float*)d_in[20]; const float* r1b = (const float*)d_in[21];
    const float* r2w = (const float*)d_in[22]; const float* r2b = (const float*)d_in[23];

    if (ws_size < (size_t)W_END * sizeof(float)) return;

    float* ws    = (float*)d_ws;
    float* xp    = ws + W_XP;
    float* convt = ws + W_CT;
    float* projp = ws + W_PROJ;
    unsigned int* wt3 = (unsigned int*)(ws + W_VW);
    unsigned int* wt5 = wt3 + 512*512*3;
    unsigned int* wt7 = wt5 + 512*512*5;
    unsigned int* wt9 = wt7 + 512*512*7;
    float* Vbufp = ws + W_VW;
    float* hregp = ws + W_HREG;
    float* Tp    = ws + W_T;
    int*    idxp  = (int*)(ws + W_IDX);
    double* asump = (double*)(ws + W_ASUM);
    double* cbbp  = (double*)(ws + W_CBB);
    double* lpart = (double*)(ws + W_LPART);
    float*  pbvp  = ws + W_PBV;
    int*    pbip  = (int*)(ws + W_PBI);

    float* out = (float*)d_out;

    float* Qbufp = xp;
    float* attp  = xp;
    float* Kbufp = convt;
    float* encp  = convt;
    float* Rp    = projp;

    const unsigned int* xpu = (const unsigned int*)xp;

    conv_w_tr_r20<3><<<3072, 256, 0, stream>>>(c3w, wt3);
    conv_w_tr_r20<5><<<5120, 256, 0, stream>>>(c5w, wt5);
    conv_w_tr_r20<7><<<7168, 256, 0, stream>>>(c7w, wt7);
    conv_w_tr_r20<9><<<9216, 256, 0, stream>>>(c9w, wt9);

    const dim3 gT(128, 4);

    gemm_mfma_r20<GF_BIAS|GF_POS><<<gT, 256, 0, stream>>>(market, W_in, b_in, pos, nullptr, xp, 512, 512, 512, 512);
    split_xp_r20<<<32768, 256, 0, stream>>>(xp);

    conv_mfma_r20<3><<<gT, 256, 0, stream>>>(xpu, wt3, c3b, convt);
    gemm_mfma_r20<GF_BIAS><<<gT, 256, 0, stream>>>(convt, msw + 0*512, msb, nullptr, nullptr, projp, 512, 512, 2048, 512);
    conv_mfma_r20<5><<<gT, 256, 0, stream>>>(xpu, wt5, c5b, convt);
    gemm_mfma_r20<GF_ACC><<<gT, 256, 0, stream>>>(convt, msw + 1*512, nullptr, nullptr, nullptr, projp, 512, 512, 2048, 512);
    conv_mfma_r20<7><<<gT, 256, 0, stream>>>(xpu, wt7, c7b, convt);
    gemm_mfma_r20<GF_ACC><<<gT, 256, 0, stream>>>(convt, msw + 2*512, nullptr, nullptr, nullptr, projp, 512, 512, 2048, 512);
    conv_mfma_r20<9><<<gT, 256, 0, stream>>>(xpu, wt9, c9b, convt);
    gemm_mfma_r20<GF_ACC><<<gT, 256, 0, stream>>>(convt, msw + 3*512, nullptr, nullptr, nullptr, projp, 512, 512, 2048, 512);

    gemm_mfma_r20<GF_BIAS><<<gT, 256, 0, stream>>>(projp, inw + 512*512,  inb + 512,  nullptr, nullptr, Kbufp, 512, 512, 512, 512);
    gemm_mfma_r20<GF_BIAS><<<gT, 256, 0, stream>>>(projp, inw + 1024*512, inb + 1024, nullptr, nullptr, Vbufp, 512, 512, 512, 512);
    gemm_mfma_r20<GF_BIAS><<<gT, 256, 0, stream>>>(projp, inw,            inb,        nullptr, nullptr, Qbufp, 512, 512, 512, 512);

    attn_mfma_r20<<<2048, 256, 0, stream>>>(Qbufp, Kbufp, Vbufp, attp);

    gemm_mfma_r20<GF_BIAS|GF_ADD><<<gT, 256, 0, stream>>>(attp, aow, aob, nullptr, projp, encp, 512, 512, 512, 512);

    // VQ
    row_sumsq_r20<<<4096, 256, 0, stream>>>(encp, asump);
    row_sumsq_r20<<<512,  256, 0, stream>>>(cb, cbbp);
    vq_argmin_mfma_r20<<<dim3(128, 4), 256, 0, stream>>>(encp, cb, asump, cbbp, pbvp, pbip);
    vq_reduce_r20<<<64, 256, 0, stream>>>(pbvp, pbip, idxp, out);
    vq_loss_partial_r20<<<4096, 256, 0, stream>>>(encp, cb, idxp, lpart);

    // regime tables
    gemm_bt_r20<GF_BIAS|GF_RELU><<<dim3(16, 2),  256, 0, stream>>>(cb, r1w, r1b, nullptr, nullptr, hregp, 512, 512, 512, 256);
    gemm_bt_r20<GF_BIAS><<<dim3(16, 16), 256, 0, stream>>>(hregp, r2w, r2b, nullptr, nullptr, Rp, 256, 256, 256, 2048);
    softmax_rows_r20<<<2048, 256, 0, stream>>>(Rp);
    hash_table_r20<<<512, 256, 0, stream>>>(cb, hw, Tp);

    // outputs
    write_loss_r20<<<1, 256, 0, stream>>>(lpart, out);
    write_regime_r20<<<131072, 256, 0, stream>>>(Rp, idxp, out);
    write_hash_r20<<<4096, 256, 0, stream>>>(Tp, idxp, out);
    write_quant_r20<<<32768, 256, 0, stream>>>(cb, idxp, out);
}

// Round 21
// 1554.425 us; speedup vs baseline: 1.2203x; 1.0026x over previous
//
#include <hip/hip_runtime.h>
#include <hip/hip_bf16.h>

// ---------------- problem constants ----------------
// B=32, S=512, D=512, K=2048; N = B*S = 16384. d_out is FLOAT32.
// r21 = r20 + VQ argmin reads PRE-SPLIT packed (hi,lo) enc and cb (the conv
// pattern): enc split in place after row_sumsq; cb (x2048-scaled) split into a
// spare slice of the dead proj region. Dist path bit-identical to r20.
// vq_loss reconstructs enc = hi+lo (error ~6e-7, negligible).

#define GF_BIAS 1
#define GF_RELU 2
#define GF_ADD  4
#define GF_POS  8
#define GF_ACC  16

typedef _Float16 f16x8 __attribute__((ext_vector_type(8)));
typedef float    f32x4 __attribute__((ext_vector_type(4)));

static constexpr long long O_QUANT = 0LL;
static constexpr long long O_LOSS  = 8388608LL;
static constexpr long long O_IDX   = 8388609LL;
static constexpr long long O_HASH  = 8404993LL;
static constexpr long long O_REG   = 9453569LL;
static constexpr long long O_END   = 43008001LL;

static constexpr long long W_XP    = 0LL;
static constexpr long long W_CT    = 8388608LL;
static constexpr long long W_PROJ  = 16777216LL;   // proj -> R (4.2M) | cbhl at +4.2M
static constexpr long long W_VW    = 25165824LL;
static constexpr long long W_HREG  = 33554432LL;
static constexpr long long W_T     = 34078720LL;
static constexpr long long W_IDX   = 34209792LL;
static constexpr long long W_ASUM  = 34226176LL;
static constexpr long long W_CBB   = 34258944LL;
static constexpr long long W_LPART = 34263040LL;
static constexpr long long W_PBV   = 34271232LL;
static constexpr long long W_PBI   = 34336768LL;
static constexpr long long W_END   = 34402304LL;

__device__ __forceinline__ unsigned int pack_hl(float x)
{
    _Float16 h = (_Float16)x;
    float hf = (float)h;
    _Float16 l = (_Float16)(x - hf);
    unsigned short hb = __builtin_bit_cast(unsigned short, h);
    unsigned short lb = __builtin_bit_cast(unsigned short, l);
    return (unsigned int)hb | ((unsigned int)lb << 16);
}

__device__ __forceinline__ void split2(float x, unsigned short& h, unsigned short& l)
{
    _Float16 hf = (_Float16)x;
    _Float16 lf = (_Float16)(x - (float)hf);
    h = __builtin_bit_cast(unsigned short, hf);
    l = __builtin_bit_cast(unsigned short, lf);
}

__device__ __forceinline__ float unpack_sum(unsigned int u)
{
    _Float16 h = __builtin_bit_cast(_Float16, (unsigned short)(u & 0xffff));
    _Float16 l = __builtin_bit_cast(_Float16, (unsigned short)(u >> 16));
    return (float)h + (float)l;
}

// ---------------- split buffers ----------------------------------------------
__global__ __launch_bounds__(256)
void split_inplace_r21(float* __restrict__ p)       // 8388608 elems
{
    long long i = (long long)blockIdx.x*256 + threadIdx.x;
    float x = p[i];
    ((unsigned int*)p)[i] = pack_hl(x);
}

__global__ __launch_bounds__(256)
void split_cb_r21(const float* __restrict__ cb, unsigned int* __restrict__ cbhl)  // 1048576
{
    long long i = (long long)blockIdx.x*256 + threadIdx.x;
    cbhl[i] = pack_hl(cb[i] * 2048.0f);
}

template<int KT>
__global__ __launch_bounds__(256)
void conv_w_tr_r21(const float* __restrict__ w, unsigned int* __restrict__ wt)
{
    long long i = (long long)blockIdx.x*256 + threadIdx.x;
    int o  = (int)(i / (512*KT));
    int rem= (int)(i % (512*KT));
    int t  = rem >> 9;
    int ii = rem & 511;
    wt[i] = pack_hl(w[(long long)o*512*KT + (long long)ii*KT + t]);
}

// ---------------- conv via f16x3 MFMA (r20 verbatim) -------------------------
template<int KT>
__global__ __launch_bounds__(256)
void conv_mfma_r21(const unsigned int* __restrict__ xphl,
                   const unsigned int* __restrict__ wthl,
                   const float* __restrict__ bias, float* __restrict__ outp)
{
    constexpr int PAD = KT / 2;
    __shared__ unsigned short Ah[136][40];
    __shared__ unsigned short Al[136][40];
    __shared__ unsigned short Bh[128][40];
    __shared__ unsigned short Bl[128][40];
    const int tid  = threadIdx.x;
    const int lane = tid & 63;
    const int wave = tid >> 6;
    const int wm = (wave >> 1) * 64, wn = (wave & 1) * 64;
    const int bm = blockIdx.x * 128, bn = blockIdx.y * 128;
    const int l15 = lane & 15;
    const int lk8 = (lane >> 4) * 8;
    const int rbase = (lane >> 4) * 4;
    const int sb = bm & 511;
    const int brow0 = tid >> 3, bc = tid & 7;

    f32x4 acc[4][4];
    #pragma unroll
    for (int i=0;i<4;i++)
        #pragma unroll
        for (int j=0;j<4;j++)
            acc[i][j] = (f32x4){0.f,0.f,0.f,0.f};

    for (int i0 = 0; i0 < 512; i0 += 32) {
        __syncthreads();
        for (int sl = tid; sl < 136*8; sl += 256) {
            const int row = sl >> 3, c = sl & 7;
            const int srow = sb + row - 4;
            uint4 v = make_uint4(0u,0u,0u,0u);
            if (srow >= 0 && srow < 512)
                v = *(const uint4*)(xphl + (long long)(bm + row - 4)*512 + i0 + c*4);
            Ah[row][c*4+0] = (unsigned short)(v.x & 0xffff);
            Ah[row][c*4+1] = (unsigned short)(v.y & 0xffff);
            Ah[row][c*4+2] = (unsigned short)(v.z & 0xffff);
            Ah[row][c*4+3] = (unsigned short)(v.w & 0xffff);
            Al[row][c*4+0] = (unsigned short)(v.x >> 16);
            Al[row][c*4+1] = (unsigned short)(v.y >> 16);
            Al[row][c*4+2] = (unsigned short)(v.z >> 16);
            Al[row][c*4+3] = (unsigned short)(v.w >> 16);
        }
        uint4 vb[4];
        #pragma unroll
        for (int q = 0; q < 4; ++q) {
            const int row = brow0 + q*32;
            vb[q] = *(const uint4*)(wthl + (long long)(bn + row)*(KT*512) + 0*512 + i0 + bc*4);
        }
        for (int t = 0; t < KT; ++t) {
            #pragma unroll
            for (int q = 0; q < 4; ++q) {
                const int row = brow0 + q*32;
                Bh[row][bc*4+0] = (unsigned short)(vb[q].x & 0xffff);
                Bh[row][bc*4+1] = (unsigned short)(vb[q].y & 0xffff);
                Bh[row][bc*4+2] = (unsigned short)(vb[q].z & 0xffff);
                Bh[row][bc*4+3] = (unsigned short)(vb[q].w & 0xffff);
                Bl[row][bc*4+0] = (unsigned short)(vb[q].x >> 16);
                Bl[row][bc*4+1] = (unsigned short)(vb[q].y >> 16);
                Bl[row][bc*4+2] = (unsigned short)(vb[q].z >> 16);
                Bl[row][bc*4+3] = (unsigned short)(vb[q].w >> 16);
            }
            if (t + 1 < KT) {
                #pragma unroll
                for (int q = 0; q < 4; ++q) {
                    const int row = brow0 + q*32;
                    vb[q] = *(const uint4*)(wthl + (long long)(bn + row)*(KT*512) + (t+1)*512 + i0 + bc*4);
                }
            }
            __syncthreads();
            const int tofs = t - PAD + 4;
            f16x8 ah[4], al[4], bh[4], bl[4];
            #pragma unroll
            for (int mi = 0; mi < 4; ++mi) {
                ah[mi] = *(const f16x8*)(&Ah[wm + mi*16 + l15 + tofs][lk8]);
                al[mi] = *(const f16x8*)(&Al[wm + mi*16 + l15 + tofs][lk8]);
            }
            #pragma unroll
            for (int nj = 0; nj < 4; ++nj) {
                bh[nj] = *(const f16x8*)(&Bh[wn + nj*16 + l15][lk8]);
                bl[nj] = *(const f16x8*)(&Bl[wn + nj*16 + l15][lk8]);
            }
            #pragma unroll
            for (int mi = 0; mi < 4; ++mi)
                #pragma unroll
                for (int nj = 0; nj < 4; ++nj) {
                    acc[mi][nj] = __builtin_amdgcn_mfma_f32_16x16x32_f16(ah[mi], bh[nj], acc[mi][nj], 0, 0, 0);
                    acc[mi][nj] = __builtin_amdgcn_mfma_f32_16x16x32_f16(ah[mi], bl[nj], acc[mi][nj], 0, 0, 0);
                    acc[mi][nj] = __builtin_amdgcn_mfma_f32_16x16x32_f16(al[mi], bh[nj], acc[mi][nj], 0, 0, 0);
                }
            if (t + 1 < KT) __syncthreads();
        }
    }
    #pragma unroll
    for (int mi = 0; mi < 4; ++mi) {
        #pragma unroll
        for (int nj = 0; nj < 4; ++nj) {
            const int col = bn + wn + nj*16 + l15;
            const float bcol = bias[col];
            #pragma unroll
            for (int r = 0; r < 4; ++r) {
                const int row = bm + wm + mi*16 + rbase + r;
                float v = acc[mi][nj][r] + bcol;
                outp[(long long)row*512 + col] = fmaxf(v, 0.0f);
            }
        }
    }
}

// ---------------- generic GEMM via f16x3 MFMA (r20 verbatim) -----------------
template<int FLAGS>
__global__ __launch_bounds__(256)
void gemm_mfma_r21(const float* __restrict__ A, const float* __restrict__ Bm,
                   const float* __restrict__ bias, const float* __restrict__ pos,
                   const float* __restrict__ addsrc, float* __restrict__ C,
                   int Kdim, int lda, int ldb, int ldc)
{
    __shared__ unsigned short Ah[128][56];
    __shared__ unsigned short Al[128][56];
    __shared__ unsigned short Bh[128][56];
    __shared__ unsigned short Bl[128][56];
    const int tid  = threadIdx.x;
    const int lane = tid & 63;
    const int wave = tid >> 6;
    const int wm = (wave >> 1) * 64, wn = (wave & 1) * 64;
    const int bm = blockIdx.x * 128, bn = blockIdx.y * 128;
    const int l15 = lane & 15;
    const int lk8 = (lane >> 4) * 8;
    const int rbase = (lane >> 4) * 4;
    const int cg   = tid & 7;
    const int rw0  = tid >> 3;

    f32x4 acc[4][4];
    #pragma unroll
    for (int i=0;i<4;i++)
        #pragma unroll
        for (int j=0;j<4;j++)
            acc[i][j] = (f32x4){0.f,0.f,0.f,0.f};

    for (int k0 = 0; k0 < Kdim; k0 += 32) {
        float4 fa[4], fb[4];
        #pragma unroll
        for (int q = 0; q < 4; ++q) {
            const int row = rw0 + q*32;
            fa[q] = *(const float4*)(A  + (long long)(bm + row)*lda + k0 + cg*4);
            fb[q] = *(const float4*)(Bm + (long long)(bn + row)*ldb + k0 + cg*4);
        }
        __syncthreads();
        #pragma unroll
        for (int q = 0; q < 4; ++q) {
            const int row = rw0 + q*32;
            ushort4 ah_, al_, bh_, bl_;
            split2(fa[q].x, ah_.x, al_.x);
            split2(fa[q].y, ah_.y, al_.y);
            split2(fa[q].z, ah_.z, al_.z);
            split2(fa[q].w, ah_.w, al_.w);
            split2(fb[q].x, bh_.x, bl_.x);
            split2(fb[q].y, bh_.y, bl_.y);
            split2(fb[q].z, bh_.z, bl_.z);
            split2(fb[q].w, bh_.w, bl_.w);
            *(ushort4*)(&Ah[row][cg*4]) = ah_;
            *(ushort4*)(&Al[row][cg*4]) = al_;
            *(ushort4*)(&Bh[row][cg*4]) = bh_;
            *(ushort4*)(&Bl[row][cg*4]) = bl_;
        }
        __syncthreads();
        f16x8 ah[4], al[4], bh[4], bl[4];
        #pragma unroll
        for (int mi = 0; mi < 4; ++mi) {
            ah[mi] = *(const f16x8*)(&Ah[wm + mi*16 + l15][lk8]);
            al[mi] = *(const f16x8*)(&Al[wm + mi*16 + l15][lk8]);
        }
        #pragma unroll
        for (int nj = 0; nj < 4; ++nj) {
            bh[nj] = *(const f16x8*)(&Bh[wn + nj*16 + l15][lk8]);
            bl[nj] = *(const f16x8*)(&Bl[wn + nj*16 + l15][lk8]);
        }
        #pragma unroll
        for (int mi = 0; mi < 4; ++mi)
            #pragma unroll
            for (int nj = 0; nj < 4; ++nj) {
                acc[mi][nj] = __builtin_amdgcn_mfma_f32_16x16x32_f16(ah[mi], bh[nj], acc[mi][nj], 0, 0, 0);
                acc[mi][nj] = __builtin_amdgcn_mfma_f32_16x16x32_f16(ah[mi], bl[nj], acc[mi][nj], 0, 0, 0);
                acc[mi][nj] = __builtin_amdgcn_mfma_f32_16x16x32_f16(al[mi], bh[nj], acc[mi][nj], 0, 0, 0);
            }
    }
    #pragma unroll
    for (int mi = 0; mi < 4; ++mi) {
        #pragma unroll
        for (int nj = 0; nj < 4; ++nj) {
            const int col = bn + wn + nj*16 + l15;
            #pragma unroll
            for (int r = 0; r < 4; ++r) {
                const int row = bm + wm + mi*16 + rbase + r;
                float v = acc[mi][nj][r];
                if constexpr (FLAGS & GF_BIAS) v += bias[col];
                if constexpr (FLAGS & GF_POS)  v += pos[(long long)(row & 511)*512 + col];
                if constexpr (FLAGS & GF_ADD)  v += addsrc[(long long)row*ldc + col];
                if constexpr (FLAGS & GF_ACC)  v += C[(long long)row*ldc + col];
                if constexpr (FLAGS & GF_RELU) v = fmaxf(v, 0.0f);
                C[(long long)row*ldc + col] = v;
            }
        }
    }
}

// ---------------- fused attention via f16x3 MFMA (r20 verbatim) --------------
__global__ __launch_bounds__(256)
void attn_mfma_r21(const float* __restrict__ Qbuf, const float* __restrict__ Kbuf,
                   const float* __restrict__ Vbuf, float* __restrict__ att)
{
    __shared__ unsigned short Qh[64][68];
    __shared__ unsigned short Ql[64][68];
    __shared__ unsigned short Kh[64][68];
    __shared__ unsigned short Kl[64][68];
    __shared__ unsigned short Vh[64][68];
    __shared__ unsigned short Vl[64][68];
    const int tid  = threadIdx.x;
    const int lane = tid & 63;
    const int wave = tid >> 6;
    const int l15  = lane & 15;
    const int lq   = lane >> 4;
    const int lq8  = lq * 8;
    const int bid = blockIdx.x;
    const int qt = bid & 7, h = (bid >> 3) & 7, b = bid >> 6;
    const int row0 = b*512 + qt*64;

    #pragma unroll
    for (int u = 0; u < 16; ++u) {
        int e = u*256 + tid;
        int r = e >> 6, c = e & 63;
        float q = Qbuf[(long long)(row0 + r)*512 + h*64 + c] * 0.125f;
        unsigned short hs, ls;
        split2(q, hs, ls);
        Qh[r][c] = hs; Ql[r][c] = ls;
    }

    float m[4], l[4];
    f32x4 accO[4];
    #pragma unroll
    for (int r=0;r<4;r++){ m[r] = -1e30f; l[r] = 0.f; }
    #pragma unroll
    for (int j=0;j<4;j++) accO[j] = (f32x4){0.f,0.f,0.f,0.f};

    for (int kv = 0; kv < 512; kv += 64) {
        __syncthreads();
        #pragma unroll
        for (int u = 0; u < 16; ++u) {
            int e = u*256 + tid;
            int r = e >> 6, c = e & 63;
            float kvf = Kbuf[(long long)(b*512 + kv + r)*512 + h*64 + c];
            float vvf = Vbuf[(long long)(b*512 + kv + r)*512 + h*64 + c];
            unsigned short hs, ls;
            split2(kvf, hs, ls);
            Kh[r][c] = hs; Kl[r][c] = ls;
            split2(vvf, hs, ls);
            Vh[c][r] = hs; Vl[c][r] = ls;
        }
        __syncthreads();
        f32x4 accS[4];
        #pragma unroll
        for (int j=0;j<4;j++) accS[j] = (f32x4){0.f,0.f,0.f,0.f};
        #pragma unroll
        for (int ks = 0; ks < 2; ++ks) {
            f16x8 qh = *(const f16x8*)(&Qh[wave*16 + l15][ks*32 + lq8]);
            f16x8 ql = *(const f16x8*)(&Ql[wave*16 + l15][ks*32 + lq8]);
            #pragma unroll
            for (int nj = 0; nj < 4; ++nj) {
                f16x8 kh = *(const f16x8*)(&Kh[nj*16 + l15][ks*32 + lq8]);
                f16x8 kl = *(const f16x8*)(&Kl[nj*16 + l15][ks*32 + lq8]);
                accS[nj] = __builtin_amdgcn_mfma_f32_16x16x32_f16(qh, kh, accS[nj], 0, 0, 0);
                accS[nj] = __builtin_amdgcn_mfma_f32_16x16x32_f16(qh, kl, accS[nj], 0, 0, 0);
                accS[nj] = __builtin_amdgcn_mfma_f32_16x16x32_f16(ql, kh, accS[nj], 0, 0, 0);
            }
        }
        #pragma unroll
        for (int r = 0; r < 4; ++r) {
            float tm = fmaxf(fmaxf(accS[0][r], accS[1][r]), fmaxf(accS[2][r], accS[3][r]));
            #pragma unroll
            for (int msk = 1; msk < 16; msk <<= 1) tm = fmaxf(tm, __shfl_xor(tm, msk, 64));
            float mn = fmaxf(m[r], tm);
            float scale = expf(m[r] - mn);
            float rs = 0.f;
            #pragma unroll
            for (int nj = 0; nj < 4; ++nj) {
                float p = expf(accS[nj][r] - mn);
                accS[nj][r] = p;
                rs += p;
            }
            #pragma unroll
            for (int msk = 1; msk < 16; msk <<= 1) rs += __shfl_xor(rs, msk, 64);
            l[r] = l[r]*scale + rs;
            m[r] = mn;
            #pragma unroll
            for (int nj = 0; nj < 4; ++nj) accO[nj][r] *= scale;
        }
        __syncthreads();
        #pragma unroll
        for (int r = 0; r < 4; ++r)
            #pragma unroll
            for (int nj = 0; nj < 4; ++nj) {
                unsigned short hs, ls;
                split2(accS[nj][r], hs, ls);
                Kh[wave*16 + lq*4 + r][nj*16 + l15] = hs;
                Kl[wave*16 + lq*4 + r][nj*16 + l15] = ls;
            }
        __syncthreads();
        #pragma unroll
        for (int ks = 0; ks < 2; ++ks) {
            f16x8 ph = *(const f16x8*)(&Kh[wave*16 + l15][ks*32 + lq8]);
            f16x8 pl = *(const f16x8*)(&Kl[wave*16 + l15][ks*32 + lq8]);
            #pragma unroll
            for (int nj = 0; nj < 4; ++nj) {
                f16x8 vh = *(const f16x8*)(&Vh[nj*16 + l15][ks*32 + lq8]);
                f16x8 vl = *(const f16x8*)(&Vl[nj*16 + l15][ks*32 + lq8]);
                accO[nj] = __builtin_amdgcn_mfma_f32_16x16x32_f16(ph, vh, accO[nj], 0, 0, 0);
                accO[nj] = __builtin_amdgcn_mfma_f32_16x16x32_f16(ph, vl, accO[nj], 0, 0, 0);
                accO[nj] = __builtin_amdgcn_mfma_f32_16x16x32_f16(pl, vh, accO[nj], 0, 0, 0);
            }
        }
    }
    #pragma unroll
    for (int nj = 0; nj < 4; ++nj)
        #pragma unroll
        for (int r = 0; r < 4; ++r) {
            const int row = row0 + wave*16 + lq*4 + r;
            att[(long long)row*512 + h*64 + nj*16 + l15] = accO[nj][r] / l[r];
        }
}

// ---------------- row sum of squares (f64) -----------------------------------
__global__ __launch_bounds__(256)
void row_sumsq_r21(const float* __restrict__ X, double* __restrict__ outp)
{
    const int row  = blockIdx.x*4 + (threadIdx.x >> 6);
    const int lane = threadIdx.x & 63;
    double s = 0.0;
    #pragma unroll
    for (int u = 0; u < 8; ++u) {
        float v = X[(long long)row*512 + lane + u*64];
        s += (double)v * (double)v;
    }
    #pragma unroll
    for (int msk = 32; msk; msk >>= 1) s += __shfl_xor(s, msk, 64);
    if (lane == 0) outp[row] = s;
}

// ---------------- VQ argmin: pre-split inputs, pure bit-unpack staging -------
__global__ __launch_bounds__(256)
void vq_argmin_mfma_r21(const unsigned int* __restrict__ enchl,
                        const unsigned int* __restrict__ cbhl,
                        const double* __restrict__ Asum, const double* __restrict__ cbB,
                        float* __restrict__ pbv, int* __restrict__ pbi)
{
    __shared__ unsigned int smem[10240];   // 40960 B
    unsigned short* AhP = (unsigned short*)smem;           // [128][40]
    unsigned short* AlP = AhP + 128*40;
    unsigned short* BhP = AlP + 128*40;
    unsigned short* BlP = BhP + 128*40;
    float* bvsP = (float*)smem;                            // [128][32]
    int*   bisP = (int*)(smem + 4096);

    const int tid  = threadIdx.x;
    const int lane = tid & 63;
    const int wave = tid >> 6;
    const int wm = (wave >> 1) * 64, wn = (wave & 1) * 64;
    const int bm = blockIdx.x * 128;
    const int l15 = lane & 15;
    const int lk8 = (lane >> 4) * 8;
    const int rbase = (lane >> 4) * 4;
    const int cg   = tid & 7;
    const int rw0  = tid >> 3;

    float bestv[16]; int besti[16];
    #pragma unroll
    for (int g = 0; g < 16; ++g) { bestv[g] = 3.0e38f; besti[g] = 2048; }

    for (int nb = 0; nb < 4; ++nb) {
        const int ct0 = blockIdx.y * 512 + nb * 128;
        f32x4 acc[4][4];
        #pragma unroll
        for (int i=0;i<4;i++)
            #pragma unroll
            for (int j=0;j<4;j++)
                acc[i][j] = (f32x4){0.f,0.f,0.f,0.f};

        for (int k0 = 0; k0 < 512; k0 += 32) {
            uint4 va[4], vb[4];
            #pragma unroll
            for (int q = 0; q < 4; ++q) {
                const int row = rw0 + q*32;
                va[q] = *(const uint4*)(enchl + (long long)(bm + row)*512 + k0 + cg*4);
                vb[q] = *(const uint4*)(cbhl  + (long long)(ct0 + row)*512 + k0 + cg*4);
            }
            __syncthreads();
            #pragma unroll
            for (int q = 0; q < 4; ++q) {
                const int row = rw0 + q*32;
                AhP[row*40 + cg*4+0] = (unsigned short)(va[q].x & 0xffff);
                AhP[row*40 + cg*4+1] = (unsigned short)(va[q].y & 0xffff);
                AhP[row*40 + cg*4+2] = (unsigned short)(va[q].z & 0xffff);
                AhP[row*40 + cg*4+3] = (unsigned short)(va[q].w & 0xffff);
                AlP[row*40 + cg*4+0] = (unsigned short)(va[q].x >> 16);
                AlP[row*40 + cg*4+1] = (unsigned short)(va[q].y >> 16);
                AlP[row*40 + cg*4+2] = (unsigned short)(va[q].z >> 16);
                AlP[row*40 + cg*4+3] = (unsigned short)(va[q].w >> 16);
                BhP[row*40 + cg*4+0] = (unsigned short)(vb[q].x & 0xffff);
                BhP[row*40 + cg*4+1] = (unsigned short)(vb[q].y & 0xffff);
                BhP[row*40 + cg*4+2] = (unsigned short)(vb[q].z & 0xffff);
                BhP[row*40 + cg*4+3] = (unsigned short)(vb[q].w & 0xffff);
                BlP[row*40 + cg*4+0] = (unsigned short)(vb[q].x >> 16);
                BlP[row*40 + cg*4+1] = (unsigned short)(vb[q].y >> 16);
                BlP[row*40 + cg*4+2] = (unsigned short)(vb[q].z >> 16);
                BlP[row*40 + cg*4+3] = (unsigned short)(vb[q].w >> 16);
            }
            __syncthreads();
            f16x8 ah[4], al[4], bh[4], bl[4];
            #pragma unroll
            for (int mi = 0; mi < 4; ++mi) {
                ah[mi] = *(const f16x8*)(&AhP[(wm + mi*16 + l15)*40 + lk8]);
                al[mi] = *(const f16x8*)(&AlP[(wm + mi*16 + l15)*40 + lk8]);
            }
            #pragma unroll
            for (int nj = 0; nj < 4; ++nj) {
                bh[nj] = *(const f16x8*)(&BhP[(wn + nj*16 + l15)*40 + lk8]);
                bl[nj] = *(const f16x8*)(&BlP[(wn + nj*16 + l15)*40 + lk8]);
            }
            #pragma unroll
            for (int mi = 0; mi < 4; ++mi)
                #pragma unroll
                for (int nj = 0; nj < 4; ++nj) {
                    acc[mi][nj] = __builtin_amdgcn_mfma_f32_16x16x32_f16(ah[mi], bh[nj], acc[mi][nj], 0, 0, 0);
                    acc[mi][nj] = __builtin_amdgcn_mfma_f32_16x16x32_f16(ah[mi], bl[nj], acc[mi][nj], 0, 0, 0);
                    acc[mi][nj] = __builtin_amdgcn_mfma_f32_16x16x32_f16(al[mi], bh[nj], acc[mi][nj], 0, 0, 0);
                }
        }
        #pragma unroll
        for (int mi = 0; mi < 4; ++mi) {
            #pragma unroll
            for (int r = 0; r < 4; ++r) {
                const int g = mi*4 + r;
                const float anf = (float)Asum[bm + wm + mi*16 + rbase + r];
                #pragma unroll
                for (int nj = 0; nj < 4; ++nj) {
                    const int col = ct0 + wn + nj*16 + l15;
                    const float bf = (float)cbB[col];
                    const float s1 = anf + bf;
                    const float dot = acc[mi][nj][r] * (1.0f/2048.0f);
                    const float df  = 2.0f * dot;
                    const float qd  = s1 - df;
                    if (qd < bestv[g] || (qd == bestv[g] && col < besti[g])) {
                        bestv[g] = qd; besti[g] = col;
                    }
                }
            }
        }
    }
    __syncthreads();
    #pragma unroll
    for (int mi = 0; mi < 4; ++mi)
        #pragma unroll
        for (int r = 0; r < 4; ++r) {
            const int row  = wm + mi*16 + rbase + r;
            const int slot = (wave & 1)*16 + l15;
            bvsP[row*32 + slot] = bestv[mi*4 + r];
            bisP[row*32 + slot] = besti[mi*4 + r];
        }
    __syncthreads();
    if (tid < 128) {
        float bv = bvsP[tid*32]; int bi = bisP[tid*32];
        #pragma unroll
        for (int s = 1; s < 32; ++s) {
            float v = bvsP[tid*32 + s]; int ii = bisP[tid*32 + s];
            if (v < bv || (v == bv && ii < bi)) { bv = v; bi = ii; }
        }
        pbv[(long long)blockIdx.y*16384 + bm + tid] = bv;
        pbi[(long long)blockIdx.y*16384 + bm + tid] = bi;
    }
}

// vq_reduce also writes the idx output
__global__ __launch_bounds__(256)
void vq_reduce_r21(const float* __restrict__ pbv, const int* __restrict__ pbi,
                   int* __restrict__ idxout, float* __restrict__ out)
{
    int n = blockIdx.x*256 + threadIdx.x;
    if (n >= 16384) return;
    float bv = pbv[n]; int bi = pbi[n];
    #pragma unroll
    for (int q = 1; q < 4; ++q) {
        float v = pbv[q*16384 + n]; int ii = pbi[q*16384 + n];
        if (v < bv || (v == bv && ii < bi)) { bv = v; bi = ii; }
    }
    int ci = bi & 2047;
    idxout[n] = ci;
    out[O_IDX + n] = (float)ci;
}

// ---------------- vq loss (enc reconstructed from packed) --------------------
__global__ __launch_bounds__(256)
void vq_loss_partial_r21(const unsigned int* __restrict__ enchl,
                         const float* __restrict__ cb,
                         const int* __restrict__ idxp, double* __restrict__ part)
{
    __shared__ double red[4];
    const int row  = blockIdx.x*4 + (threadIdx.x >> 6);
    const int lane = threadIdx.x & 63;
    const int ci = idxp[row] & 2047;
    double s = 0.0;
    #pragma unroll
    for (int u = 0; u < 8; ++u) {
        int d = lane + u*64;
        float e = unpack_sum(enchl[(long long)row*512 + d]);
        double dv = (double)cb[(long long)ci*512 + d] - (double)e;
        s += dv * dv;
    }
    #pragma unroll
    for (int msk = 32; msk; msk >>= 1) s += __shfl_xor(s, msk, 64);
    if (lane == 0) red[threadIdx.x >> 6] = s;
    __syncthreads();
    if (threadIdx.x == 0)
        part[blockIdx.x] = red[0] + red[1] + red[2] + red[3];
}

// ---------------- regime f32 GEMM (small) ------------------------------------
template<int FLAGS>
__global__ __launch_bounds__(256)
void gemm_bt_r21(const float* __restrict__ A, const float* __restrict__ Bm,
                 const float* __restrict__ bias, const float* __restrict__ pos,
                 const float* __restrict__ addsrc, float* __restrict__ C,
                 int Kdim, int lda, int ldb, int ldc)
{
    __shared__ float As[16][132];
    __shared__ float Bs[16][132];
    const int tid = threadIdx.x;
    const int tx = tid & 15, ty = tid >> 4;
    const int bm = blockIdx.x * 128, bn = blockIdx.y * 128;
    const int r0 = tid >> 2;
    const int kg = (tid & 3) << 2;
    const float* Arow0 = A  + (long long)(bm + r0) * lda + kg;
    const float* Arow1 = A  + (long long)(bm + r0 + 64) * lda + kg;
    const float* Brow0 = Bm + (long long)(bn + r0) * ldb + kg;
    const float* Brow1 = Bm + (long long)(bn + r0 + 64) * ldb + kg;

    float acc[8][8] = {};
    for (int k0 = 0; k0 < Kdim; k0 += 16) {
        float4 a0 = *(const float4*)(Arow0 + k0);
        float4 a1 = *(const float4*)(Arow1 + k0);
        float4 b0 = *(const float4*)(Brow0 + k0);
        float4 b1 = *(const float4*)(Brow1 + k0);
        __syncthreads();
        As[kg+0][r0]=a0.x; As[kg+1][r0]=a0.y; As[kg+2][r0]=a0.z; As[kg+3][r0]=a0.w;
        As[kg+0][r0+64]=a1.x; As[kg+1][r0+64]=a1.y; As[kg+2][r0+64]=a1.z; As[kg+3][r0+64]=a1.w;
        Bs[kg+0][r0]=b0.x; Bs[kg+1][r0]=b0.y; Bs[kg+2][r0]=b0.z; Bs[kg+3][r0]=b0.w;
        Bs[kg+0][r0+64]=b1.x; Bs[kg+1][r0+64]=b1.y; Bs[kg+2][r0+64]=b1.z; Bs[kg+3][r0+64]=b1.w;
        __syncthreads();
        #pragma unroll
        for (int kk = 0; kk < 16; ++kk) {
            float a[8], b[8];
            #pragma unroll
            for (int i=0;i<8;i++) a[i] = As[kk][ty*8+i];
            #pragma unroll
            for (int j=0;j<4;j++) b[j]   = Bs[kk][tx*4+j];
            #pragma unroll
            for (int j=0;j<4;j++) b[4+j] = Bs[kk][64+tx*4+j];
            #pragma unroll
            for (int i=0;i<8;i++)
                #pragma unroll
                for (int j=0;j<8;j++)
                    acc[i][j] = fmaf(a[i], b[j], acc[i][j]);
        }
    }
    #pragma unroll
    for (int i=0;i<8;i++){
        const int row = bm + ty*8 + i;
        #pragma unroll
        for (int j=0;j<8;j++){
            const int col = bn + ((j < 4) ? (tx*4 + j) : (64 + tx*4 + (j-4)));
            float v = acc[i][j];
            if constexpr (FLAGS & GF_BIAS) v += bias[col];
            if constexpr (FLAGS & GF_POS)  v += pos[(long long)(row & 511)*512 + col];
            if constexpr (FLAGS & GF_ADD)  v += addsrc[(long long)row*ldc + col];
            if constexpr (FLAGS & GF_ACC)  v += C[(long long)row*ldc + col];
            if constexpr (FLAGS & GF_RELU) v = fmaxf(v, 0.0f);
            C[(long long)row*ldc + col] = v;
        }
    }
}

// ---------------- regime softmax ---------------------------------------------
__global__ __launch_bounds__(256)
void softmax_rows_r21(float* __restrict__ R)
{
    const int row = blockIdx.x;
    const int tid = threadIdx.x;
    __shared__ float  redf[256];
    __shared__ double redd[256];
    float* p = R + (long long)row * 2048;
    float mx = -1e30f;
    for (int c = tid; c < 2048; c += 256) mx = fmaxf(mx, p[c]);
    redf[tid] = mx; __syncthreads();
    for (int s2 = 128; s2; s2 >>= 1) { if (tid < s2) redf[tid] = fmaxf(redf[tid], redf[tid+s2]); __syncthreads(); }
    mx = redf[0];
    double sum = 0.0;
    for (int c = tid; c < 2048; c += 256) { float e = expf(p[c] - mx); p[c] = e; sum += e; }
    redd[tid] = sum; __syncthreads();
    for (int s2 = 128; s2; s2 >>= 1) { if (tid < s2) redd[tid] += redd[tid+s2]; __syncthreads(); }
    double tot = redd[0];
    for (int c = tid; c < 2048; c += 256) p[c] = (float)((double)p[c] / tot);
}

// ---------------- hash table -------------------------------------------------
__global__ __launch_bounds__(256)
void hash_table_r21(const float* __restrict__ cb, const float* __restrict__ hw,
                    float* __restrict__ T)
{
    const int k = blockIdx.x*4 + (threadIdx.x >> 6);
    const int j = threadIdx.x & 63;
    double s = 0.0;
    for (int d = 0; d < 512; ++d)
        s += (double)cb[(long long)k*512 + d] * (double)hw[(long long)j*512 + d];
    T[(long long)k*64 + j] = (s > 0.0) ? 1.0f : 0.0f;
}

// ---------------- output writers ---------------------------------------------
__global__ void write_loss_r21(const double* __restrict__ part,
                               float* __restrict__ out)
{
    __shared__ double red[256];
    double s = 0.0;
    for (int i = threadIdx.x; i < 4096; i += 256) s += part[i];
    red[threadIdx.x] = s; __syncthreads();
    for (int s2 = 128; s2; s2 >>= 1) {
        if (threadIdx.x < s2) red[threadIdx.x] += red[threadIdx.x + s2];
        __syncthreads();
    }
    if (threadIdx.x == 0)
        out[O_LOSS] = (float)(1.25 * red[0] / 8388608.0);
}

__global__ __launch_bounds__(256)
void write_regime_r21(const float* __restrict__ R, const int* __restrict__ idxp,
                      float* __restrict__ out)
{
    long long i = (long long)blockIdx.x*256 + threadIdx.x;
    if (i >= 33554432LL) return;
    int n = (int)(i >> 11), c = (int)(i & 2047);
    int ci = idxp[n] & 2047;
    out[O_REG + i] = R[(long long)ci*2048 + c];
}

__global__ __launch_bounds__(256)
void write_hash_r21(const float* __restrict__ T, const int* __restrict__ idxp,
                    float* __restrict__ out)
{
    long long i = (long long)blockIdx.x*256 + threadIdx.x;
    if (i >= 1048576LL) return;
    int n = (int)(i >> 6), j = (int)(i & 63);
    int ci = idxp[n] & 2047;
    out[O_HASH + i] = T[(long long)ci*64 + j];
}

__global__ __launch_bounds__(256)
void write_quant_r21(const float* __restrict__ cb, const int* __restrict__ idxp,
                     float* __restrict__ out)
{
    long long i = (long long)blockIdx.x*256 + threadIdx.x;
    if (i >= 8388608LL) return;
    int n = (int)(i >> 9), d = (int)(i & 511);
    int ci = idxp[n] & 2047;
    out[O_QUANT + i] = cb[(long long)ci*512 + d];
}

// ---------------- launcher ----------------------------------------------------
extern "C" void kernel_launch(void* const* d_in, const int* in_sizes, int n_in,
                              void* d_out, int out_size, void* d_ws, size_t ws_size,
                              hipStream_t stream)
{
    (void)in_sizes; (void)n_in; (void)out_size;
    const float* market = (const float*)d_in[0];
    const float* W_in   = (const float*)d_in[1];
    const float* b_in   = (const float*)d_in[2];
    const float* pos    = (const float*)d_in[3];
    const float* c3w = (const float*)d_in[4];  const float* c3b = (const float*)d_in[5];
    const float* c5w = (const float*)d_in[6];  const float* c5b = (const float*)d_in[7];
    const float* c7w = (const float*)d_in[8];  const float* c7b = (const float*)d_in[9];
    const float* c9w = (const float*)d_in[10]; const float* c9b = (const float*)d_in[11];
    const float* msw = (const float*)d_in[12]; const float* msb = (const float*)d_in[13];
    const float* inw = (const float*)d_in[14]; const float* inb = (const float*)d_in[15];
    const float* aow = (const float*)d_in[16]; const float* aob = (const float*)d_in[17];
    const float* cb  = (const float*)d_in[18]; const float* hw  = (const float*)d_in[19];
    const float* r1w = (const float*)d_in[20]; const float* r1b = (const float*)d_in[21];
    const float* r2w = (const float*)d_in[22]; const float* r2b = (const float*)d_in[23];

    if (ws_size < (size_t)W_END * sizeof(float)) return;

    float* ws    = (float*)d_ws;
    float* xp    = ws + W_XP;
    float* convt = ws + W_CT;
    float* projp = ws + W_PROJ;
    unsigned int* wt3 = (unsigned int*)(ws + W_VW);
    unsigned int* wt5 = wt3 + 512*512*3;
    unsigned int* wt7 = wt5 + 512*512*5;
    unsigned int* wt9 = wt7 + 512*512*7;
    float* Vbufp = ws + W_VW;
    float* hregp = ws + W_HREG;
    float* Tp    = ws + W_T;
    int*    idxp  = (int*)(ws + W_IDX);
    double* asump = (double*)(ws + W_ASUM);
    double* cbbp  = (double*)(ws + W_CBB);
    double* lpart = (double*)(ws + W_LPART);
    float*  pbvp  = ws + W_PBV;
    int*    pbip  = (int*)(ws + W_PBI);
    // packed cb lives in the dead proj region, after the R table footprint
    unsigned int* cbhl = (unsigned int*)(ws + W_PROJ + 4194304);

    float* out = (float*)d_out;

    float* Qbufp = xp;
    float* attp  = xp;
    float* Kbufp = convt;
    float* encp  = convt;
    float* Rp    = projp;

    const unsigned int* xpu  = (const unsigned int*)xp;
    const unsigned int* encu = (const unsigned int*)encp;

    conv_w_tr_r21<3><<<3072, 256, 0, stream>>>(c3w, wt3);
    conv_w_tr_r21<5><<<5120, 256, 0, stream>>>(c5w, wt5);
    conv_w_tr_r21<7><<<7168, 256, 0, stream>>>(c7w, wt7);
    conv_w_tr_r21<9><<<9216, 256, 0, stream>>>(c9w, wt9);

    const dim3 gT(128, 4);

    gemm_mfma_r21<GF_BIAS|GF_POS><<<gT, 256, 0, stream>>>(market, W_in, b_in, pos, nullptr, xp, 512, 512, 512, 512);
    split_inplace_r21<<<32768, 256, 0, stream>>>(xp);

    conv_mfma_r21<3><<<gT, 256, 0, stream>>>(xpu, wt3, c3b, convt);
    gemm_mfma_r21<GF_BIAS><<<gT, 256, 0, stream>>>(convt, msw + 0*512, msb, nullptr, nullptr, projp, 512, 512, 2048, 512);
    conv_mfma_r21<5><<<gT, 256, 0, stream>>>(xpu, wt5, c5b, convt);
    gemm_mfma_r21<GF_ACC><<<gT, 256, 0, stream>>>(convt, msw + 1*512, nullptr, nullptr, nullptr, projp, 512, 512, 2048, 512);
    conv_mfma_r21<7><<<gT, 256, 0, stream>>>(xpu, wt7, c7b, convt);
    gemm_mfma_r21<GF_ACC><<<gT, 256, 0, stream>>>(convt, msw + 2*512, nullptr, nullptr, nullptr, projp, 512, 512, 2048, 512);
    conv_mfma_r21<9><<<gT, 256, 0, stream>>>(xpu, wt9, c9b, convt);
    gemm_mfma_r21<GF_ACC><<<gT, 256, 0, stream>>>(convt, msw + 3*512, nullptr, nullptr, nullptr, projp, 512, 512, 2048, 512);

    gemm_mfma_r21<GF_BIAS><<<gT, 256, 0, stream>>>(projp, inw + 512*512,  inb + 512,  nullptr, nullptr, Kbufp, 512, 512, 512, 512);
    gemm_mfma_r21<GF_BIAS><<<gT, 256, 0, stream>>>(projp, inw + 1024*512, inb + 1024, nullptr, nullptr, Vbufp, 512, 512, 512, 512);
    gemm_mfma_r21<GF_BIAS><<<gT, 256, 0, stream>>>(projp, inw,            inb,        nullptr, nullptr, Qbufp, 512, 512, 512, 512);

    attn_mfma_r21<<<2048, 256, 0, stream>>>(Qbufp, Kbufp, Vbufp, attp);

    gemm_mfma_r21<GF_BIAS|GF_ADD><<<gT, 256, 0, stream>>>(attp, aow, aob, nullptr, projp, encp, 512, 512, 512, 512);

    // VQ: sums in f32, then pre-split enc (in place) + cb (scaled) for MFMA
    row_sumsq_r21<<<4096, 256, 0, stream>>>(encp, asump);
    row_sumsq_r21<<<512,  256, 0, stream>>>(cb, cbbp);
    split_inplace_r21<<<32768, 256, 0, stream>>>(encp);
    split_cb_r21<<<4096, 256, 0, stream>>>(cb, cbhl);
    vq_argmin_mfma_r21<<<dim3(128, 4), 256, 0, stream>>>(encu, cbhl, asump, cbbp, pbvp, pbip);
    vq_reduce_r21<<<64, 256, 0, stream>>>(pbvp, pbip, idxp, out);
    vq_loss_partial_r21<<<4096, 256, 0, stream>>>(encu, cb, idxp, lpart);

    // regime tables
    gemm_bt_r21<GF_BIAS|GF_RELU><<<dim3(16, 2),  256, 0, stream>>>(cb, r1w, r1b, nullptr, nullptr, hregp, 512, 512, 512, 256);
    gemm_bt_r21<GF_BIAS><<<dim3(16, 16), 256, 0, stream>>>(hregp, r2w, r2b, nullptr, nullptr, Rp, 256, 256, 256, 2048);
    softmax_rows_r21<<<2048, 256, 0, stream>>>(Rp);
    hash_table_r21<<<512, 256, 0, stream>>>(cb, hw, Tp);

    // outputs
    write_loss_r21<<<1, 256, 0, stream>>>(lpart, out);
    write_regime_r21<<<131072, 256, 0, stream>>>(Rp, idxp, out);
    write_hash_r21<<<4096, 256, 0, stream>>>(Tp, idxp, out);
    write_quant_r21<<<32768, 256, 0, stream>>>(cb, idxp, out);
}

// Round 22
// 1521.152 us; speedup vs baseline: 1.2470x; 1.0219x over previous
//
#include <hip/hip_runtime.h>
#include <hip/hip_bf16.h>

// ---------------- problem constants ----------------
// B=32, S=512, D=512, K=2048; N = B*S = 16384. d_out is FLOAT32.
// r22: FULL PACKED FLOW. All GEMM/conv/attn operands are packed (hi,lo) f16
// pairs in u32 (pre-split weights + packed intermediates); staging is pure
// bit-unpack (no in-kernel split2 except attention's P tile).
// Intermediate storage rounds to ~22-bit mantissa = proven-safe noise class.
// VQ argmin (f64-free absorbed compare + first-index ties) r21-verbatim.

#define GF_BIAS 1
#define GF_RELU 2
#define GF_ADDP 4
#define GF_POS  8
#define GF_ACCP 16
#define GF_QSCALE 32

typedef _Float16 f16x8 __attribute__((ext_vector_type(8)));
typedef float    f32x4 __attribute__((ext_vector_type(4)));

static constexpr long long O_QUANT = 0LL;
static constexpr long long O_LOSS  = 8388608LL;
static constexpr long long O_IDX   = 8388609LL;
static constexpr long long O_HASH  = 8404993LL;
static constexpr long long O_REG   = 9453569LL;
static constexpr long long O_END   = 43008001LL;

static constexpr long long W_XP    = 0LL;         // xp.hl -> Q.hl -> att.hl
static constexpr long long W_CT    = 8388608LL;   // mk.hl -> convt.hl -> K.hl -> enc.hl
static constexpr long long W_PROJ  = 16777216LL;  // proj.hl -> R | cbhl at +4194304
static constexpr long long W_VW    = 25165824LL;  // conv wt + msw/Win/inwq/inwk .hl -> V.hl
static constexpr long long W_HREG  = 33554432LL;  // inwv.hl + aow.hl -> hreg
static constexpr long long W_T     = 34078720LL;
static constexpr long long W_IDX   = 34209792LL;
static constexpr long long W_ASUM  = 34226176LL;
static constexpr long long W_CBB   = 34258944LL;
static constexpr long long W_LPART = 34263040LL;
static constexpr long long W_PBV   = 34271232LL;
static constexpr long long W_PBI   = 34336768LL;
static constexpr long long W_END   = 34402304LL;

__device__ __forceinline__ unsigned int pack_hl(float x)
{
    _Float16 h = (_Float16)x;
    float hf = (float)h;
    _Float16 l = (_Float16)(x - hf);
    unsigned short hb = __builtin_bit_cast(unsigned short, h);
    unsigned short lb = __builtin_bit_cast(unsigned short, l);
    return (unsigned int)hb | ((unsigned int)lb << 16);
}

__device__ __forceinline__ void split2(float x, unsigned short& h, unsigned short& l)
{
    _Float16 hf = (_Float16)x;
    _Float16 lf = (_Float16)(x - (float)hf);
    h = __builtin_bit_cast(unsigned short, hf);
    l = __builtin_bit_cast(unsigned short, lf);
}

__device__ __forceinline__ float unpack_sum(unsigned int u)
{
    _Float16 h = __builtin_bit_cast(_Float16, (unsigned short)(u & 0xffff));
    _Float16 l = __builtin_bit_cast(_Float16, (unsigned short)(u >> 16));
    return (float)h + (float)l;
}

// ---------------- generic split: f32 -> packed (hi,lo) ----------------------
__global__ __launch_bounds__(256)
void split_hl_r22(const float* __restrict__ src, unsigned int* __restrict__ dst)
{
    long long i = (long long)blockIdx.x*256 + threadIdx.x;
    dst[i] = pack_hl(src[i]);
}

__global__ __launch_bounds__(256)
void split_cb_r22(const float* __restrict__ cb, unsigned int* __restrict__ cbhl)
{
    long long i = (long long)blockIdx.x*256 + threadIdx.x;
    cbhl[i] = pack_hl(cb[i] * 2048.0f);
}

template<int KT>
__global__ __launch_bounds__(256)
void conv_w_tr_r22(const float* __restrict__ w, unsigned int* __restrict__ wt)
{
    long long i = (long long)blockIdx.x*256 + threadIdx.x;
    int o  = (int)(i / (512*KT));
    int rem= (int)(i % (512*KT));
    int t  = rem >> 9;
    int ii = rem & 511;
    wt[i] = pack_hl(w[(long long)o*512*KT + (long long)ii*KT + t]);
}

// ---------------- conv via f16x3 MFMA (r21 structure, packed output) ---------
template<int KT>
__global__ __launch_bounds__(256)
void conv_mfma_r22(const unsigned int* __restrict__ xphl,
                   const unsigned int* __restrict__ wthl,
                   const float* __restrict__ bias, unsigned int* __restrict__ outp)
{
    constexpr int PAD = KT / 2;
    __shared__ unsigned short Ah[136][40];
    __shared__ unsigned short Al[136][40];
    __shared__ unsigned short Bh[128][40];
    __shared__ unsigned short Bl[128][40];
    const int tid  = threadIdx.x;
    const int lane = tid & 63;
    const int wave = tid >> 6;
    const int wm = (wave >> 1) * 64, wn = (wave & 1) * 64;
    const int bm = blockIdx.x * 128, bn = blockIdx.y * 128;
    const int l15 = lane & 15;
    const int lk8 = (lane >> 4) * 8;
    const int rbase = (lane >> 4) * 4;
    const int sb = bm & 511;
    const int brow0 = tid >> 3, bc = tid & 7;

    f32x4 acc[4][4];
    #pragma unroll
    for (int i=0;i<4;i++)
        #pragma unroll
        for (int j=0;j<4;j++)
            acc[i][j] = (f32x4){0.f,0.f,0.f,0.f};

    for (int i0 = 0; i0 < 512; i0 += 32) {
        __syncthreads();
        for (int sl = tid; sl < 136*8; sl += 256) {
            const int row = sl >> 3, c = sl & 7;
            const int srow = sb + row - 4;
            uint4 v = make_uint4(0u,0u,0u,0u);
            if (srow >= 0 && srow < 512)
                v = *(const uint4*)(xphl + (long long)(bm + row - 4)*512 + i0 + c*4);
            Ah[row][c*4+0] = (unsigned short)(v.x & 0xffff);
            Ah[row][c*4+1] = (unsigned short)(v.y & 0xffff);
            Ah[row][c*4+2] = (unsigned short)(v.z & 0xffff);
            Ah[row][c*4+3] = (unsigned short)(v.w & 0xffff);
            Al[row][c*4+0] = (unsigned short)(v.x >> 16);
            Al[row][c*4+1] = (unsigned short)(v.y >> 16);
            Al[row][c*4+2] = (unsigned short)(v.z >> 16);
            Al[row][c*4+3] = (unsigned short)(v.w >> 16);
        }
        uint4 vb[4];
        #pragma unroll
        for (int q = 0; q < 4; ++q) {
            const int row = brow0 + q*32;
            vb[q] = *(const uint4*)(wthl + (long long)(bn + row)*(KT*512) + 0*512 + i0 + bc*4);
        }
        for (int t = 0; t < KT; ++t) {
            #pragma unroll
            for (int q = 0; q < 4; ++q) {
                const int row = brow0 + q*32;
                Bh[row][bc*4+0] = (unsigned short)(vb[q].x & 0xffff);
                Bh[row][bc*4+1] = (unsigned short)(vb[q].y & 0xffff);
                Bh[row][bc*4+2] = (unsigned short)(vb[q].z & 0xffff);
                Bh[row][bc*4+3] = (unsigned short)(vb[q].w & 0xffff);
                Bl[row][bc*4+0] = (unsigned short)(vb[q].x >> 16);
                Bl[row][bc*4+1] = (unsigned short)(vb[q].y >> 16);
                Bl[row][bc*4+2] = (unsigned short)(vb[q].z >> 16);
                Bl[row][bc*4+3] = (unsigned short)(vb[q].w >> 16);
            }
            if (t + 1 < KT) {
                #pragma unroll
                for (int q = 0; q < 4; ++q) {
                    const int row = brow0 + q*32;
                    vb[q] = *(const uint4*)(wthl + (long long)(bn + row)*(KT*512) + (t+1)*512 + i0 + bc*4);
                }
            }
            __syncthreads();
            const int tofs = t - PAD + 4;
            f16x8 ah[4], al[4], bh[4], bl[4];
            #pragma unroll
            for (int mi = 0; mi < 4; ++mi) {
                ah[mi] = *(const f16x8*)(&Ah[wm + mi*16 + l15 + tofs][lk8]);
                al[mi] = *(const f16x8*)(&Al[wm + mi*16 + l15 + tofs][lk8]);
            }
            #pragma unroll
            for (int nj = 0; nj < 4; ++nj) {
                bh[nj] = *(const f16x8*)(&Bh[wn + nj*16 + l15][lk8]);
                bl[nj] = *(const f16x8*)(&Bl[wn + nj*16 + l15][lk8]);
            }
            #pragma unroll
            for (int mi = 0; mi < 4; ++mi)
                #pragma unroll
                for (int nj = 0; nj < 4; ++nj) {
                    acc[mi][nj] = __builtin_amdgcn_mfma_f32_16x16x32_f16(ah[mi], bh[nj], acc[mi][nj], 0, 0, 0);
                    acc[mi][nj] = __builtin_amdgcn_mfma_f32_16x16x32_f16(ah[mi], bl[nj], acc[mi][nj], 0, 0, 0);
                    acc[mi][nj] = __builtin_amdgcn_mfma_f32_16x16x32_f16(al[mi], bh[nj], acc[mi][nj], 0, 0, 0);
                }
            if (t + 1 < KT) __syncthreads();
        }
    }
    #pragma unroll
    for (int mi = 0; mi < 4; ++mi) {
        #pragma unroll
        for (int nj = 0; nj < 4; ++nj) {
            const int col = bn + wn + nj*16 + l15;
            const float bcol = bias[col];
            #pragma unroll
            for (int r = 0; r < 4; ++r) {
                const int row = bm + wm + mi*16 + rbase + r;
                float v = acc[mi][nj][r] + bcol;
                outp[(long long)row*512 + col] = pack_hl(fmaxf(v, 0.0f));
            }
        }
    }
}

// ---------------- packed GEMM: A.hl x B.hl -> C.hl ---------------------------
template<int FLAGS>
__global__ __launch_bounds__(256)
void gemm_hl_r22(const unsigned int* __restrict__ A, const unsigned int* __restrict__ Bm,
                 const float* __restrict__ bias, const float* __restrict__ pos,
                 const unsigned int* __restrict__ addsrc, unsigned int* __restrict__ C,
                 int Kdim, int lda, int ldb, int ldc)
{
    __shared__ unsigned short Ah[128][40];
    __shared__ unsigned short Al[128][40];
    __shared__ unsigned short Bh[128][40];
    __shared__ unsigned short Bl[128][40];
    const int tid  = threadIdx.x;
    const int lane = tid & 63;
    const int wave = tid >> 6;
    const int wm = (wave >> 1) * 64, wn = (wave & 1) * 64;
    const int bm = blockIdx.x * 128, bn = blockIdx.y * 128;
    const int l15 = lane & 15;
    const int lk8 = (lane >> 4) * 8;
    const int rbase = (lane >> 4) * 4;
    const int cg   = tid & 7;
    const int rw0  = tid >> 3;

    f32x4 acc[4][4];
    #pragma unroll
    for (int i=0;i<4;i++)
        #pragma unroll
        for (int j=0;j<4;j++)
            acc[i][j] = (f32x4){0.f,0.f,0.f,0.f};

    for (int k0 = 0; k0 < Kdim; k0 += 32) {
        uint4 va[4], vb[4];
        #pragma unroll
        for (int q = 0; q < 4; ++q) {
            const int row = rw0 + q*32;
            va[q] = *(const uint4*)(A  + (long long)(bm + row)*lda + k0 + cg*4);
            vb[q] = *(const uint4*)(Bm + (long long)(bn + row)*ldb + k0 + cg*4);
        }
        __syncthreads();
        #pragma unroll
        for (int q = 0; q < 4; ++q) {
            const int row = rw0 + q*32;
            Ah[row][cg*4+0] = (unsigned short)(va[q].x & 0xffff);
            Ah[row][cg*4+1] = (unsigned short)(va[q].y & 0xffff);
            Ah[row][cg*4+2] = (unsigned short)(va[q].z & 0xffff);
            Ah[row][cg*4+3] = (unsigned short)(va[q].w & 0xffff);
            Al[row][cg*4+0] = (unsigned short)(va[q].x >> 16);
            Al[row][cg*4+1] = (unsigned short)(va[q].y >> 16);
            Al[row][cg*4+2] = (unsigned short)(va[q].z >> 16);
            Al[row][cg*4+3] = (unsigned short)(va[q].w >> 16);
            Bh[row][cg*4+0] = (unsigned short)(vb[q].x & 0xffff);
            Bh[row][cg*4+1] = (unsigned short)(vb[q].y & 0xffff);
            Bh[row][cg*4+2] = (unsigned short)(vb[q].z & 0xffff);
            Bh[row][cg*4+3] = (unsigned short)(vb[q].w & 0xffff);
            Bl[row][cg*4+0] = (unsigned short)(vb[q].x >> 16);
            Bl[row][cg*4+1] = (unsigned short)(vb[q].y >> 16);
            Bl[row][cg*4+2] = (unsigned short)(vb[q].z >> 16);
            Bl[row][cg*4+3] = (unsigned short)(vb[q].w >> 16);
        }
        __syncthreads();
        f16x8 ah[4], al[4], bh[4], bl[4];
        #pragma unroll
        for (int mi = 0; mi < 4; ++mi) {
            ah[mi] = *(const f16x8*)(&Ah[wm + mi*16 + l15][lk8]);
            al[mi] = *(const f16x8*)(&Al[wm + mi*16 + l15][lk8]);
        }
        #pragma unroll
        for (int nj = 0; nj < 4; ++nj) {
            bh[nj] = *(const f16x8*)(&Bh[wn + nj*16 + l15][lk8]);
            bl[nj] = *(const f16x8*)(&Bl[wn + nj*16 + l15][lk8]);
        }
        #pragma unroll
        for (int mi = 0; mi < 4; ++mi)
            #pragma unroll
            for (int nj = 0; nj < 4; ++nj) {
                acc[mi][nj] = __builtin_amdgcn_mfma_f32_16x16x32_f16(ah[mi], bh[nj], acc[mi][nj], 0, 0, 0);
                acc[mi][nj] = __builtin_amdgcn_mfma_f32_16x16x32_f16(ah[mi], bl[nj], acc[mi][nj], 0, 0, 0);
                acc[mi][nj] = __builtin_amdgcn_mfma_f32_16x16x32_f16(al[mi], bh[nj], acc[mi][nj], 0, 0, 0);
            }
    }
    #pragma unroll
    for (int mi = 0; mi < 4; ++mi) {
        #pragma unroll
        for (int nj = 0; nj < 4; ++nj) {
            const int col = bn + wn + nj*16 + l15;
            #pragma unroll
            for (int r = 0; r < 4; ++r) {
                const int row = bm + wm + mi*16 + rbase + r;
                float v = acc[mi][nj][r];
                if constexpr (FLAGS & GF_BIAS) v += bias[col];
                if constexpr (FLAGS & GF_POS)  v += pos[(long long)(row & 511)*512 + col];
                if constexpr (FLAGS & GF_ADDP) v += unpack_sum(addsrc[(long long)row*ldc + col]);
                if constexpr (FLAGS & GF_ACCP) v += unpack_sum(C[(long long)row*ldc + col]);
                if constexpr (FLAGS & GF_QSCALE) v *= 0.125f;
                C[(long long)row*ldc + col] = pack_hl(v);
            }
        }
    }
}

// ---------------- fused attention: packed Q/K/V in, packed att out -----------
__global__ __launch_bounds__(256)
void attn_mfma_r22(const unsigned int* __restrict__ Qbuf, const unsigned int* __restrict__ Kbuf,
                   const unsigned int* __restrict__ Vbuf, unsigned int* __restrict__ att)
{
    __shared__ unsigned short Qh[64][68];
    __shared__ unsigned short Ql[64][68];
    __shared__ unsigned short Kh[64][68];
    __shared__ unsigned short Kl[64][68];
    __shared__ unsigned short Vh[64][68];
    __shared__ unsigned short Vl[64][68];
    const int tid  = threadIdx.x;
    const int lane = tid & 63;
    const int wave = tid >> 6;
    const int l15  = lane & 15;
    const int lq   = lane >> 4;
    const int lq8  = lq * 8;
    const int bid = blockIdx.x;
    const int qt = bid & 7, h = (bid >> 3) & 7, b = bid >> 6;
    const int row0 = b*512 + qt*64;

    #pragma unroll
    for (int u = 0; u < 16; ++u) {
        int e = u*256 + tid;
        int r = e >> 6, c = e & 63;
        unsigned int uq = Qbuf[(long long)(row0 + r)*512 + h*64 + c];  // 0.125 pre-applied
        Qh[r][c] = (unsigned short)(uq & 0xffff);
        Ql[r][c] = (unsigned short)(uq >> 16);
    }

    float m[4], l[4];
    f32x4 accO[4];
    #pragma unroll
    for (int r=0;r<4;r++){ m[r] = -1e30f; l[r] = 0.f; }
    #pragma unroll
    for (int j=0;j<4;j++) accO[j] = (f32x4){0.f,0.f,0.f,0.f};

    for (int kv = 0; kv < 512; kv += 64) {
        __syncthreads();
        #pragma unroll
        for (int u = 0; u < 16; ++u) {
            int e = u*256 + tid;
            int r = e >> 6, c = e & 63;
            unsigned int uk = Kbuf[(long long)(b*512 + kv + r)*512 + h*64 + c];
            unsigned int uv = Vbuf[(long long)(b*512 + kv + r)*512 + h*64 + c];
            Kh[r][c] = (unsigned short)(uk & 0xffff);
            Kl[r][c] = (unsigned short)(uk >> 16);
            Vh[c][r] = (unsigned short)(uv & 0xffff);
            Vl[c][r] = (unsigned short)(uv >> 16);
        }
        __syncthreads();
        f32x4 accS[4];
        #pragma unroll
        for (int j=0;j<4;j++) accS[j] = (f32x4){0.f,0.f,0.f,0.f};
        #pragma unroll
        for (int ks = 0; ks < 2; ++ks) {
            f16x8 qh = *(const f16x8*)(&Qh[wave*16 + l15][ks*32 + lq8]);
            f16x8 ql = *(const f16x8*)(&Ql[wave*16 + l15][ks*32 + lq8]);
            #pragma unroll
            for (int nj = 0; nj < 4; ++nj) {
                f16x8 kh = *(const f16x8*)(&Kh[nj*16 + l15][ks*32 + lq8]);
                f16x8 kl = *(const f16x8*)(&Kl[nj*16 + l15][ks*32 + lq8]);
                accS[nj] = __builtin_amdgcn_mfma_f32_16x16x32_f16(qh, kh, accS[nj], 0, 0, 0);
                accS[nj] = __builtin_amdgcn_mfma_f32_16x16x32_f16(qh, kl, accS[nj], 0, 0, 0);
                accS[nj] = __builtin_amdgcn_mfma_f32_16x16x32_f16(ql, kh, accS[nj], 0, 0, 0);
            }
        }
        #pragma unroll
        for (int r = 0; r < 4; ++r) {
            float tm = fmaxf(fmaxf(accS[0][r], accS[1][r]), fmaxf(accS[2][r], accS[3][r]));
            #pragma unroll
            for (int msk = 1; msk < 16; msk <<= 1) tm = fmaxf(tm, __shfl_xor(tm, msk, 64));
            float mn = fmaxf(m[r], tm);
            float scale = expf(m[r] - mn);
            float rs = 0.f;
            #pragma unroll
            for (int nj = 0; nj < 4; ++nj) {
                float p = expf(accS[nj][r] - mn);
                accS[nj][r] = p;
                rs += p;
            }
            #pragma unroll
            for (int msk = 1; msk < 16; msk <<= 1) rs += __shfl_xor(rs, msk, 64);
            l[r] = l[r]*scale + rs;
            m[r] = mn;
            #pragma unroll
            for (int nj = 0; nj < 4; ++nj) accO[nj][r] *= scale;
        }
        __syncthreads();
        #pragma unroll
        for (int r = 0; r < 4; ++r)
            #pragma unroll
            for (int nj = 0; nj < 4; ++nj) {
                unsigned short hs, ls;
                split2(accS[nj][r], hs, ls);
                Kh[wave*16 + lq*4 + r][nj*16 + l15] = hs;
                Kl[wave*16 + lq*4 + r][nj*16 + l15] = ls;
            }
        __syncthreads();
        #pragma unroll
        for (int ks = 0; ks < 2; ++ks) {
            f16x8 ph = *(const f16x8*)(&Kh[wave*16 + l15][ks*32 + lq8]);
            f16x8 pl = *(const f16x8*)(&Kl[wave*16 + l15][ks*32 + lq8]);
            #pragma unroll
            for (int nj = 0; nj < 4; ++nj) {
                f16x8 vh = *(const f16x8*)(&Vh[nj*16 + l15][ks*32 + lq8]);
                f16x8 vl = *(const f16x8*)(&Vl[nj*16 + l15][ks*32 + lq8]);
                accO[nj] = __builtin_amdgcn_mfma_f32_16x16x32_f16(ph, vh, accO[nj], 0, 0, 0);
                accO[nj] = __builtin_amdgcn_mfma_f32_16x16x32_f16(ph, vl, accO[nj], 0, 0, 0);
                accO[nj] = __builtin_amdgcn_mfma_f32_16x16x32_f16(pl, vh, accO[nj], 0, 0, 0);
            }
        }
    }
    #pragma unroll
    for (int nj = 0; nj < 4; ++nj)
        #pragma unroll
        for (int r = 0; r < 4; ++r) {
            const int row = row0 + wave*16 + lq*4 + r;
            att[(long long)row*512 + h*64 + nj*16 + l15] = pack_hl(accO[nj][r] / l[r]);
        }
}

// ---------------- row sum of squares -----------------------------------------
__global__ __launch_bounds__(256)
void row_sumsq_r22(const float* __restrict__ X, double* __restrict__ outp)
{
    const int row  = blockIdx.x*4 + (threadIdx.x >> 6);
    const int lane = threadIdx.x & 63;
    double s = 0.0;
    #pragma unroll
    for (int u = 0; u < 8; ++u) {
        float v = X[(long long)row*512 + lane + u*64];
        s += (double)v * (double)v;
    }
    #pragma unroll
    for (int msk = 32; msk; msk >>= 1) s += __shfl_xor(s, msk, 64);
    if (lane == 0) outp[row] = s;
}

__global__ __launch_bounds__(256)
void row_sumsq_hl_r22(const unsigned int* __restrict__ X, double* __restrict__ outp)
{
    const int row  = blockIdx.x*4 + (threadIdx.x >> 6);
    const int lane = threadIdx.x & 63;
    double s = 0.0;
    #pragma unroll
    for (int u = 0; u < 8; ++u) {
        float v = unpack_sum(X[(long long)row*512 + lane + u*64]);
        s += (double)v * (double)v;
    }
    #pragma unroll
    for (int msk = 32; msk; msk >>= 1) s += __shfl_xor(s, msk, 64);
    if (lane == 0) outp[row] = s;
}

// ---------------- VQ argmin (r21 verbatim) -----------------------------------
__global__ __launch_bounds__(256)
void vq_argmin_mfma_r22(const unsigned int* __restrict__ enchl,
                        const unsigned int* __restrict__ cbhl,
                        const double* __restrict__ Asum, const double* __restrict__ cbB,
                        float* __restrict__ pbv, int* __restrict__ pbi)
{
    __shared__ unsigned int smem[10240];
    unsigned short* AhP = (unsigned short*)smem;
    unsigned short* AlP = AhP + 128*40;
    unsigned short* BhP = AlP + 128*40;
    unsigned short* BlP = BhP + 128*40;
    float* bvsP = (float*)smem;
    int*   bisP = (int*)(smem + 4096);

    const int tid  = threadIdx.x;
    const int lane = tid & 63;
    const int wave = tid >> 6;
    const int wm = (wave >> 1) * 64, wn = (wave & 1) * 64;
    const int bm = blockIdx.x * 128;
    const int l15 = lane & 15;
    const int lk8 = (lane >> 4) * 8;
    const int rbase = (lane >> 4) * 4;
    const int cg   = tid & 7;
    const int rw0  = tid >> 3;

    float bestv[16]; int besti[16];
    #pragma unroll
    for (int g = 0; g < 16; ++g) { bestv[g] = 3.0e38f; besti[g] = 2048; }

    for (int nb = 0; nb < 4; ++nb) {
        const int ct0 = blockIdx.y * 512 + nb * 128;
        f32x4 acc[4][4];
        #pragma unroll
        for (int i=0;i<4;i++)
            #pragma unroll
            for (int j=0;j<4;j++)
                acc[i][j] = (f32x4){0.f,0.f,0.f,0.f};

        for (int k0 = 0; k0 < 512; k0 += 32) {
            uint4 va[4], vb[4];
            #pragma unroll
            for (int q = 0; q < 4; ++q) {
                const int row = rw0 + q*32;
                va[q] = *(const uint4*)(enchl + (long long)(bm + row)*512 + k0 + cg*4);
                vb[q] = *(const uint4*)(cbhl  + (long long)(ct0 + row)*512 + k0 + cg*4);
            }
            __syncthreads();
            #pragma unroll
            for (int q = 0; q < 4; ++q) {
                const int row = rw0 + q*32;
                AhP[row*40 + cg*4+0] = (unsigned short)(va[q].x & 0xffff);
                AhP[row*40 + cg*4+1] = (unsigned short)(va[q].y & 0xffff);
                AhP[row*40 + cg*4+2] = (unsigned short)(va[q].z & 0xffff);
                AhP[row*40 + cg*4+3] = (unsigned short)(va[q].w & 0xffff);
                AlP[row*40 + cg*4+0] = (unsigned short)(va[q].x >> 16);
                AlP[row*40 + cg*4+1] = (unsigned short)(va[q].y >> 16);
                AlP[row*40 + cg*4+2] = (unsigned short)(va[q].z >> 16);
                AlP[row*40 + cg*4+3] = (unsigned short)(va[q].w >> 16);
                BhP[row*40 + cg*4+0] = (unsigned short)(vb[q].x & 0xffff);
                BhP[row*40 + cg*4+1] = (unsigned short)(vb[q].y & 0xffff);
                BhP[row*40 + cg*4+2] = (unsigned short)(vb[q].z & 0xffff);
                BhP[row*40 + cg*4+3] = (unsigned short)(vb[q].w & 0xffff);
                BlP[row*40 + cg*4+0] = (unsigned short)(vb[q].x >> 16);
                BlP[row*40 + cg*4+1] = (unsigned short)(vb[q].y >> 16);
                BlP[row*40 + cg*4+2] = (unsigned short)(vb[q].z >> 16);
                BlP[row*40 + cg*4+3] = (unsigned short)(vb[q].w >> 16);
            }
            __syncthreads();
            f16x8 ah[4], al[4], bh[4], bl[4];
            #pragma unroll
            for (int mi = 0; mi < 4; ++mi) {
                ah[mi] = *(const f16x8*)(&AhP[(wm + mi*16 + l15)*40 + lk8]);
                al[mi] = *(const f16x8*)(&AlP[(wm + mi*16 + l15)*40 + lk8]);
            }
            #pragma unroll
            for (int nj = 0; nj < 4; ++nj) {
                bh[nj] = *(const f16x8*)(&BhP[(wn + nj*16 + l15)*40 + lk8]);
                bl[nj] = *(const f16x8*)(&BlP[(wn + nj*16 + l15)*40 + lk8]);
            }
            #pragma unroll
            for (int mi = 0; mi < 4; ++mi)
                #pragma unroll
                for (int nj = 0; nj < 4; ++nj) {
                    acc[mi][nj] = __builtin_amdgcn_mfma_f32_16x16x32_f16(ah[mi], bh[nj], acc[mi][nj], 0, 0, 0);
                    acc[mi][nj] = __builtin_amdgcn_mfma_f32_16x16x32_f16(ah[mi], bl[nj], acc[mi][nj], 0, 0, 0);
                    acc[mi][nj] = __builtin_amdgcn_mfma_f32_16x16x32_f16(al[mi], bh[nj], acc[mi][nj], 0, 0, 0);
                }
        }
        #pragma unroll
        for (int mi = 0; mi < 4; ++mi) {
            #pragma unroll
            for (int r = 0; r < 4; ++r) {
                const int g = mi*4 + r;
                const float anf = (float)Asum[bm + wm + mi*16 + rbase + r];
                #pragma unroll
                for (int nj = 0; nj < 4; ++nj) {
                    const int col = ct0 + wn + nj*16 + l15;
                    const float bf = (float)cbB[col];
                    const float s1 = anf + bf;
                    const float dot = acc[mi][nj][r] * (1.0f/2048.0f);
                    const float df  = 2.0f * dot;
                    const float qd  = s1 - df;
                    if (qd < bestv[g] || (qd == bestv[g] && col < besti[g])) {
                        bestv[g] = qd; besti[g] = col;
                    }
                }
            }
        }
    }
    __syncthreads();
    #pragma unroll
    for (int mi = 0; mi < 4; ++mi)
        #pragma unroll
        for (int r = 0; r < 4; ++r) {
            const int row  = wm + mi*16 + rbase + r;
            const int slot = (wave & 1)*16 + l15;
            bvsP[row*32 + slot] = bestv[mi*4 + r];
            bisP[row*32 + slot] = besti[mi*4 + r];
        }
    __syncthreads();
    if (tid < 128) {
        float bv = bvsP[tid*32]; int bi = bisP[tid*32];
        #pragma unroll
        for (int s = 1; s < 32; ++s) {
            float v = bvsP[tid*32 + s]; int ii = bisP[tid*32 + s];
            if (v < bv || (v == bv && ii < bi)) { bv = v; bi = ii; }
        }
        pbv[(long long)blockIdx.y*16384 + bm + tid] = bv;
        pbi[(long long)blockIdx.y*16384 + bm + tid] = bi;
    }
}

__global__ __launch_bounds__(256)
void vq_reduce_r22(const float* __restrict__ pbv, const int* __restrict__ pbi,
                   int* __restrict__ idxout, float* __restrict__ out)
{
    int n = blockIdx.x*256 + threadIdx.x;
    if (n >= 16384) return;
    float bv = pbv[n]; int bi = pbi[n];
    #pragma unroll
    for (int q = 1; q < 4; ++q) {
        float v = pbv[q*16384 + n]; int ii = pbi[q*16384 + n];
        if (v < bv || (v == bv && ii < bi)) { bv = v; bi = ii; }
    }
    int ci = bi & 2047;
    idxout[n] = ci;
    out[O_IDX + n] = (float)ci;
}

// ---------------- vq loss (packed enc) ---------------------------------------
__global__ __launch_bounds__(256)
void vq_loss_partial_r22(const unsigned int* __restrict__ enchl,
                         const float* __restrict__ cb,
                         const int* __restrict__ idxp, double* __restrict__ part)
{
    __shared__ double red[4];
    const int row  = blockIdx.x*4 + (threadIdx.x >> 6);
    const int lane = threadIdx.x & 63;
    const int ci = idxp[row] & 2047;
    double s = 0.0;
    #pragma unroll
    for (int u = 0; u < 8; ++u) {
        int d = lane + u*64;
        float e = unpack_sum(enchl[(long long)row*512 + d]);
        double dv = (double)cb[(long long)ci*512 + d] - (double)e;
        s += dv * dv;
    }
    #pragma unroll
    for (int msk = 32; msk; msk >>= 1) s += __shfl_xor(s, msk, 64);
    if (lane == 0) red[threadIdx.x >> 6] = s;
    __syncthreads();
    if (threadIdx.x == 0)
        part[blockIdx.x] = red[0] + red[1] + red[2] + red[3];
}

// ---------------- regime f32 GEMM (small, r21 verbatim) ----------------------
template<int FLAGS>
__global__ __launch_bounds__(256)
void gemm_bt_r22(const float* __restrict__ A, const float* __restrict__ Bm,
                 const float* __restrict__ bias, const float* __restrict__ pos,
                 const float* __restrict__ addsrc, float* __restrict__ C,
                 int Kdim, int lda, int ldb, int ldc)
{
    __shared__ float As[16][132];
    __shared__ float Bs[16][132];
    const int tid = threadIdx.x;
    const int tx = tid & 15, ty = tid >> 4;
    const int bm = blockIdx.x * 128, bn = blockIdx.y * 128;
    const int r0 = tid >> 2;
    const int kg = (tid & 3) << 2;
    const float* Arow0 = A  + (long long)(bm + r0) * lda + kg;
    const float* Arow1 = A  + (long long)(bm + r0 + 64) * lda + kg;
    const float* Brow0 = Bm + (long long)(bn + r0) * ldb + kg;
    const float* Brow1 = Bm + (long long)(bn + r0 + 64) * ldb + kg;

    float acc[8][8] = {};
    for (int k0 = 0; k0 < Kdim; k0 += 16) {
        float4 a0 = *(const float4*)(Arow0 + k0);
        float4 a1 = *(const float4*)(Arow1 + k0);
        float4 b0 = *(const float4*)(Brow0 + k0);
        float4 b1 = *(const float4*)(Brow1 + k0);
        __syncthreads();
        As[kg+0][r0]=a0.x; As[kg+1][r0]=a0.y; As[kg+2][r0]=a0.z; As[kg+3][r0]=a0.w;
        As[kg+0][r0+64]=a1.x; As[kg+1][r0+64]=a1.y; As[kg+2][r0+64]=a1.z; As[kg+3][r0+64]=a1.w;
        Bs[kg+0][r0]=b0.x; Bs[kg+1][r0]=b0.y; Bs[kg+2][r0]=b0.z; Bs[kg+3][r0]=b0.w;
        Bs[kg+0][r0+64]=b1.x; Bs[kg+1][r0+64]=b1.y; Bs[kg+2][r0+64]=b1.z; Bs[kg+3][r0+64]=b1.w;
        __syncthreads();
        #pragma unroll
        for (int kk = 0; kk < 16; ++kk) {
            float a[8], b[8];
            #pragma unroll
            for (int i=0;i<8;i++) a[i] = As[kk][ty*8+i];
            #pragma unroll
            for (int j=0;j<4;j++) b[j]   = Bs[kk][tx*4+j];
            #pragma unroll
            for (int j=0;j<4;j++) b[4+j] = Bs[kk][64+tx*4+j];
            #pragma unroll
            for (int i=0;i<8;i++)
                #pragma unroll
                for (int j=0;j<8;j++)
                    acc[i][j] = fmaf(a[i], b[j], acc[i][j]);
        }
    }
    #pragma unroll
    for (int i=0;i<8;i++){
        const int row = bm + ty*8 + i;
        #pragma unroll
        for (int j=0;j<8;j++){
            const int col = bn + ((j < 4) ? (tx*4 + j) : (64 + tx*4 + (j-4)));
            float v = acc[i][j];
            if constexpr (FLAGS & GF_BIAS) v += bias[col];
            if constexpr (FLAGS & GF_RELU) v = fmaxf(v, 0.0f);
            C[(long long)row*ldc + col] = v;
        }
    }
}

// ---------------- regime softmax ---------------------------------------------
__global__ __launch_bounds__(256)
void softmax_rows_r22(float* __restrict__ R)
{
    const int row = blockIdx.x;
    const int tid = threadIdx.x;
    __shared__ float  redf[256];
    __shared__ double redd[256];
    float* p = R + (long long)row * 2048;
    float mx = -1e30f;
    for (int c = tid; c < 2048; c += 256) mx = fmaxf(mx, p[c]);
    redf[tid] = mx; __syncthreads();
    for (int s2 = 128; s2; s2 >>= 1) { if (tid < s2) redf[tid] = fmaxf(redf[tid], redf[tid+s2]); __syncthreads(); }
    mx = redf[0];
    double sum = 0.0;
    for (int c = tid; c < 2048; c += 256) { float e = expf(p[c] - mx); p[c] = e; sum += e; }
    redd[tid] = sum; __syncthreads();
    for (int s2 = 128; s2; s2 >>= 1) { if (tid < s2) redd[tid] += redd[tid+s2]; __syncthreads(); }
    double tot = redd[0];
    for (int c = tid; c < 2048; c += 256) p[c] = (float)((double)p[c] / tot);
}

// ---------------- hash table -------------------------------------------------
__global__ __launch_bounds__(256)
void hash_table_r22(const float* __restrict__ cb, const float* __restrict__ hw,
                    float* __restrict__ T)
{
    const int k = blockIdx.x*4 + (threadIdx.x >> 6);
    const int j = threadIdx.x & 63;
    double s = 0.0;
    for (int d = 0; d < 512; ++d)
        s += (double)cb[(long long)k*512 + d] * (double)hw[(long long)j*512 + d];
    T[(long long)k*64 + j] = (s > 0.0) ? 1.0f : 0.0f;
}

// ---------------- output writers ---------------------------------------------
__global__ void write_loss_r22(const double* __restrict__ part,
                               float* __restrict__ out)
{
    __shared__ double red[256];
    double s = 0.0;
    for (int i = threadIdx.x; i < 4096; i += 256) s += part[i];
    red[threadIdx.x] = s; __syncthreads();
    for (int s2 = 128; s2; s2 >>= 1) {
        if (threadIdx.x < s2) red[threadIdx.x] += red[threadIdx.x + s2];
        __syncthreads();
    }
    if (threadIdx.x == 0)
        out[O_LOSS] = (float)(1.25 * red[0] / 8388608.0);
}

__global__ __launch_bounds__(256)
void write_regime_r22(const float* __restrict__ R, const int* __restrict__ idxp,
                      float* __restrict__ out)
{
    long long i = (long long)blockIdx.x*256 + threadIdx.x;
    if (i >= 33554432LL) return;
    int n = (int)(i >> 11), c = (int)(i & 2047);
    int ci = idxp[n] & 2047;
    out[O_REG + i] = R[(long long)ci*2048 + c];
}

__global__ __launch_bounds__(256)
void write_hash_r22(const float* __restrict__ T, const int* __restrict__ idxp,
                    float* __restrict__ out)
{
    long long i = (long long)blockIdx.x*256 + threadIdx.x;
    if (i >= 1048576LL) return;
    int n = (int)(i >> 6), j = (int)(i & 63);
    int ci = idxp[n] & 2047;
    out[O_HASH + i] = T[(long long)ci*64 + j];
}

__global__ __launch_bounds__(256)
void write_quant_r22(const float* __restrict__ cb, const int* __restrict__ idxp,
                     float* __restrict__ out)
{
    long long i = (long long)blockIdx.x*256 + threadIdx.x;
    if (i >= 8388608LL) return;
    int n = (int)(i >> 9), d = (int)(i & 511);
    int ci = idxp[n] & 2047;
    out[O_QUANT + i] = cb[(long long)ci*512 + d];
}

// ---------------- launcher ----------------------------------------------------
extern "C" void kernel_launch(void* const* d_in, const int* in_sizes, int n_in,
                              void* d_out, int out_size, void* d_ws, size_t ws_size,
                              hipStream_t stream)
{
    (void)in_sizes; (void)n_in; (void)out_size;
    const float* market = (const float*)d_in[0];
    const float* W_in   = (const float*)d_in[1];
    const float* b_in   = (const float*)d_in[2];
    const float* pos    = (const float*)d_in[3];
    const float* c3w = (const float*)d_in[4];  const float* c3b = (const float*)d_in[5];
    const float* c5w = (const float*)d_in[6];  const float* c5b = (const float*)d_in[7];
    const float* c7w = (const float*)d_in[8];  const float* c7b = (const float*)d_in[9];
    const float* c9w = (const float*)d_in[10]; const float* c9b = (const float*)d_in[11];
    const float* msw = (const float*)d_in[12]; const float* msb = (const float*)d_in[13];
    const float* inw = (const float*)d_in[14]; const float* inb = (const float*)d_in[15];
    const float* aow = (const float*)d_in[16]; const float* aob = (const float*)d_in[17];
    const float* cb  = (const float*)d_in[18]; const float* hw  = (const float*)d_in[19];
    const float* r1w = (const float*)d_in[20]; const float* r1b = (const float*)d_in[21];
    const float* r2w = (const float*)d_in[22]; const float* r2b = (const float*)d_in[23];

    if (ws_size < (size_t)W_END * sizeof(float)) return;

    float* ws = (float*)d_ws;
    // packed pointers
    unsigned int* xphl   = (unsigned int*)(ws + W_XP);      // xp -> Q -> att
    unsigned int* cthl   = (unsigned int*)(ws + W_CT);      // mk -> convt -> K -> enc
    unsigned int* projhl = (unsigned int*)(ws + W_PROJ);
    unsigned int* vwbase = (unsigned int*)(ws + W_VW);
    unsigned int* wt3 = vwbase;                              // 786432
    unsigned int* wt5 = wt3 + 512*512*3;                     // 1310720
    unsigned int* wt7 = wt5 + 512*512*5;                     // 1835008
    unsigned int* wt9 = wt7 + 512*512*7;                     // 2359296 -> end 6291456
    unsigned int* mswhl  = vwbase + 6291456;                 // 1048576
    unsigned int* winhl  = mswhl + 1048576;                  // 262144
    unsigned int* inwqhl = winhl + 262144;                   // 262144
    unsigned int* inwkhl = inwqhl + 262144;                  // 262144 -> end 8126464
    unsigned int* vhl    = vwbase;                           // V output (full region)
    unsigned int* inwvhl = (unsigned int*)(ws + W_HREG);     // 262144
    unsigned int* aowhl  = inwvhl + 262144;                  // 262144
    float* hregp = ws + W_HREG;                              // overwrites later
    float* Tp    = ws + W_T;
    int*    idxp  = (int*)(ws + W_IDX);
    double* asump = (double*)(ws + W_ASUM);
    double* cbbp  = (double*)(ws + W_CBB);
    double* lpart = (double*)(ws + W_LPART);
    float*  pbvp  = ws + W_PBV;
    int*    pbip  = (int*)(ws + W_PBI);
    unsigned int* cbhl = (unsigned int*)(ws + W_PROJ + 4194304);
    float* Rp = ws + W_PROJ;

    float* out = (float*)d_out;

    // ---- pre-split weights + market ----
    conv_w_tr_r22<3><<<3072, 256, 0, stream>>>(c3w, wt3);
    conv_w_tr_r22<5><<<5120, 256, 0, stream>>>(c5w, wt5);
    conv_w_tr_r22<7><<<7168, 256, 0, stream>>>(c7w, wt7);
    conv_w_tr_r22<9><<<9216, 256, 0, stream>>>(c9w, wt9);
    split_hl_r22<<<32768, 256, 0, stream>>>(market, cthl);            // mk.hl in CT
    split_hl_r22<<<1024,  256, 0, stream>>>(W_in, winhl);
    split_hl_r22<<<4096,  256, 0, stream>>>(msw, mswhl);
    split_hl_r22<<<1024,  256, 0, stream>>>(inw,            inwqhl);  // Q rows 0..511
    split_hl_r22<<<1024,  256, 0, stream>>>(inw + 262144,   inwkhl);  // K rows
    split_hl_r22<<<1024,  256, 0, stream>>>(inw + 524288,   inwvhl);  // V rows (HREG)
    split_hl_r22<<<1024,  256, 0, stream>>>(aow, aowhl);

    const dim3 gT(128, 4);

    // xp = market @ W_in^T + b_in + pos  (A=mk.hl in CT, out xp.hl in XP)
    gemm_hl_r22<GF_BIAS|GF_POS><<<gT, 256, 0, stream>>>(cthl, winhl, b_in, pos, nullptr, xphl, 512, 512, 512, 512);

    // convs (A=xp.hl) -> convt.hl in CT (mk dead); ms gemms accumulate proj.hl
    conv_mfma_r22<3><<<gT, 256, 0, stream>>>(xphl, wt3, c3b, cthl);
    gemm_hl_r22<GF_BIAS><<<gT, 256, 0, stream>>>(cthl, mswhl + 0*512, msb, nullptr, nullptr, projhl, 512, 512, 2048, 512);
    conv_mfma_r22<5><<<gT, 256, 0, stream>>>(xphl, wt5, c5b, cthl);
    gemm_hl_r22<GF_ACCP><<<gT, 256, 0, stream>>>(cthl, mswhl + 1*512, nullptr, nullptr, nullptr, projhl, 512, 512, 2048, 512);
    conv_mfma_r22<7><<<gT, 256, 0, stream>>>(xphl, wt7, c7b, cthl);
    gemm_hl_r22<GF_ACCP><<<gT, 256, 0, stream>>>(cthl, mswhl + 2*512, nullptr, nullptr, nullptr, projhl, 512, 512, 2048, 512);
    conv_mfma_r22<9><<<gT, 256, 0, stream>>>(xphl, wt9, c9b, cthl);
    gemm_hl_r22<GF_ACCP><<<gT, 256, 0, stream>>>(cthl, mswhl + 3*512, nullptr, nullptr, nullptr, projhl, 512, 512, 2048, 512);

    // K (out CT over convt), Q (out XP over xp, scaled), then V (out VW, weights
    // there are dead; V's own weights live in HREG -> no read/write hazard)
    gemm_hl_r22<GF_BIAS><<<gT, 256, 0, stream>>>(projhl, inwkhl, inb + 512,  nullptr, nullptr, cthl, 512, 512, 512, 512);
    gemm_hl_r22<GF_BIAS|GF_QSCALE><<<gT, 256, 0, stream>>>(projhl, inwqhl, inb, nullptr, nullptr, xphl, 512, 512, 512, 512);
    gemm_hl_r22<GF_BIAS><<<gT, 256, 0, stream>>>(projhl, inwvhl, inb + 1024, nullptr, nullptr, vhl, 512, 512, 512, 512);

    attn_mfma_r22<<<2048, 256, 0, stream>>>(xphl, cthl, vhl, xphl);

    // enc = proj + att @ aow^T + aob  (A=att.hl, B=aow.hl, ADD=proj.hl, out enc.hl in CT)
    gemm_hl_r22<GF_BIAS|GF_ADDP><<<gT, 256, 0, stream>>>(xphl, aowhl, aob, nullptr, projhl, cthl, 512, 512, 512, 512);

    // VQ
    row_sumsq_hl_r22<<<4096, 256, 0, stream>>>(cthl, asump);
    row_sumsq_r22<<<512,  256, 0, stream>>>(cb, cbbp);
    split_cb_r22<<<4096, 256, 0, stream>>>(cb, cbhl);
    vq_argmin_mfma_r22<<<dim3(128, 4), 256, 0, stream>>>(cthl, cbhl, asump, cbbp, pbvp, pbip);
    vq_reduce_r22<<<64, 256, 0, stream>>>(pbvp, pbip, idxp, out);
    vq_loss_partial_r22<<<4096, 256, 0, stream>>>(cthl, cb, idxp, lpart);

    // regime tables (hreg overwrites dead inwv/aow.hl; R overwrites proj head)
    gemm_bt_r22<GF_BIAS|GF_RELU><<<dim3(16, 2),  256, 0, stream>>>(cb, r1w, r1b, nullptr, nullptr, hregp, 512, 512, 512, 256);
    gemm_bt_r22<GF_BIAS><<<dim3(16, 16), 256, 0, stream>>>(hregp, r2w, r2b, nullptr, nullptr, Rp, 256, 256, 256, 2048);
    softmax_rows_r22<<<2048, 256, 0, stream>>>(Rp);
    hash_table_r22<<<512, 256, 0, stream>>>(cb, hw, Tp);

    // outputs
    write_loss_r22<<<1, 256, 0, stream>>>(lpart, out);
    write_regime_r22<<<131072, 256, 0, stream>>>(Rp, idxp, out);
    write_hash_r22<<<4096, 256, 0, stream>>>(Tp, idxp, out);
    write_quant_r22<<<32768, 256, 0, stream>>>(cb, idxp, out);
}

// Round 23
// 1469.410 us; speedup vs baseline: 1.2909x; 1.0352x over previous
//
#include <hip/hip_runtime.h>
#include <hip/hip_bf16.h>

// ---------------- problem constants ----------------
// B=32, S=512, D=512, K=2048; N = B*S = 16384. d_out is FLOAT32.
// r23 = r22 with reg-double-buffered staging (the r20 conv pattern) ported to
// the packed GEMMs and the VQ dist kernel: next-chunk loads issue BEFORE the
// MFMA phase. Bit-identical numerics (schedule-only change).

#define GF_BIAS 1
#define GF_RELU 2
#define GF_ADDP 4
#define GF_POS  8
#define GF_ACCP 16
#define GF_QSCALE 32

typedef _Float16 f16x8 __attribute__((ext_vector_type(8)));
typedef float    f32x4 __attribute__((ext_vector_type(4)));

static constexpr long long O_QUANT = 0LL;
static constexpr long long O_LOSS  = 8388608LL;
static constexpr long long O_IDX   = 8388609LL;
static constexpr long long O_HASH  = 8404993LL;
static constexpr long long O_REG   = 9453569LL;
static constexpr long long O_END   = 43008001LL;

static constexpr long long W_XP    = 0LL;
static constexpr long long W_CT    = 8388608LL;
static constexpr long long W_PROJ  = 16777216LL;
static constexpr long long W_VW    = 25165824LL;
static constexpr long long W_HREG  = 33554432LL;
static constexpr long long W_T     = 34078720LL;
static constexpr long long W_IDX   = 34209792LL;
static constexpr long long W_ASUM  = 34226176LL;
static constexpr long long W_CBB   = 34258944LL;
static constexpr long long W_LPART = 34263040LL;
static constexpr long long W_PBV   = 34271232LL;
static constexpr long long W_PBI   = 34336768LL;
static constexpr long long W_END   = 34402304LL;

__device__ __forceinline__ unsigned int pack_hl(float x)
{
    _Float16 h = (_Float16)x;
    float hf = (float)h;
    _Float16 l = (_Float16)(x - hf);
    unsigned short hb = __builtin_bit_cast(unsigned short, h);
    unsigned short lb = __builtin_bit_cast(unsigned short, l);
    return (unsigned int)hb | ((unsigned int)lb << 16);
}

__device__ __forceinline__ void split2(float x, unsigned short& h, unsigned short& l)
{
    _Float16 hf = (_Float16)x;
    _Float16 lf = (_Float16)(x - (float)hf);
    h = __builtin_bit_cast(unsigned short, hf);
    l = __builtin_bit_cast(unsigned short, lf);
}

__device__ __forceinline__ float unpack_sum(unsigned int u)
{
    _Float16 h = __builtin_bit_cast(_Float16, (unsigned short)(u & 0xffff));
    _Float16 l = __builtin_bit_cast(_Float16, (unsigned short)(u >> 16));
    return (float)h + (float)l;
}

// ---------------- splits -----------------------------------------------------
__global__ __launch_bounds__(256)
void split_hl_r23(const float* __restrict__ src, unsigned int* __restrict__ dst)
{
    long long i = (long long)blockIdx.x*256 + threadIdx.x;
    dst[i] = pack_hl(src[i]);
}

__global__ __launch_bounds__(256)
void split_cb_r23(const float* __restrict__ cb, unsigned int* __restrict__ cbhl)
{
    long long i = (long long)blockIdx.x*256 + threadIdx.x;
    cbhl[i] = pack_hl(cb[i] * 2048.0f);
}

template<int KT>
__global__ __launch_bounds__(256)
void conv_w_tr_r23(const float* __restrict__ w, unsigned int* __restrict__ wt)
{
    long long i = (long long)blockIdx.x*256 + threadIdx.x;
    int o  = (int)(i / (512*KT));
    int rem= (int)(i % (512*KT));
    int t  = rem >> 9;
    int ii = rem & 511;
    wt[i] = pack_hl(w[(long long)o*512*KT + (long long)ii*KT + t]);
}

// ---------------- conv via f16x3 MFMA (r22 verbatim) -------------------------
template<int KT>
__global__ __launch_bounds__(256)
void conv_mfma_r23(const unsigned int* __restrict__ xphl,
                   const unsigned int* __restrict__ wthl,
                   const float* __restrict__ bias, unsigned int* __restrict__ outp)
{
    constexpr int PAD = KT / 2;
    __shared__ unsigned short Ah[136][40];
    __shared__ unsigned short Al[136][40];
    __shared__ unsigned short Bh[128][40];
    __shared__ unsigned short Bl[128][40];
    const int tid  = threadIdx.x;
    const int lane = tid & 63;
    const int wave = tid >> 6;
    const int wm = (wave >> 1) * 64, wn = (wave & 1) * 64;
    const int bm = blockIdx.x * 128, bn = blockIdx.y * 128;
    const int l15 = lane & 15;
    const int lk8 = (lane >> 4) * 8;
    const int rbase = (lane >> 4) * 4;
    const int sb = bm & 511;
    const int brow0 = tid >> 3, bc = tid & 7;

    f32x4 acc[4][4];
    #pragma unroll
    for (int i=0;i<4;i++)
        #pragma unroll
        for (int j=0;j<4;j++)
            acc[i][j] = (f32x4){0.f,0.f,0.f,0.f};

    for (int i0 = 0; i0 < 512; i0 += 32) {
        __syncthreads();
        for (int sl = tid; sl < 136*8; sl += 256) {
            const int row = sl >> 3, c = sl & 7;
            const int srow = sb + row - 4;
            uint4 v = make_uint4(0u,0u,0u,0u);
            if (srow >= 0 && srow < 512)
                v = *(const uint4*)(xphl + (long long)(bm + row - 4)*512 + i0 + c*4);
            Ah[row][c*4+0] = (unsigned short)(v.x & 0xffff);
            Ah[row][c*4+1] = (unsigned short)(v.y & 0xffff);
            Ah[row][c*4+2] = (unsigned short)(v.z & 0xffff);
            Ah[row][c*4+3] = (unsigned short)(v.w & 0xffff);
            Al[row][c*4+0] = (unsigned short)(v.x >> 16);
            Al[row][c*4+1] = (unsigned short)(v.y >> 16);
            Al[row][c*4+2] = (unsigned short)(v.z >> 16);
            Al[row][c*4+3] = (unsigned short)(v.w >> 16);
        }
        uint4 vb[4];
        #pragma unroll
        for (int q = 0; q < 4; ++q) {
            const int row = brow0 + q*32;
            vb[q] = *(const uint4*)(wthl + (long long)(bn + row)*(KT*512) + 0*512 + i0 + bc*4);
        }
        for (int t = 0; t < KT; ++t) {
            #pragma unroll
            for (int q = 0; q < 4; ++q) {
                const int row = brow0 + q*32;
                Bh[row][bc*4+0] = (unsigned short)(vb[q].x & 0xffff);
                Bh[row][bc*4+1] = (unsigned short)(vb[q].y & 0xffff);
                Bh[row][bc*4+2] = (unsigned short)(vb[q].z & 0xffff);
                Bh[row][bc*4+3] = (unsigned short)(vb[q].w & 0xffff);
                Bl[row][bc*4+0] = (unsigned short)(vb[q].x >> 16);
                Bl[row][bc*4+1] = (unsigned short)(vb[q].y >> 16);
                Bl[row][bc*4+2] = (unsigned short)(vb[q].z >> 16);
                Bl[row][bc*4+3] = (unsigned short)(vb[q].w >> 16);
            }
            if (t + 1 < KT) {
                #pragma unroll
                for (int q = 0; q < 4; ++q) {
                    const int row = brow0 + q*32;
                    vb[q] = *(const uint4*)(wthl + (long long)(bn + row)*(KT*512) + (t+1)*512 + i0 + bc*4);
                }
            }
            __syncthreads();
            const int tofs = t - PAD + 4;
            f16x8 ah[4], al[4], bh[4], bl[4];
            #pragma unroll
            for (int mi = 0; mi < 4; ++mi) {
                ah[mi] = *(const f16x8*)(&Ah[wm + mi*16 + l15 + tofs][lk8]);
                al[mi] = *(const f16x8*)(&Al[wm + mi*16 + l15 + tofs][lk8]);
            }
            #pragma unroll
            for (int nj = 0; nj < 4; ++nj) {
                bh[nj] = *(const f16x8*)(&Bh[wn + nj*16 + l15][lk8]);
                bl[nj] = *(const f16x8*)(&Bl[wn + nj*16 + l15][lk8]);
            }
            #pragma unroll
            for (int mi = 0; mi < 4; ++mi)
                #pragma unroll
                for (int nj = 0; nj < 4; ++nj) {
                    acc[mi][nj] = __builtin_amdgcn_mfma_f32_16x16x32_f16(ah[mi], bh[nj], acc[mi][nj], 0, 0, 0);
                    acc[mi][nj] = __builtin_amdgcn_mfma_f32_16x16x32_f16(ah[mi], bl[nj], acc[mi][nj], 0, 0, 0);
                    acc[mi][nj] = __builtin_amdgcn_mfma_f32_16x16x32_f16(al[mi], bh[nj], acc[mi][nj], 0, 0, 0);
                }
            if (t + 1 < KT) __syncthreads();
        }
    }
    #pragma unroll
    for (int mi = 0; mi < 4; ++mi) {
        #pragma unroll
        for (int nj = 0; nj < 4; ++nj) {
            const int col = bn + wn + nj*16 + l15;
            const float bcol = bias[col];
            #pragma unroll
            for (int r = 0; r < 4; ++r) {
                const int row = bm + wm + mi*16 + rbase + r;
                float v = acc[mi][nj][r] + bcol;
                outp[(long long)row*512 + col] = pack_hl(fmaxf(v, 0.0f));
            }
        }
    }
}

// ---------------- packed GEMM with reg-double-buffered staging ---------------
template<int FLAGS>
__global__ __launch_bounds__(256)
void gemm_hl_r23(const unsigned int* __restrict__ A, const unsigned int* __restrict__ Bm,
                 const float* __restrict__ bias, const float* __restrict__ pos,
                 const unsigned int* __restrict__ addsrc, unsigned int* __restrict__ C,
                 int Kdim, int lda, int ldb, int ldc)
{
    __shared__ unsigned short Ah[128][40];
    __shared__ unsigned short Al[128][40];
    __shared__ unsigned short Bh[128][40];
    __shared__ unsigned short Bl[128][40];
    const int tid  = threadIdx.x;
    const int lane = tid & 63;
    const int wave = tid >> 6;
    const int wm = (wave >> 1) * 64, wn = (wave & 1) * 64;
    const int bm = blockIdx.x * 128, bn = blockIdx.y * 128;
    const int l15 = lane & 15;
    const int lk8 = (lane >> 4) * 8;
    const int rbase = (lane >> 4) * 4;
    const int cg   = tid & 7;
    const int rw0  = tid >> 3;

    f32x4 acc[4][4];
    #pragma unroll
    for (int i=0;i<4;i++)
        #pragma unroll
        for (int j=0;j<4;j++)
            acc[i][j] = (f32x4){0.f,0.f,0.f,0.f};

    uint4 va[4], vb[4];
    #pragma unroll
    for (int q = 0; q < 4; ++q) {
        const int row = rw0 + q*32;
        va[q] = *(const uint4*)(A  + (long long)(bm + row)*lda + cg*4);
        vb[q] = *(const uint4*)(Bm + (long long)(bn + row)*ldb + cg*4);
    }

    for (int k0 = 0; k0 < Kdim; k0 += 32) {
        __syncthreads();   // prior chunk's MFMA readers done
        #pragma unroll
        for (int q = 0; q < 4; ++q) {
            const int row = rw0 + q*32;
            Ah[row][cg*4+0] = (unsigned short)(va[q].x & 0xffff);
            Ah[row][cg*4+1] = (unsigned short)(va[q].y & 0xffff);
            Ah[row][cg*4+2] = (unsigned short)(va[q].z & 0xffff);
            Ah[row][cg*4+3] = (unsigned short)(va[q].w & 0xffff);
            Al[row][cg*4+0] = (unsigned short)(va[q].x >> 16);
            Al[row][cg*4+1] = (unsigned short)(va[q].y >> 16);
            Al[row][cg*4+2] = (unsigned short)(va[q].z >> 16);
            Al[row][cg*4+3] = (unsigned short)(va[q].w >> 16);
            Bh[row][cg*4+0] = (unsigned short)(vb[q].x & 0xffff);
            Bh[row][cg*4+1] = (unsigned short)(vb[q].y & 0xffff);
            Bh[row][cg*4+2] = (unsigned short)(vb[q].z & 0xffff);
            Bh[row][cg*4+3] = (unsigned short)(vb[q].w & 0xffff);
            Bl[row][cg*4+0] = (unsigned short)(vb[q].x >> 16);
            Bl[row][cg*4+1] = (unsigned short)(vb[q].y >> 16);
            Bl[row][cg*4+2] = (unsigned short)(vb[q].z >> 16);
            Bl[row][cg*4+3] = (unsigned short)(vb[q].w >> 16);
        }
        if (k0 + 32 < Kdim) {
            #pragma unroll
            for (int q = 0; q < 4; ++q) {
                const int row = rw0 + q*32;
                va[q] = *(const uint4*)(A  + (long long)(bm + row)*lda + k0 + 32 + cg*4);
                vb[q] = *(const uint4*)(Bm + (long long)(bn + row)*ldb + k0 + 32 + cg*4);
            }
        }
        __syncthreads();
        f16x8 ah[4], al[4], bh[4], bl[4];
        #pragma unroll
        for (int mi = 0; mi < 4; ++mi) {
            ah[mi] = *(const f16x8*)(&Ah[wm + mi*16 + l15][lk8]);
            al[mi] = *(const f16x8*)(&Al[wm + mi*16 + l15][lk8]);
        }
        #pragma unroll
        for (int nj = 0; nj < 4; ++nj) {
            bh[nj] = *(const f16x8*)(&Bh[wn + nj*16 + l15][lk8]);
            bl[nj] = *(const f16x8*)(&Bl[wn + nj*16 + l15][lk8]);
        }
        #pragma unroll
        for (int mi = 0; mi < 4; ++mi)
            #pragma unroll
            for (int nj = 0; nj < 4; ++nj) {
                acc[mi][nj] = __builtin_amdgcn_mfma_f32_16x16x32_f16(ah[mi], bh[nj], acc[mi][nj], 0, 0, 0);
                acc[mi][nj] = __builtin_amdgcn_mfma_f32_16x16x32_f16(ah[mi], bl[nj], acc[mi][nj], 0, 0, 0);
                acc[mi][nj] = __builtin_amdgcn_mfma_f32_16x16x32_f16(al[mi], bh[nj], acc[mi][nj], 0, 0, 0);
            }
    }
    #pragma unroll
    for (int mi = 0; mi < 4; ++mi) {
        #pragma unroll
        for (int nj = 0; nj < 4; ++nj) {
            const int col = bn + wn + nj*16 + l15;
            #pragma unroll
            for (int r = 0; r < 4; ++r) {
                const int row = bm + wm + mi*16 + rbase + r;
                float v = acc[mi][nj][r];
                if constexpr (FLAGS & GF_BIAS) v += bias[col];
                if constexpr (FLAGS & GF_POS)  v += pos[(long long)(row & 511)*512 + col];
                if constexpr (FLAGS & GF_ADDP) v += unpack_sum(addsrc[(long long)row*ldc + col]);
                if constexpr (FLAGS & GF_ACCP) v += unpack_sum(C[(long long)row*ldc + col]);
                if constexpr (FLAGS & GF_QSCALE) v *= 0.125f;
                C[(long long)row*ldc + col] = pack_hl(v);
            }
        }
    }
}

// ---------------- fused attention (r22 verbatim) -----------------------------
__global__ __launch_bounds__(256)
void attn_mfma_r23(const unsigned int* __restrict__ Qbuf, const unsigned int* __restrict__ Kbuf,
                   const unsigned int* __restrict__ Vbuf, unsigned int* __restrict__ att)
{
    __shared__ unsigned short Qh[64][68];
    __shared__ unsigned short Ql[64][68];
    __shared__ unsigned short Kh[64][68];
    __shared__ unsigned short Kl[64][68];
    __shared__ unsigned short Vh[64][68];
    __shared__ unsigned short Vl[64][68];
    const int tid  = threadIdx.x;
    const int lane = tid & 63;
    const int wave = tid >> 6;
    const int l15  = lane & 15;
    const int lq   = lane >> 4;
    const int lq8  = lq * 8;
    const int bid = blockIdx.x;
    const int qt = bid & 7, h = (bid >> 3) & 7, b = bid >> 6;
    const int row0 = b*512 + qt*64;

    #pragma unroll
    for (int u = 0; u < 16; ++u) {
        int e = u*256 + tid;
        int r = e >> 6, c = e & 63;
        unsigned int uq = Qbuf[(long long)(row0 + r)*512 + h*64 + c];
        Qh[r][c] = (unsigned short)(uq & 0xffff);
        Ql[r][c] = (unsigned short)(uq >> 16);
    }

    float m[4], l[4];
    f32x4 accO[4];
    #pragma unroll
    for (int r=0;r<4;r++){ m[r] = -1e30f; l[r] = 0.f; }
    #pragma unroll
    for (int j=0;j<4;j++) accO[j] = (f32x4){0.f,0.f,0.f,0.f};

    for (int kv = 0; kv < 512; kv += 64) {
        __syncthreads();
        #pragma unroll
        for (int u = 0; u < 16; ++u) {
            int e = u*256 + tid;
            int r = e >> 6, c = e & 63;
            unsigned int uk = Kbuf[(long long)(b*512 + kv + r)*512 + h*64 + c];
            unsigned int uv = Vbuf[(long long)(b*512 + kv + r)*512 + h*64 + c];
            Kh[r][c] = (unsigned short)(uk & 0xffff);
            Kl[r][c] = (unsigned short)(uk >> 16);
            Vh[c][r] = (unsigned short)(uv & 0xffff);
            Vl[c][r] = (unsigned short)(uv >> 16);
        }
        __syncthreads();
        f32x4 accS[4];
        #pragma unroll
        for (int j=0;j<4;j++) accS[j] = (f32x4){0.f,0.f,0.f,0.f};
        #pragma unroll
        for (int ks = 0; ks < 2; ++ks) {
            f16x8 qh = *(const f16x8*)(&Qh[wave*16 + l15][ks*32 + lq8]);
            f16x8 ql = *(const f16x8*)(&Ql[wave*16 + l15][ks*32 + lq8]);
            #pragma unroll
            for (int nj = 0; nj < 4; ++nj) {
                f16x8 kh = *(const f16x8*)(&Kh[nj*16 + l15][ks*32 + lq8]);
                f16x8 kl = *(const f16x8*)(&Kl[nj*16 + l15][ks*32 + lq8]);
                accS[nj] = __builtin_amdgcn_mfma_f32_16x16x32_f16(qh, kh, accS[nj], 0, 0, 0);
                accS[nj] = __builtin_amdgcn_mfma_f32_16x16x32_f16(qh, kl, accS[nj], 0, 0, 0);
                accS[nj] = __builtin_amdgcn_mfma_f32_16x16x32_f16(ql, kh, accS[nj], 0, 0, 0);
            }
        }
        #pragma unroll
        for (int r = 0; r < 4; ++r) {
            float tm = fmaxf(fmaxf(accS[0][r], accS[1][r]), fmaxf(accS[2][r], accS[3][r]));
            #pragma unroll
            for (int msk = 1; msk < 16; msk <<= 1) tm = fmaxf(tm, __shfl_xor(tm, msk, 64));
            float mn = fmaxf(m[r], tm);
            float scale = expf(m[r] - mn);
            float rs = 0.f;
            #pragma unroll
            for (int nj = 0; nj < 4; ++nj) {
                float p = expf(accS[nj][r] - mn);
                accS[nj][r] = p;
                rs += p;
            }
            #pragma unroll
            for (int msk = 1; msk < 16; msk <<= 1) rs += __shfl_xor(rs, msk, 64);
            l[r] = l[r]*scale + rs;
            m[r] = mn;
            #pragma unroll
            for (int nj = 0; nj < 4; ++nj) accO[nj][r] *= scale;
        }
        __syncthreads();
        #pragma unroll
        for (int r = 0; r < 4; ++r)
            #pragma unroll
            for (int nj = 0; nj < 4; ++nj) {
                unsigned short hs, ls;
                split2(accS[nj][r], hs, ls);
                Kh[wave*16 + lq*4 + r][nj*16 + l15] = hs;
                Kl[wave*16 + lq*4 + r][nj*16 + l15] = ls;
            }
        __syncthreads();
        #pragma unroll
        for (int ks = 0; ks < 2; ++ks) {
            f16x8 ph = *(const f16x8*)(&Kh[wave*16 + l15][ks*32 + lq8]);
            f16x8 pl = *(const f16x8*)(&Kl[wave*16 + l15][ks*32 + lq8]);
            #pragma unroll
            for (int nj = 0; nj < 4; ++nj) {
                f16x8 vh = *(const f16x8*)(&Vh[nj*16 + l15][ks*32 + lq8]);
                f16x8 vl = *(const f16x8*)(&Vl[nj*16 + l15][ks*32 + lq8]);
                accO[nj] = __builtin_amdgcn_mfma_f32_16x16x32_f16(ph, vh, accO[nj], 0, 0, 0);
                accO[nj] = __builtin_amdgcn_mfma_f32_16x16x32_f16(ph, vl, accO[nj], 0, 0, 0);
                accO[nj] = __builtin_amdgcn_mfma_f32_16x16x32_f16(pl, vh, accO[nj], 0, 0, 0);
            }
        }
    }
    #pragma unroll
    for (int nj = 0; nj < 4; ++nj)
        #pragma unroll
        for (int r = 0; r < 4; ++r) {
            const int row = row0 + wave*16 + lq*4 + r;
            att[(long long)row*512 + h*64 + nj*16 + l15] = pack_hl(accO[nj][r] / l[r]);
        }
}

// ---------------- row sum of squares -----------------------------------------
__global__ __launch_bounds__(256)
void row_sumsq_r23(const float* __restrict__ X, double* __restrict__ outp)
{
    const int row  = blockIdx.x*4 + (threadIdx.x >> 6);
    const int lane = threadIdx.x & 63;
    double s = 0.0;
    #pragma unroll
    for (int u = 0; u < 8; ++u) {
        float v = X[(long long)row*512 + lane + u*64];
        s += (double)v * (double)v;
    }
    #pragma unroll
    for (int msk = 32; msk; msk >>= 1) s += __shfl_xor(s, msk, 64);
    if (lane == 0) outp[row] = s;
}

__global__ __launch_bounds__(256)
void row_sumsq_hl_r23(const unsigned int* __restrict__ X, double* __restrict__ outp)
{
    const int row  = blockIdx.x*4 + (threadIdx.x >> 6);
    const int lane = threadIdx.x & 63;
    double s = 0.0;
    #pragma unroll
    for (int u = 0; u < 8; ++u) {
        float v = unpack_sum(X[(long long)row*512 + lane + u*64]);
        s += (double)v * (double)v;
    }
    #pragma unroll
    for (int msk = 32; msk; msk >>= 1) s += __shfl_xor(s, msk, 64);
    if (lane == 0) outp[row] = s;
}

// ---------------- VQ argmin with reg-double-buffered staging -----------------
__global__ __launch_bounds__(256)
void vq_argmin_mfma_r23(const unsigned int* __restrict__ enchl,
                        const unsigned int* __restrict__ cbhl,
                        const double* __restrict__ Asum, const double* __restrict__ cbB,
                        float* __restrict__ pbv, int* __restrict__ pbi)
{
    __shared__ unsigned int smem[10240];
    unsigned short* AhP = (unsigned short*)smem;
    unsigned short* AlP = AhP + 128*40;
    unsigned short* BhP = AlP + 128*40;
    unsigned short* BlP = BhP + 128*40;
    float* bvsP = (float*)smem;
    int*   bisP = (int*)(smem + 4096);

    const int tid  = threadIdx.x;
    const int lane = tid & 63;
    const int wave = tid >> 6;
    const int wm = (wave >> 1) * 64, wn = (wave & 1) * 64;
    const int bm = blockIdx.x * 128;
    const int l15 = lane & 15;
    const int lk8 = (lane >> 4) * 8;
    const int rbase = (lane >> 4) * 4;
    const int cg   = tid & 7;
    const int rw0  = tid >> 3;

    float bestv[16]; int besti[16];
    #pragma unroll
    for (int g = 0; g < 16; ++g) { bestv[g] = 3.0e38f; besti[g] = 2048; }

    for (int nb = 0; nb < 4; ++nb) {
        const int ct0 = blockIdx.y * 512 + nb * 128;
        f32x4 acc[4][4];
        #pragma unroll
        for (int i=0;i<4;i++)
            #pragma unroll
            for (int j=0;j<4;j++)
                acc[i][j] = (f32x4){0.f,0.f,0.f,0.f};

        uint4 va[4], vb[4];
        #pragma unroll
        for (int q = 0; q < 4; ++q) {
            const int row = rw0 + q*32;
            va[q] = *(const uint4*)(enchl + (long long)(bm + row)*512 + cg*4);
            vb[q] = *(const uint4*)(cbhl  + (long long)(ct0 + row)*512 + cg*4);
        }

        for (int k0 = 0; k0 < 512; k0 += 32) {
            __syncthreads();
            #pragma unroll
            for (int q = 0; q < 4; ++q) {
                const int row = rw0 + q*32;
                AhP[row*40 + cg*4+0] = (unsigned short)(va[q].x & 0xffff);
                AhP[row*40 + cg*4+1] = (unsigned short)(va[q].y & 0xffff);
                AhP[row*40 + cg*4+2] = (unsigned short)(va[q].z & 0xffff);
                AhP[row*40 + cg*4+3] = (unsigned short)(va[q].w & 0xffff);
                AlP[row*40 + cg*4+0] = (unsigned short)(va[q].x >> 16);
                AlP[row*40 + cg*4+1] = (unsigned short)(va[q].y >> 16);
                AlP[row*40 + cg*4+2] = (unsigned short)(va[q].z >> 16);
                AlP[row*40 + cg*4+3] = (unsigned short)(va[q].w >> 16);
                BhP[row*40 + cg*4+0] = (unsigned short)(vb[q].x & 0xffff);
                BhP[row*40 + cg*4+1] = (unsigned short)(vb[q].y & 0xffff);
                BhP[row*40 + cg*4+2] = (unsigned short)(vb[q].z & 0xffff);
                BhP[row*40 + cg*4+3] = (unsigned short)(vb[q].w & 0xffff);
                BlP[row*40 + cg*4+0] = (unsigned short)(vb[q].x >> 16);
                BlP[row*40 + cg*4+1] = (unsigned short)(vb[q].y >> 16);
                BlP[row*40 + cg*4+2] = (unsigned short)(vb[q].z >> 16);
                BlP[row*40 + cg*4+3] = (unsigned short)(vb[q].w >> 16);
            }
            if (k0 + 32 < 512) {
                #pragma unroll
                for (int q = 0; q < 4; ++q) {
                    const int row = rw0 + q*32;
                    va[q] = *(const uint4*)(enchl + (long long)(bm + row)*512 + k0 + 32 + cg*4);
                    vb[q] = *(const uint4*)(cbhl  + (long long)(ct0 + row)*512 + k0 + 32 + cg*4);
                }
            }
            __syncthreads();
            f16x8 ah[4], al[4], bh[4], bl[4];
            #pragma unroll
            for (int mi = 0; mi < 4; ++mi) {
                ah[mi] = *(const f16x8*)(&AhP[(wm + mi*16 + l15)*40 + lk8]);
                al[mi] = *(const f16x8*)(&AlP[(wm + mi*16 + l15)*40 + lk8]);
            }
            #pragma unroll
            for (int nj = 0; nj < 4; ++nj) {
                bh[nj] = *(const f16x8*)(&BhP[(wn + nj*16 + l15)*40 + lk8]);
                bl[nj] = *(const f16x8*)(&BlP[(wn + nj*16 + l15)*40 + lk8]);
            }
            #pragma unroll
            for (int mi = 0; mi < 4; ++mi)
                #pragma unroll
                for (int nj = 0; nj < 4; ++nj) {
                    acc[mi][nj] = __builtin_amdgcn_mfma_f32_16x16x32_f16(ah[mi], bh[nj], acc[mi][nj], 0, 0, 0);
                    acc[mi][nj] = __builtin_amdgcn_mfma_f32_16x16x32_f16(ah[mi], bl[nj], acc[mi][nj], 0, 0, 0);
                    acc[mi][nj] = __builtin_amdgcn_mfma_f32_16x16x32_f16(al[mi], bh[nj], acc[mi][nj], 0, 0, 0);
                }
        }
        #pragma unroll
        for (int mi = 0; mi < 4; ++mi) {
            #pragma unroll
            for (int r = 0; r < 4; ++r) {
                const int g = mi*4 + r;
                const float anf = (float)Asum[bm + wm + mi*16 + rbase + r];
                #pragma unroll
                for (int nj = 0; nj < 4; ++nj) {
                    const int col = ct0 + wn + nj*16 + l15;
                    const float bf = (float)cbB[col];
                    const float s1 = anf + bf;
                    const float dot = acc[mi][nj][r] * (1.0f/2048.0f);
                    const float df  = 2.0f * dot;
                    const float qd  = s1 - df;
                    if (qd < bestv[g] || (qd == bestv[g] && col < besti[g])) {
                        bestv[g] = qd; besti[g] = col;
                    }
                }
            }
        }
    }
    __syncthreads();
    #pragma unroll
    for (int mi = 0; mi < 4; ++mi)
        #pragma unroll
        for (int r = 0; r < 4; ++r) {
            const int row  = wm + mi*16 + rbase + r;
            const int slot = (wave & 1)*16 + l15;
            bvsP[row*32 + slot] = bestv[mi*4 + r];
            bisP[row*32 + slot] = besti[mi*4 + r];
        }
    __syncthreads();
    if (tid < 128) {
        float bv = bvsP[tid*32]; int bi = bisP[tid*32];
        #pragma unroll
        for (int s = 1; s < 32; ++s) {
            float v = bvsP[tid*32 + s]; int ii = bisP[tid*32 + s];
            if (v < bv || (v == bv && ii < bi)) { bv = v; bi = ii; }
        }
        pbv[(long long)blockIdx.y*16384 + bm + tid] = bv;
        pbi[(long long)blockIdx.y*16384 + bm + tid] = bi;
    }
}

__global__ __launch_bounds__(256)
void vq_reduce_r23(const float* __restrict__ pbv, const int* __restrict__ pbi,
                   int* __restrict__ idxout, float* __restrict__ out)
{
    int n = blockIdx.x*256 + threadIdx.x;
    if (n >= 16384) return;
    float bv = pbv[n]; int bi = pbi[n];
    #pragma unroll
    for (int q = 1; q < 4; ++q) {
        float v = pbv[q*16384 + n]; int ii = pbi[q*16384 + n];
        if (v < bv || (v == bv && ii < bi)) { bv = v; bi = ii; }
    }
    int ci = bi & 2047;
    idxout[n] = ci;
    out[O_IDX + n] = (float)ci;
}

// ---------------- vq loss (packed enc) ---------------------------------------
__global__ __launch_bounds__(256)
void vq_loss_partial_r23(const unsigned int* __restrict__ enchl,
                         const float* __restrict__ cb,
                         const int* __restrict__ idxp, double* __restrict__ part)
{
    __shared__ double red[4];
    const int row  = blockIdx.x*4 + (threadIdx.x >> 6);
    const int lane = threadIdx.x & 63;
    const int ci = idxp[row] & 2047;
    double s = 0.0;
    #pragma unroll
    for (int u = 0; u < 8; ++u) {
        int d = lane + u*64;
        float e = unpack_sum(enchl[(long long)row*512 + d]);
        double dv = (double)cb[(long long)ci*512 + d] - (double)e;
        s += dv * dv;
    }
    #pragma unroll
    for (int msk = 32; msk; msk >>= 1) s += __shfl_xor(s, msk, 64);
    if (lane == 0) red[threadIdx.x >> 6] = s;
    __syncthreads();
    if (threadIdx.x == 0)
        part[blockIdx.x] = red[0] + red[1] + red[2] + red[3];
}

// ---------------- regime f32 GEMM (small, r22 verbatim) ----------------------
template<int FLAGS>
__global__ __launch_bounds__(256)
void gemm_bt_r23(const float* __restrict__ A, const float* __restrict__ Bm,
                 const float* __restrict__ bias, const float* __restrict__ pos,
                 const float* __restrict__ addsrc, float* __restrict__ C,
                 int Kdim, int lda, int ldb, int ldc)
{
    __shared__ float As[16][132];
    __shared__ float Bs[16][132];
    const int tid = threadIdx.x;
    const int tx = tid & 15, ty = tid >> 4;
    const int bm = blockIdx.x * 128, bn = blockIdx.y * 128;
    const int r0 = tid >> 2;
    const int kg = (tid & 3) << 2;
    const float* Arow0 = A  + (long long)(bm + r0) * lda + kg;
    const float* Arow1 = A  + (long long)(bm + r0 + 64) * lda + kg;
    const float* Brow0 = Bm + (long long)(bn + r0) * ldb + kg;
    const float* Brow1 = Bm + (long long)(bn + r0 + 64) * ldb + kg;

    float acc[8][8] = {};
    for (int k0 = 0; k0 < Kdim; k0 += 16) {
        float4 a0 = *(const float4*)(Arow0 + k0);
        float4 a1 = *(const float4*)(Arow1 + k0);
        float4 b0 = *(const float4*)(Brow0 + k0);
        float4 b1 = *(const float4*)(Brow1 + k0);
        __syncthreads();
        As[kg+0][r0]=a0.x; As[kg+1][r0]=a0.y; As[kg+2][r0]=a0.z; As[kg+3][r0]=a0.w;
        As[kg+0][r0+64]=a1.x; As[kg+1][r0+64]=a1.y; As[kg+2][r0+64]=a1.z; As[kg+3][r0+64]=a1.w;
        Bs[kg+0][r0]=b0.x; Bs[kg+1][r0]=b0.y; Bs[kg+2][r0]=b0.z; Bs[kg+3][r0]=b0.w;
        Bs[kg+0][r0+64]=b1.x; Bs[kg+1][r0+64]=b1.y; Bs[kg+2][r0+64]=b1.z; Bs[kg+3][r0+64]=b1.w;
        __syncthreads();
        #pragma unroll
        for (int kk = 0; kk < 16; ++kk) {
            float a[8], b[8];
            #pragma unroll
            for (int i=0;i<8;i++) a[i] = As[kk][ty*8+i];
            #pragma unroll
            for (int j=0;j<4;j++) b[j]   = Bs[kk][tx*4+j];
            #pragma unroll
            for (int j=0;j<4;j++) b[4+j] = Bs[kk][64+tx*4+j];
            #pragma unroll
            for (int i=0;i<8;i++)
                #pragma unroll
                for (int j=0;j<8;j++)
                    acc[i][j] = fmaf(a[i], b[j], acc[i][j]);
        }
    }
    #pragma unroll
    for (int i=0;i<8;i++){
        const int row = bm + ty*8 + i;
        #pragma unroll
        for (int j=0;j<8;j++){
            const int col = bn + ((j < 4) ? (tx*4 + j) : (64 + tx*4 + (j-4)));
            float v = acc[i][j];
            if constexpr (FLAGS & GF_BIAS) v += bias[col];
            if constexpr (FLAGS & GF_RELU) v = fmaxf(v, 0.0f);
            C[(long long)row*ldc + col] = v;
        }
    }
}

// ---------------- regime softmax ---------------------------------------------
__global__ __launch_bounds__(256)
void softmax_rows_r23(float* __restrict__ R)
{
    const int row = blockIdx.x;
    const int tid = threadIdx.x;
    __shared__ float  redf[256];
    __shared__ double redd[256];
    float* p = R + (long long)row * 2048;
    float mx = -1e30f;
    for (int c = tid; c < 2048; c += 256) mx = fmaxf(mx, p[c]);
    redf[tid] = mx; __syncthreads();
    for (int s2 = 128; s2; s2 >>= 1) { if (tid < s2) redf[tid] = fmaxf(redf[tid], redf[tid+s2]); __syncthreads(); }
    mx = redf[0];
    double sum = 0.0;
    for (int c = tid; c < 2048; c += 256) { float e = expf(p[c] - mx); p[c] = e; sum += e; }
    redd[tid] = sum; __syncthreads();
    for (int s2 = 128; s2; s2 >>= 1) { if (tid < s2) redd[tid] += redd[tid+s2]; __syncthreads(); }
    double tot = redd[0];
    for (int c = tid; c < 2048; c += 256) p[c] = (float)((double)p[c] / tot);
}

// ---------------- hash table -------------------------------------------------
__global__ __launch_bounds__(256)
void hash_table_r23(const float* __restrict__ cb, const float* __restrict__ hw,
                    float* __restrict__ T)
{
    const int k = blockIdx.x*4 + (threadIdx.x >> 6);
    const int j = threadIdx.x & 63;
    double s = 0.0;
    for (int d = 0; d < 512; ++d)
        s += (double)cb[(long long)k*512 + d] * (double)hw[(long long)j*512 + d];
    T[(long long)k*64 + j] = (s > 0.0) ? 1.0f : 0.0f;
}

// ---------------- output writers ---------------------------------------------
__global__ void write_loss_r23(const double* __restrict__ part,
                               float* __restrict__ out)
{
    __shared__ double red[256];
    double s = 0.0;
    for (int i = threadIdx.x; i < 4096; i += 256) s += part[i];
    red[threadIdx.x] = s; __syncthreads();
    for (int s2 = 128; s2; s2 >>= 1) {
        if (threadIdx.x < s2) red[threadIdx.x] += red[threadIdx.x + s2];
        __syncthreads();
    }
    if (threadIdx.x == 0)
        out[O_LOSS] = (float)(1.25 * red[0] / 8388608.0);
}

__global__ __launch_bounds__(256)
void write_regime_r23(const float* __restrict__ R, const int* __restrict__ idxp,
                      float* __restrict__ out)
{
    long long i = (long long)blockIdx.x*256 + threadIdx.x;
    if (i >= 33554432LL) return;
    int n = (int)(i >> 11), c = (int)(i & 2047);
    int ci = idxp[n] & 2047;
    out[O_REG + i] = R[(long long)ci*2048 + c];
}

__global__ __launch_bounds__(256)
void write_hash_r23(const float* __restrict__ T, const int* __restrict__ idxp,
                    float* __restrict__ out)
{
    long long i = (long long)blockIdx.x*256 + threadIdx.x;
    if (i >= 1048576LL) return;
    int n = (int)(i >> 6), j = (int)(i & 63);
    int ci = idxp[n] & 2047;
    out[O_HASH + i] = T[(long long)ci*64 + j];
}

__global__ __launch_bounds__(256)
void write_quant_r23(const float* __restrict__ cb, const int* __restrict__ idxp,
                     float* __restrict__ out)
{
    long long i = (long long)blockIdx.x*256 + threadIdx.x;
    if (i >= 8388608LL) return;
    int n = (int)(i >> 9), d = (int)(i & 511);
    int ci = idxp[n] & 2047;
    out[O_QUANT + i] = cb[(long long)ci*512 + d];
}

// ---------------- launcher ----------------------------------------------------
extern "C" void kernel_launch(void* const* d_in, const int* in_sizes, int n_in,
                              void* d_out, int out_size, void* d_ws, size_t ws_size,
                              hipStream_t stream)
{
    (void)in_sizes; (void)n_in; (void)out_size;
    const float* market = (const float*)d_in[0];
    const float* W_in   = (const float*)d_in[1];
    const float* b_in   = (const float*)d_in[2];
    const float* pos    = (const float*)d_in[3];
    const float* c3w = (const float*)d_in[4];  const float* c3b = (const float*)d_in[5];
    const float* c5w = (const float*)d_in[6];  const float* c5b = (const float*)d_in[7];
    const float* c7w = (const float*)d_in[8];  const float* c7b = (const float*)d_in[9];
    const float* c9w = (const float*)d_in[10]; const float* c9b = (const float*)d_in[11];
    const float* msw = (const float*)d_in[12]; const float* msb = (const float*)d_in[13];
    const float* inw = (const float*)d_in[14]; const float* inb = (const float*)d_in[15];
    const float* aow = (const float*)d_in[16]; const float* aob = (const float*)d_in[17];
    const float* cb  = (const float*)d_in[18]; const float* hw  = (const float*)d_in[19];
    const float* r1w = (const float*)d_in[20]; const float* r1b = (const float*)d_in[21];
    const float* r2w = (const float*)d_in[22]; const float* r2b = (const float*)d_in[23];

    if (ws_size < (size_t)W_END * sizeof(float)) return;

    float* ws = (float*)d_ws;
    unsigned int* xphl   = (unsigned int*)(ws + W_XP);
    unsigned int* cthl   = (unsigned int*)(ws + W_CT);
    unsigned int* projhl = (unsigned int*)(ws + W_PROJ);
    unsigned int* vwbase = (unsigned int*)(ws + W_VW);
    unsigned int* wt3 = vwbase;
    unsigned int* wt5 = wt3 + 512*512*3;
    unsigned int* wt7 = wt5 + 512*512*5;
    unsigned int* wt9 = wt7 + 512*512*7;
    unsigned int* mswhl  = vwbase + 6291456;
    unsigned int* winhl  = mswhl + 1048576;
    unsigned int* inwqhl = winhl + 262144;
    unsigned int* inwkhl = inwqhl + 262144;
    unsigned int* vhl    = vwbase;
    unsigned int* inwvhl = (unsigned int*)(ws + W_HREG);
    unsigned int* aowhl  = inwvhl + 262144;
    float* hregp = ws + W_HREG;
    float* Tp    = ws + W_T;
    int*    idxp  = (int*)(ws + W_IDX);
    double* asump = (double*)(ws + W_ASUM);
    double* cbbp  = (double*)(ws + W_CBB);
    double* lpart = (double*)(ws + W_LPART);
    float*  pbvp  = ws + W_PBV;
    int*    pbip  = (int*)(ws + W_PBI);
    unsigned int* cbhl = (unsigned int*)(ws + W_PROJ + 4194304);
    float* Rp = ws + W_PROJ;

    float* out = (float*)d_out;

    conv_w_tr_r23<3><<<3072, 256, 0, stream>>>(c3w, wt3);
    conv_w_tr_r23<5><<<5120, 256, 0, stream>>>(c5w, wt5);
    conv_w_tr_r23<7><<<7168, 256, 0, stream>>>(c7w, wt7);
    conv_w_tr_r23<9><<<9216, 256, 0, stream>>>(c9w, wt9);
    split_hl_r23<<<32768, 256, 0, stream>>>(market, cthl);
    split_hl_r23<<<1024,  256, 0, stream>>>(W_in, winhl);
    split_hl_r23<<<4096,  256, 0, stream>>>(msw, mswhl);
    split_hl_r23<<<1024,  256, 0, stream>>>(inw,            inwqhl);
    split_hl_r23<<<1024,  256, 0, stream>>>(inw + 262144,   inwkhl);
    split_hl_r23<<<1024,  256, 0, stream>>>(inw + 524288,   inwvhl);
    split_hl_r23<<<1024,  256, 0, stream>>>(aow, aowhl);

    const dim3 gT(128, 4);

    gemm_hl_r23<GF_BIAS|GF_POS><<<gT, 256, 0, stream>>>(cthl, winhl, b_in, pos, nullptr, xphl, 512, 512, 512, 512);

    conv_mfma_r23<3><<<gT, 256, 0, stream>>>(xphl, wt3, c3b, cthl);
    gemm_hl_r23<GF_BIAS><<<gT, 256, 0, stream>>>(cthl, mswhl + 0*512, msb, nullptr, nullptr, projhl, 512, 512, 2048, 512);
    conv_mfma_r23<5><<<gT, 256, 0, stream>>>(xphl, wt5, c5b, cthl);
    gemm_hl_r23<GF_ACCP><<<gT, 256, 0, stream>>>(cthl, mswhl + 1*512, nullptr, nullptr, nullptr, projhl, 512, 512, 2048, 512);
    conv_mfma_r23<7><<<gT, 256, 0, stream>>>(xphl, wt7, c7b, cthl);
    gemm_hl_r23<GF_ACCP><<<gT, 256, 0, stream>>>(cthl, mswhl + 2*512, nullptr, nullptr, nullptr, projhl, 512, 512, 2048, 512);
    conv_mfma_r23<9><<<gT, 256, 0, stream>>>(xphl, wt9, c9b, cthl);
    gemm_hl_r23<GF_ACCP><<<gT, 256, 0, stream>>>(cthl, mswhl + 3*512, nullptr, nullptr, nullptr, projhl, 512, 512, 2048, 512);

    gemm_hl_r23<GF_BIAS><<<gT, 256, 0, stream>>>(projhl, inwkhl, inb + 512,  nullptr, nullptr, cthl, 512, 512, 512, 512);
    gemm_hl_r23<GF_BIAS|GF_QSCALE><<<gT, 256, 0, stream>>>(projhl, inwqhl, inb, nullptr, nullptr, xphl, 512, 512, 512, 512);
    gemm_hl_r23<GF_BIAS><<<gT, 256, 0, stream>>>(projhl, inwvhl, inb + 1024, nullptr, nullptr, vhl, 512, 512, 512, 512);

    attn_mfma_r23<<<2048, 256, 0, stream>>>(xphl, cthl, vhl, xphl);

    gemm_hl_r23<GF_BIAS|GF_ADDP><<<gT, 256, 0, stream>>>(xphl, aowhl, aob, nullptr, projhl, cthl, 512, 512, 512, 512);

    // VQ
    row_sumsq_hl_r23<<<4096, 256, 0, stream>>>(cthl, asump);
    row_sumsq_r23<<<512,  256, 0, stream>>>(cb, cbbp);
    split_cb_r23<<<4096, 256, 0, stream>>>(cb, cbhl);
    vq_argmin_mfma_r23<<<dim3(128, 4), 256, 0, stream>>>(cthl, cbhl, asump, cbbp, pbvp, pbip);
    vq_reduce_r23<<<64, 256, 0, stream>>>(pbvp, pbip, idxp, out);
    vq_loss_partial_r23<<<4096, 256, 0, stream>>>(cthl, cb, idxp, lpart);

    // regime tables
    gemm_bt_r23<GF_BIAS|GF_RELU><<<dim3(16, 2),  256, 0, stream>>>(cb, r1w, r1b, nullptr, nullptr, hregp, 512, 512, 512, 256);
    gemm_bt_r23<GF_BIAS><<<dim3(16, 16), 256, 0, stream>>>(hregp, r2w, r2b, nullptr, nullptr, Rp, 256, 256, 256, 2048);
    softmax_rows_r23<<<2048, 256, 0, stream>>>(Rp);
    hash_table_r23<<<512, 256, 0, stream>>>(cb, hw, Tp);

    // outputs
    write_loss_r23<<<1, 256, 0, stream>>>(lpart, out);
    write_regime_r23<<<131072, 256, 0, stream>>>(Rp, idxp, out);
    write_hash_r23<<<4096, 256, 0, stream>>>(Tp, idxp, out);
    write_quant_r23<<<32768, 256, 0, stream>>>(cb, idxp, out);
}

// Round 24
// 1451.267 us; speedup vs baseline: 1.3070x; 1.0125x over previous
//
#include <hip/hip_runtime.h>
#include <hip/hip_bf16.h>

// ---------------- problem constants ----------------
// B=32, S=512, D=512, K=2048; N = B*S = 16384. d_out is FLOAT32.
// r24 = r23 with LDS double-buffering (ONE barrier per iteration) in
// conv_mfma (B tile), gemm_hl (A+B tiles), vq_argmin (A+B tiles).
// Bit-identical numerics (schedule-only change).

#define GF_BIAS 1
#define GF_RELU 2
#define GF_ADDP 4
#define GF_POS  8
#define GF_ACCP 16
#define GF_QSCALE 32

typedef _Float16 f16x8 __attribute__((ext_vector_type(8)));
typedef float    f32x4 __attribute__((ext_vector_type(4)));

static constexpr long long O_QUANT = 0LL;
static constexpr long long O_LOSS  = 8388608LL;
static constexpr long long O_IDX   = 8388609LL;
static constexpr long long O_HASH  = 8404993LL;
static constexpr long long O_REG   = 9453569LL;
static constexpr long long O_END   = 43008001LL;

static constexpr long long W_XP    = 0LL;
static constexpr long long W_CT    = 8388608LL;
static constexpr long long W_PROJ  = 16777216LL;
static constexpr long long W_VW    = 25165824LL;
static constexpr long long W_HREG  = 33554432LL;
static constexpr long long W_T     = 34078720LL;
static constexpr long long W_IDX   = 34209792LL;
static constexpr long long W_ASUM  = 34226176LL;
static constexpr long long W_CBB   = 34258944LL;
static constexpr long long W_LPART = 34263040LL;
static constexpr long long W_PBV   = 34271232LL;
static constexpr long long W_PBI   = 34336768LL;
static constexpr long long W_END   = 34402304LL;

__device__ __forceinline__ unsigned int pack_hl(float x)
{
    _Float16 h = (_Float16)x;
    float hf = (float)h;
    _Float16 l = (_Float16)(x - hf);
    unsigned short hb = __builtin_bit_cast(unsigned short, h);
    unsigned short lb = __builtin_bit_cast(unsigned short, l);
    return (unsigned int)hb | ((unsigned int)lb << 16);
}

__device__ __forceinline__ void split2(float x, unsigned short& h, unsigned short& l)
{
    _Float16 hf = (_Float16)x;
    _Float16 lf = (_Float16)(x - (float)hf);
    h = __builtin_bit_cast(unsigned short, hf);
    l = __builtin_bit_cast(unsigned short, lf);
}

__device__ __forceinline__ float unpack_sum(unsigned int u)
{
    _Float16 h = __builtin_bit_cast(_Float16, (unsigned short)(u & 0xffff));
    _Float16 l = __builtin_bit_cast(_Float16, (unsigned short)(u >> 16));
    return (float)h + (float)l;
}

// unpack a u32 into hi/lo LDS slots
__device__ __forceinline__ void st_hl(unsigned short* Hp, unsigned short* Lp, uint4 v)
{
    Hp[0] = (unsigned short)(v.x & 0xffff);
    Hp[1] = (unsigned short)(v.y & 0xffff);
    Hp[2] = (unsigned short)(v.z & 0xffff);
    Hp[3] = (unsigned short)(v.w & 0xffff);
    Lp[0] = (unsigned short)(v.x >> 16);
    Lp[1] = (unsigned short)(v.y >> 16);
    Lp[2] = (unsigned short)(v.z >> 16);
    Lp[3] = (unsigned short)(v.w >> 16);
}

// ---------------- splits -----------------------------------------------------
__global__ __launch_bounds__(256)
void split_hl_r24(const float* __restrict__ src, unsigned int* __restrict__ dst)
{
    long long i = (long long)blockIdx.x*256 + threadIdx.x;
    dst[i] = pack_hl(src[i]);
}

__global__ __launch_bounds__(256)
void split_cb_r24(const float* __restrict__ cb, unsigned int* __restrict__ cbhl)
{
    long long i = (long long)blockIdx.x*256 + threadIdx.x;
    cbhl[i] = pack_hl(cb[i] * 2048.0f);
}

template<int KT>
__global__ __launch_bounds__(256)
void conv_w_tr_r24(const float* __restrict__ w, unsigned int* __restrict__ wt)
{
    long long i = (long long)blockIdx.x*256 + threadIdx.x;
    int o  = (int)(i / (512*KT));
    int rem= (int)(i % (512*KT));
    int t  = rem >> 9;
    int ii = rem & 511;
    wt[i] = pack_hl(w[(long long)o*512*KT + (long long)ii*KT + t]);
}

// ---------------- conv via f16x3 MFMA: B LDS double-buffered -----------------
template<int KT>
__global__ __launch_bounds__(256)
void conv_mfma_r24(const unsigned int* __restrict__ xphl,
                   const unsigned int* __restrict__ wthl,
                   const float* __restrict__ bias, unsigned int* __restrict__ outp)
{
    constexpr int PAD = KT / 2;
    __shared__ unsigned short Ah[136][40];
    __shared__ unsigned short Al[136][40];
    __shared__ unsigned short Bh[2][128][40];
    __shared__ unsigned short Bl[2][128][40];
    const int tid  = threadIdx.x;
    const int lane = tid & 63;
    const int wave = tid >> 6;
    const int wm = (wave >> 1) * 64, wn = (wave & 1) * 64;
    const int bm = blockIdx.x * 128, bn = blockIdx.y * 128;
    const int l15 = lane & 15;
    const int lk8 = (lane >> 4) * 8;
    const int rbase = (lane >> 4) * 4;
    const int sb = bm & 511;
    const int brow0 = tid >> 3, bc = tid & 7;

    f32x4 acc[4][4];
    #pragma unroll
    for (int i=0;i<4;i++)
        #pragma unroll
        for (int j=0;j<4;j++)
            acc[i][j] = (f32x4){0.f,0.f,0.f,0.f};

    for (int i0 = 0; i0 < 512; i0 += 32) {
        // prior i0's readers finished via loop-end barrier below
        for (int sl = tid; sl < 136*8; sl += 256) {
            const int row = sl >> 3, c = sl & 7;
            const int srow = sb + row - 4;
            uint4 v = make_uint4(0u,0u,0u,0u);
            if (srow >= 0 && srow < 512)
                v = *(const uint4*)(xphl + (long long)(bm + row - 4)*512 + i0 + c*4);
            st_hl(&Ah[row][c*4], &Al[row][c*4], v);
        }
        uint4 vb[4];
        #pragma unroll
        for (int q = 0; q < 4; ++q) {
            const int row = brow0 + q*32;
            vb[q] = *(const uint4*)(wthl + (long long)(bn + row)*(KT*512) + 0*512 + i0 + bc*4);
        }
        #pragma unroll
        for (int q = 0; q < 4; ++q) {
            const int row = brow0 + q*32;
            st_hl(&Bh[0][row][bc*4], &Bl[0][row][bc*4], vb[q]);
        }
        if (KT > 1) {
            #pragma unroll
            for (int q = 0; q < 4; ++q) {
                const int row = brow0 + q*32;
                vb[q] = *(const uint4*)(wthl + (long long)(bn + row)*(KT*512) + 1*512 + i0 + bc*4);
            }
        }
        __syncthreads();   // A + B[0] visible
        for (int t = 0; t < KT; ++t) {
            const int buf = t & 1;
            const int tofs = t - PAD + 4;
            f16x8 ah[4], al[4], bh[4], bl[4];
            #pragma unroll
            for (int mi = 0; mi < 4; ++mi) {
                ah[mi] = *(const f16x8*)(&Ah[wm + mi*16 + l15 + tofs][lk8]);
                al[mi] = *(const f16x8*)(&Al[wm + mi*16 + l15 + tofs][lk8]);
            }
            #pragma unroll
            for (int nj = 0; nj < 4; ++nj) {
                bh[nj] = *(const f16x8*)(&Bh[buf][wn + nj*16 + l15][lk8]);
                bl[nj] = *(const f16x8*)(&Bl[buf][wn + nj*16 + l15][lk8]);
            }
            #pragma unroll
            for (int mi = 0; mi < 4; ++mi)
                #pragma unroll
                for (int nj = 0; nj < 4; ++nj) {
                    acc[mi][nj] = __builtin_amdgcn_mfma_f32_16x16x32_f16(ah[mi], bh[nj], acc[mi][nj], 0, 0, 0);
                    acc[mi][nj] = __builtin_amdgcn_mfma_f32_16x16x32_f16(ah[mi], bl[nj], acc[mi][nj], 0, 0, 0);
                    acc[mi][nj] = __builtin_amdgcn_mfma_f32_16x16x32_f16(al[mi], bh[nj], acc[mi][nj], 0, 0, 0);
                }
            if (t + 1 < KT) {
                // write B(t+1) to the OTHER buffer (its old data B(t-1) was
                // fully consumed before the previous loop-end barrier)
                #pragma unroll
                for (int q = 0; q < 4; ++q) {
                    const int row = brow0 + q*32;
                    st_hl(&Bh[buf^1][row][bc*4], &Bl[buf^1][row][bc*4], vb[q]);
                }
                if (t + 2 < KT) {
                    #pragma unroll
                    for (int q = 0; q < 4; ++q) {
                        const int row = brow0 + q*32;
                        vb[q] = *(const uint4*)(wthl + (long long)(bn + row)*(KT*512) + (t+2)*512 + i0 + bc*4);
                    }
                }
            }
            __syncthreads();   // one barrier per tap
        }
    }
    #pragma unroll
    for (int mi = 0; mi < 4; ++mi) {
        #pragma unroll
        for (int nj = 0; nj < 4; ++nj) {
            const int col = bn + wn + nj*16 + l15;
            const float bcol = bias[col];
            #pragma unroll
            for (int r = 0; r < 4; ++r) {
                const int row = bm + wm + mi*16 + rbase + r;
                float v = acc[mi][nj][r] + bcol;
                outp[(long long)row*512 + col] = pack_hl(fmaxf(v, 0.0f));
            }
        }
    }
}

// ---------------- packed GEMM: A+B LDS double-buffered -----------------------
template<int FLAGS>
__global__ __launch_bounds__(256)
void gemm_hl_r24(const unsigned int* __restrict__ A, const unsigned int* __restrict__ Bm,
                 const float* __restrict__ bias, const float* __restrict__ pos,
                 const unsigned int* __restrict__ addsrc, unsigned int* __restrict__ C,
                 int Kdim, int lda, int ldb, int ldc)
{
    __shared__ unsigned short Ah[2][128][40];
    __shared__ unsigned short Al[2][128][40];
    __shared__ unsigned short Bh[2][128][40];
    __shared__ unsigned short Bl[2][128][40];
    const int tid  = threadIdx.x;
    const int lane = tid & 63;
    const int wave = tid >> 6;
    const int wm = (wave >> 1) * 64, wn = (wave & 1) * 64;
    const int bm = blockIdx.x * 128, bn = blockIdx.y * 128;
    const int l15 = lane & 15;
    const int lk8 = (lane >> 4) * 8;
    const int rbase = (lane >> 4) * 4;
    const int cg   = tid & 7;
    const int rw0  = tid >> 3;

    f32x4 acc[4][4];
    #pragma unroll
    for (int i=0;i<4;i++)
        #pragma unroll
        for (int j=0;j<4;j++)
            acc[i][j] = (f32x4){0.f,0.f,0.f,0.f};

    const int C_N = Kdim >> 5;   // chunks of 32
    uint4 va[4], vb[4];
    #pragma unroll
    for (int q = 0; q < 4; ++q) {
        const int row = rw0 + q*32;
        va[q] = *(const uint4*)(A  + (long long)(bm + row)*lda + cg*4);
        vb[q] = *(const uint4*)(Bm + (long long)(bn + row)*ldb + cg*4);
    }
    #pragma unroll
    for (int q = 0; q < 4; ++q) {
        const int row = rw0 + q*32;
        st_hl(&Ah[0][row][cg*4], &Al[0][row][cg*4], va[q]);
        st_hl(&Bh[0][row][cg*4], &Bl[0][row][cg*4], vb[q]);
    }
    if (C_N > 1) {
        #pragma unroll
        for (int q = 0; q < 4; ++q) {
            const int row = rw0 + q*32;
            va[q] = *(const uint4*)(A  + (long long)(bm + row)*lda + 32 + cg*4);
            vb[q] = *(const uint4*)(Bm + (long long)(bn + row)*ldb + 32 + cg*4);
        }
    }
    __syncthreads();

    for (int c = 0; c < C_N; ++c) {
        const int buf = c & 1;
        f16x8 ah[4], al[4], bh[4], bl[4];
        #pragma unroll
        for (int mi = 0; mi < 4; ++mi) {
            ah[mi] = *(const f16x8*)(&Ah[buf][wm + mi*16 + l15][lk8]);
            al[mi] = *(const f16x8*)(&Al[buf][wm + mi*16 + l15][lk8]);
        }
        #pragma unroll
        for (int nj = 0; nj < 4; ++nj) {
            bh[nj] = *(const f16x8*)(&Bh[buf][wn + nj*16 + l15][lk8]);
            bl[nj] = *(const f16x8*)(&Bl[buf][wn + nj*16 + l15][lk8]);
        }
        #pragma unroll
        for (int mi = 0; mi < 4; ++mi)
            #pragma unroll
            for (int nj = 0; nj < 4; ++nj) {
                acc[mi][nj] = __builtin_amdgcn_mfma_f32_16x16x32_f16(ah[mi], bh[nj], acc[mi][nj], 0, 0, 0);
                acc[mi][nj] = __builtin_amdgcn_mfma_f32_16x16x32_f16(ah[mi], bl[nj], acc[mi][nj], 0, 0, 0);
                acc[mi][nj] = __builtin_amdgcn_mfma_f32_16x16x32_f16(al[mi], bh[nj], acc[mi][nj], 0, 0, 0);
            }
        if (c + 1 < C_N) {
            #pragma unroll
            for (int q = 0; q < 4; ++q) {
                const int row = rw0 + q*32;
                st_hl(&Ah[buf^1][row][cg*4], &Al[buf^1][row][cg*4], va[q]);
                st_hl(&Bh[buf^1][row][cg*4], &Bl[buf^1][row][cg*4], vb[q]);
            }
            if (c + 2 < C_N) {
                #pragma unroll
                for (int q = 0; q < 4; ++q) {
                    const int row = rw0 + q*32;
                    va[q] = *(const uint4*)(A  + (long long)(bm + row)*lda + (c+2)*32 + cg*4);
                    vb[q] = *(const uint4*)(Bm + (long long)(bn + row)*ldb + (c+2)*32 + cg*4);
                }
            }
        }
        __syncthreads();
    }
    #pragma unroll
    for (int mi = 0; mi < 4; ++mi) {
        #pragma unroll
        for (int nj = 0; nj < 4; ++nj) {
            const int col = bn + wn + nj*16 + l15;
            #pragma unroll
            for (int r = 0; r < 4; ++r) {
                const int row = bm + wm + mi*16 + rbase + r;
                float v = acc[mi][nj][r];
                if constexpr (FLAGS & GF_BIAS) v += bias[col];
                if constexpr (FLAGS & GF_POS)  v += pos[(long long)(row & 511)*512 + col];
                if constexpr (FLAGS & GF_ADDP) v += unpack_sum(addsrc[(long long)row*ldc + col]);
                if constexpr (FLAGS & GF_ACCP) v += unpack_sum(C[(long long)row*ldc + col]);
                if constexpr (FLAGS & GF_QSCALE) v *= 0.125f;
                C[(long long)row*ldc + col] = pack_hl(v);
            }
        }
    }
}

// ---------------- fused attention (r23 verbatim) -----------------------------
__global__ __launch_bounds__(256)
void attn_mfma_r24(const unsigned int* __restrict__ Qbuf, const unsigned int* __restrict__ Kbuf,
                   const unsigned int* __restrict__ Vbuf, unsigned int* __restrict__ att)
{
    __shared__ unsigned short Qh[64][68];
    __shared__ unsigned short Ql[64][68];
    __shared__ unsigned short Kh[64][68];
    __shared__ unsigned short Kl[64][68];
    __shared__ unsigned short Vh[64][68];
    __shared__ unsigned short Vl[64][68];
    const int tid  = threadIdx.x;
    const int lane = tid & 63;
    const int wave = tid >> 6;
    const int l15  = lane & 15;
    const int lq   = lane >> 4;
    const int lq8  = lq * 8;
    const int bid = blockIdx.x;
    const int qt = bid & 7, h = (bid >> 3) & 7, b = bid >> 6;
    const int row0 = b*512 + qt*64;

    #pragma unroll
    for (int u = 0; u < 16; ++u) {
        int e = u*256 + tid;
        int r = e >> 6, c = e & 63;
        unsigned int uq = Qbuf[(long long)(row0 + r)*512 + h*64 + c];
        Qh[r][c] = (unsigned short)(uq & 0xffff);
        Ql[r][c] = (unsigned short)(uq >> 16);
    }

    float m[4], l[4];
    f32x4 accO[4];
    #pragma unroll
    for (int r=0;r<4;r++){ m[r] = -1e30f; l[r] = 0.f; }
    #pragma unroll
    for (int j=0;j<4;j++) accO[j] = (f32x4){0.f,0.f,0.f,0.f};

    for (int kv = 0; kv < 512; kv += 64) {
        __syncthreads();
        #pragma unroll
        for (int u = 0; u < 16; ++u) {
            int e = u*256 + tid;
            int r = e >> 6, c = e & 63;
            unsigned int uk = Kbuf[(long long)(b*512 + kv + r)*512 + h*64 + c];
            unsigned int uv = Vbuf[(long long)(b*512 + kv + r)*512 + h*64 + c];
            Kh[r][c] = (unsigned short)(uk & 0xffff);
            Kl[r][c] = (unsigned short)(uk >> 16);
            Vh[c][r] = (unsigned short)(uv & 0xffff);
            Vl[c][r] = (unsigned short)(uv >> 16);
        }
        __syncthreads();
        f32x4 accS[4];
        #pragma unroll
        for (int j=0;j<4;j++) accS[j] = (f32x4){0.f,0.f,0.f,0.f};
        #pragma unroll
        for (int ks = 0; ks < 2; ++ks) {
            f16x8 qh = *(const f16x8*)(&Qh[wave*16 + l15][ks*32 + lq8]);
            f16x8 ql = *(const f16x8*)(&Ql[wave*16 + l15][ks*32 + lq8]);
            #pragma unroll
            for (int nj = 0; nj < 4; ++nj) {
                f16x8 kh = *(const f16x8*)(&Kh[nj*16 + l15][ks*32 + lq8]);
                f16x8 kl = *(const f16x8*)(&Kl[nj*16 + l15][ks*32 + lq8]);
                accS[nj] = __builtin_amdgcn_mfma_f32_16x16x32_f16(qh, kh, accS[nj], 0, 0, 0);
                accS[nj] = __builtin_amdgcn_mfma_f32_16x16x32_f16(qh, kl, accS[nj], 0, 0, 0);
                accS[nj] = __builtin_amdgcn_mfma_f32_16x16x32_f16(ql, kh, accS[nj], 0, 0, 0);
            }
        }
        #pragma unroll
        for (int r = 0; r < 4; ++r) {
            float tm = fmaxf(fmaxf(accS[0][r], accS[1][r]), fmaxf(accS[2][r], accS[3][r]));
            #pragma unroll
            for (int msk = 1; msk < 16; msk <<= 1) tm = fmaxf(tm, __shfl_xor(tm, msk, 64));
            float mn = fmaxf(m[r], tm);
            float scale = expf(m[r] - mn);
            float rs = 0.f;
            #pragma unroll
            for (int nj = 0; nj < 4; ++nj) {
                float p = expf(accS[nj][r] - mn);
                accS[nj][r] = p;
                rs += p;
            }
            #pragma unroll
            for (int msk = 1; msk < 16; msk <<= 1) rs += __shfl_xor(rs, msk, 64);
            l[r] = l[r]*scale + rs;
            m[r] = mn;
            #pragma unroll
            for (int nj = 0; nj < 4; ++nj) accO[nj][r] *= scale;
        }
        __syncthreads();
        #pragma unroll
        for (int r = 0; r < 4; ++r)
            #pragma unroll
            for (int nj = 0; nj < 4; ++nj) {
                unsigned short hs, ls;
                split2(accS[nj][r], hs, ls);
                Kh[wave*16 + lq*4 + r][nj*16 + l15] = hs;
                Kl[wave*16 + lq*4 + r][nj*16 + l15] = ls;
            }
        __syncthreads();
        #pragma unroll
        for (int ks = 0; ks < 2; ++ks) {
            f16x8 ph = *(const f16x8*)(&Kh[wave*16 + l15][ks*32 + lq8]);
            f16x8 pl = *(const f16x8*)(&Kl[wave*16 + l15][ks*32 + lq8]);
            #pragma unroll
            for (int nj = 0; nj < 4; ++nj) {
                f16x8 vh = *(const f16x8*)(&Vh[nj*16 + l15][ks*32 + lq8]);
                f16x8 vl = *(const f16x8*)(&Vl[nj*16 + l15][ks*32 + lq8]);
                accO[nj] = __builtin_amdgcn_mfma_f32_16x16x32_f16(ph, vh, accO[nj], 0, 0, 0);
                accO[nj] = __builtin_amdgcn_mfma_f32_16x16x32_f16(ph, vl, accO[nj], 0, 0, 0);
                accO[nj] = __builtin_amdgcn_mfma_f32_16x16x32_f16(pl, vh, accO[nj], 0, 0, 0);
            }
        }
    }
    #pragma unroll
    for (int nj = 0; nj < 4; ++nj)
        #pragma unroll
        for (int r = 0; r < 4; ++r) {
            const int row = row0 + wave*16 + lq*4 + r;
            att[(long long)row*512 + h*64 + nj*16 + l15] = pack_hl(accO[nj][r] / l[r]);
        }
}

// ---------------- row sum of squares -----------------------------------------
__global__ __launch_bounds__(256)
void row_sumsq_r24(const float* __restrict__ X, double* __restrict__ outp)
{
    const int row  = blockIdx.x*4 + (threadIdx.x >> 6);
    const int lane = threadIdx.x & 63;
    double s = 0.0;
    #pragma unroll
    for (int u = 0; u < 8; ++u) {
        float v = X[(long long)row*512 + lane + u*64];
        s += (double)v * (double)v;
    }
    #pragma unroll
    for (int msk = 32; msk; msk >>= 1) s += __shfl_xor(s, msk, 64);
    if (lane == 0) outp[row] = s;
}

__global__ __launch_bounds__(256)
void row_sumsq_hl_r24(const unsigned int* __restrict__ X, double* __restrict__ outp)
{
    const int row  = blockIdx.x*4 + (threadIdx.x >> 6);
    const int lane = threadIdx.x & 63;
    double s = 0.0;
    #pragma unroll
    for (int u = 0; u < 8; ++u) {
        float v = unpack_sum(X[(long long)row*512 + lane + u*64]);
        s += (double)v * (double)v;
    }
    #pragma unroll
    for (int msk = 32; msk; msk >>= 1) s += __shfl_xor(s, msk, 64);
    if (lane == 0) outp[row] = s;
}

// ---------------- VQ argmin: A+B LDS double-buffered -------------------------
__global__ __launch_bounds__(256)
void vq_argmin_mfma_r24(const unsigned int* __restrict__ enchl,
                        const unsigned int* __restrict__ cbhl,
                        const double* __restrict__ Asum, const double* __restrict__ cbB,
                        float* __restrict__ pbv, int* __restrict__ pbi)
{
    __shared__ unsigned int smem[20480];   // 81920 B
    unsigned short* AhP = (unsigned short*)smem;           // [2][128][40]
    unsigned short* AlP = AhP + 2*128*40;
    unsigned short* BhP = AlP + 2*128*40;
    unsigned short* BlP = BhP + 2*128*40;
    float* bvsP = (float*)smem;                            // reduce overlay
    int*   bisP = (int*)(smem + 4096);

    const int tid  = threadIdx.x;
    const int lane = tid & 63;
    const int wave = tid >> 6;
    const int wm = (wave >> 1) * 64, wn = (wave & 1) * 64;
    const int bm = blockIdx.x * 128;
    const int l15 = lane & 15;
    const int lk8 = (lane >> 4) * 8;
    const int rbase = (lane >> 4) * 4;
    const int cg   = tid & 7;
    const int rw0  = tid >> 3;

    float bestv[16]; int besti[16];
    #pragma unroll
    for (int g = 0; g < 16; ++g) { bestv[g] = 3.0e38f; besti[g] = 2048; }

    for (int nb = 0; nb < 4; ++nb) {
        const int ct0 = blockIdx.y * 512 + nb * 128;
        f32x4 acc[4][4];
        #pragma unroll
        for (int i=0;i<4;i++)
            #pragma unroll
            for (int j=0;j<4;j++)
                acc[i][j] = (f32x4){0.f,0.f,0.f,0.f};

        uint4 va[4], vb[4];
        #pragma unroll
        for (int q = 0; q < 4; ++q) {
            const int row = rw0 + q*32;
            va[q] = *(const uint4*)(enchl + (long long)(bm + row)*512 + cg*4);
            vb[q] = *(const uint4*)(cbhl  + (long long)(ct0 + row)*512 + cg*4);
        }
        __syncthreads();   // prior nb readers done (and reduce overlay later)
        #pragma unroll
        for (int q = 0; q < 4; ++q) {
            const int row = rw0 + q*32;
            st_hl(&AhP[(0*128 + row)*40 + cg*4], &AlP[(0*128 + row)*40 + cg*4], va[q]);
            st_hl(&BhP[(0*128 + row)*40 + cg*4], &BlP[(0*128 + row)*40 + cg*4], vb[q]);
        }
        #pragma unroll
        for (int q = 0; q < 4; ++q) {
            const int row = rw0 + q*32;
            va[q] = *(const uint4*)(enchl + (long long)(bm + row)*512 + 32 + cg*4);
            vb[q] = *(const uint4*)(cbhl  + (long long)(ct0 + row)*512 + 32 + cg*4);
        }
        __syncthreads();

        for (int c = 0; c < 16; ++c) {
            const int buf = c & 1;
            f16x8 ah[4], al[4], bh[4], bl[4];
            #pragma unroll
            for (int mi = 0; mi < 4; ++mi) {
                ah[mi] = *(const f16x8*)(&AhP[(buf*128 + wm + mi*16 + l15)*40 + lk8]);
                al[mi] = *(const f16x8*)(&AlP[(buf*128 + wm + mi*16 + l15)*40 + lk8]);
            }
            #pragma unroll
            for (int nj = 0; nj < 4; ++nj) {
                bh[nj] = *(const f16x8*)(&BhP[(buf*128 + wn + nj*16 + l15)*40 + lk8]);
                bl[nj] = *(const f16x8*)(&BlP[(buf*128 + wn + nj*16 + l15)*40 + lk8]);
            }
            #pragma unroll
            for (int mi = 0; mi < 4; ++mi)
                #pragma unroll
                for (int nj = 0; nj < 4; ++nj) {
                    acc[mi][nj] = __builtin_amdgcn_mfma_f32_16x16x32_f16(ah[mi], bh[nj], acc[mi][nj], 0, 0, 0);
                    acc[mi][nj] = __builtin_amdgcn_mfma_f32_16x16x32_f16(ah[mi], bl[nj], acc[mi][nj], 0, 0, 0);
                    acc[mi][nj] = __builtin_amdgcn_mfma_f32_16x16x32_f16(al[mi], bh[nj], acc[mi][nj], 0, 0, 0);
                }
            if (c + 1 < 16) {
                #pragma unroll
                for (int q = 0; q < 4; ++q) {
                    const int row = rw0 + q*32;
                    st_hl(&AhP[((buf^1)*128 + row)*40 + cg*4], &AlP[((buf^1)*128 + row)*40 + cg*4], va[q]);
                    st_hl(&BhP[((buf^1)*128 + row)*40 + cg*4], &BlP[((buf^1)*128 + row)*40 + cg*4], vb[q]);
                }
                if (c + 2 < 16) {
                    #pragma unroll
                    for (int q = 0; q < 4; ++q) {
                        const int row = rw0 + q*32;
                        va[q] = *(const uint4*)(enchl + (long long)(bm + row)*512 + (c+2)*32 + cg*4);
                        vb[q] = *(const uint4*)(cbhl  + (long long)(ct0 + row)*512 + (c+2)*32 + cg*4);
                    }
                }
            }
            __syncthreads();
        }
        #pragma unroll
        for (int mi = 0; mi < 4; ++mi) {
            #pragma unroll
            for (int r = 0; r < 4; ++r) {
                const int g = mi*4 + r;
                const float anf = (float)Asum[bm + wm + mi*16 + rbase + r];
                #pragma unroll
                for (int nj = 0; nj < 4; ++nj) {
                    const int col = ct0 + wn + nj*16 + l15;
                    const float bf = (float)cbB[col];
                    const float s1 = anf + bf;
                    const float dot = acc[mi][nj][r] * (1.0f/2048.0f);
                    const float df  = 2.0f * dot;
                    const float qd  = s1 - df;
                    if (qd < bestv[g] || (qd == bestv[g] && col < besti[g])) {
                        bestv[g] = qd; besti[g] = col;
                    }
                }
            }
        }
    }
    __syncthreads();
    #pragma unroll
    for (int mi = 0; mi < 4; ++mi)
        #pragma unroll
        for (int r = 0; r < 4; ++r) {
            const int row  = wm + mi*16 + rbase + r;
            const int slot = (wave & 1)*16 + l15;
            bvsP[row*32 + slot] = bestv[mi*4 + r];
            bisP[row*32 + slot] = besti[mi*4 + r];
        }
    __syncthreads();
    if (tid < 128) {
        float bv = bvsP[tid*32]; int bi = bisP[tid*32];
        #pragma unroll
        for (int s = 1; s < 32; ++s) {
            float v = bvsP[tid*32 + s]; int ii = bisP[tid*32 + s];
            if (v < bv || (v == bv && ii < bi)) { bv = v; bi = ii; }
        }
        pbv[(long long)blockIdx.y*16384 + bm + tid] = bv;
        pbi[(long long)blockIdx.y*16384 + bm + tid] = bi;
    }
}

__global__ __launch_bounds__(256)
void vq_reduce_r24(const float* __restrict__ pbv, const int* __restrict__ pbi,
                   int* __restrict__ idxout, float* __restrict__ out)
{
    int n = blockIdx.x*256 + threadIdx.x;
    if (n >= 16384) return;
    float bv = pbv[n]; int bi = pbi[n];
    #pragma unroll
    for (int q = 1; q < 4; ++q) {
        float v = pbv[q*16384 + n]; int ii = pbi[q*16384 + n];
        if (v < bv || (v == bv && ii < bi)) { bv = v; bi = ii; }
    }
    int ci = bi & 2047;
    idxout[n] = ci;
    out[O_IDX + n] = (float)ci;
}

// ---------------- vq loss (packed enc) ---------------------------------------
__global__ __launch_bounds__(256)
void vq_loss_partial_r24(const unsigned int* __restrict__ enchl,
                         const float* __restrict__ cb,
                         const int* __restrict__ idxp, double* __restrict__ part)
{
    __shared__ double red[4];
    const int row  = blockIdx.x*4 + (threadIdx.x >> 6);
    const int lane = threadIdx.x & 63;
    const int ci = idxp[row] & 2047;
    double s = 0.0;
    #pragma unroll
    for (int u = 0; u < 8; ++u) {
        int d = lane + u*64;
        float e = unpack_sum(enchl[(long long)row*512 + d]);
        double dv = (double)cb[(long long)ci*512 + d] - (double)e;
        s += dv * dv;
    }
    #pragma unroll
    for (int msk = 32; msk; msk >>= 1) s += __shfl_xor(s, msk, 64);
    if (lane == 0) red[threadIdx.x >> 6] = s;
    __syncthreads();
    if (threadIdx.x == 0)
        part[blockIdx.x] = red[0] + red[1] + red[2] + red[3];
}

// ---------------- regime f32 GEMM (small, r23 verbatim) ----------------------
template<int FLAGS>
__global__ __launch_bounds__(256)
void gemm_bt_r24(const float* __restrict__ A, const float* __restrict__ Bm,
                 const float* __restrict__ bias, const float* __restrict__ pos,
                 const float* __restrict__ addsrc, float* __restrict__ C,
                 int Kdim, int lda, int ldb, int ldc)
{
    __shared__ float As[16][132];
    __shared__ float Bs[16][132];
    const int tid = threadIdx.x;
    const int tx = tid & 15, ty = tid >> 4;
    const int bm = blockIdx.x * 128, bn = blockIdx.y * 128;
    const int r0 = tid >> 2;
    const int kg = (tid & 3) << 2;
    const float* Arow0 = A  + (long long)(bm + r0) * lda + kg;
    const float* Arow1 = A  + (long long)(bm + r0 + 64) * lda + kg;
    const float* Brow0 = Bm + (long long)(bn + r0) * ldb + kg;
    const float* Brow1 = Bm + (long long)(bn + r0 + 64) * ldb + kg;

    float acc[8][8] = {};
    for (int k0 = 0; k0 < Kdim; k0 += 16) {
        float4 a0 = *(const float4*)(Arow0 + k0);
        float4 a1 = *(const float4*)(Arow1 + k0);
        float4 b0 = *(const float4*)(Brow0 + k0);
        float4 b1 = *(const float4*)(Brow1 + k0);
        __syncthreads();
        As[kg+0][r0]=a0.x; As[kg+1][r0]=a0.y; As[kg+2][r0]=a0.z; As[kg+3][r0]=a0.w;
        As[kg+0][r0+64]=a1.x; As[kg+1][r0+64]=a1.y; As[kg+2][r0+64]=a1.z; As[kg+3][r0+64]=a1.w;
        Bs[kg+0][r0]=b0.x; Bs[kg+1][r0]=b0.y; Bs[kg+2][r0]=b0.z; Bs[kg+3][r0]=b0.w;
        Bs[kg+0][r0+64]=b1.x; Bs[kg+1][r0+64]=b1.y; Bs[kg+2][r0+64]=b1.z; Bs[kg+3][r0+64]=b1.w;
        __syncthreads();
        #pragma unroll
        for (int kk = 0; kk < 16; ++kk) {
            float a[8], b[8];
            #pragma unroll
            for (int i=0;i<8;i++) a[i] = As[kk][ty*8+i];
            #pragma unroll
            for (int j=0;j<4;j++) b[j]   = Bs[kk][tx*4+j];
            #pragma unroll
            for (int j=0;j<4;j++) b[4+j] = Bs[kk][64+tx*4+j];
            #pragma unroll
            for (int i=0;i<8;i++)
                #pragma unroll
                for (int j=0;j<8;j++)
                    acc[i][j] = fmaf(a[i], b[j], acc[i][j]);
        }
    }
    #pragma unroll
    for (int i=0;i<8;i++){
        const int row = bm + ty*8 + i;
        #pragma unroll
        for (int j=0;j<8;j++){
            const int col = bn + ((j < 4) ? (tx*4 + j) : (64 + tx*4 + (j-4)));
            float v = acc[i][j];
            if constexpr (FLAGS & GF_BIAS) v += bias[col];
            if constexpr (FLAGS & GF_RELU) v = fmaxf(v, 0.0f);
            C[(long long)row*ldc + col] = v;
        }
    }
}

// ---------------- regime softmax ---------------------------------------------
__global__ __launch_bounds__(256)
void softmax_rows_r24(float* __restrict__ R)
{
    const int row = blockIdx.x;
    const int tid = threadIdx.x;
    __shared__ float  redf[256];
    __shared__ double redd[256];
    float* p = R + (long long)row * 2048;
    float mx = -1e30f;
    for (int c = tid; c < 2048; c += 256) mx = fmaxf(mx, p[c]);
    redf[tid] = mx; __syncthreads();
    for (int s2 = 128; s2; s2 >>= 1) { if (tid < s2) redf[tid] = fmaxf(redf[tid], redf[tid+s2]); __syncthreads(); }
    mx = redf[0];
    double sum = 0.0;
    for (int c = tid; c < 2048; c += 256) { float e = expf(p[c] - mx); p[c] = e; sum += e; }
    redd[tid] = sum; __syncthreads();
    for (int s2 = 128; s2; s2 >>= 1) { if (tid < s2) redd[tid] += redd[tid+s2]; __syncthreads(); }
    double tot = redd[0];
    for (int c = tid; c < 2048; c += 256) p[c] = (float)((double)p[c] / tot);
}

// ---------------- hash table -------------------------------------------------
__global__ __launch_bounds__(256)
void hash_table_r24(const float* __restrict__ cb, const float* __restrict__ hw,
                    float* __restrict__ T)
{
    const int k = blockIdx.x*4 + (threadIdx.x >> 6);
    const int j = threadIdx.x & 63;
    double s = 0.0;
    for (int d = 0; d < 512; ++d)
        s += (double)cb[(long long)k*512 + d] * (double)hw[(long long)j*512 + d];
    T[(long long)k*64 + j] = (s > 0.0) ? 1.0f : 0.0f;
}

// ---------------- output writers ---------------------------------------------
__global__ void write_loss_r24(const double* __restrict__ part,
                               float* __restrict__ out)
{
    __shared__ double red[256];
    double s = 0.0;
    for (int i = threadIdx.x; i < 4096; i += 256) s += part[i];
    red[threadIdx.x] = s; __syncthreads();
    for (int s2 = 128; s2; s2 >>= 1) {
        if (threadIdx.x < s2) red[threadIdx.x] += red[threadIdx.x + s2];
        __syncthreads();
    }
    if (threadIdx.x == 0)
        out[O_LOSS] = (float)(1.25 * red[0] / 8388608.0);
}

__global__ __launch_bounds__(256)
void write_regime_r24(const float* __restrict__ R, const int* __restrict__ idxp,
                      float* __restrict__ out)
{
    long long i = (long long)blockIdx.x*256 + threadIdx.x;
    if (i >= 33554432LL) return;
    int n = (int)(i >> 11), c = (int)(i & 2047);
    int ci = idxp[n] & 2047;
    out[O_REG + i] = R[(long long)ci*2048 + c];
}

__global__ __launch_bounds__(256)
void write_hash_r24(const float* __restrict__ T, const int* __restrict__ idxp,
                    float* __restrict__ out)
{
    long long i = (long long)blockIdx.x*256 + threadIdx.x;
    if (i >= 1048576LL) return;
    int n = (int)(i >> 6), j = (int)(i & 63);
    int ci = idxp[n] & 2047;
    out[O_HASH + i] = T[(long long)ci*64 + j];
}

__global__ __launch_bounds__(256)
void write_quant_r24(const float* __restrict__ cb, const int* __restrict__ idxp,
                     float* __restrict__ out)
{
    long long i = (long long)blockIdx.x*256 + threadIdx.x;
    if (i >= 8388608LL) return;
    int n = (int)(i >> 9), d = (int)(i & 511);
    int ci = idxp[n] & 2047;
    out[O_QUANT + i] = cb[(long long)ci*512 + d];
}

// ---------------- launcher ----------------------------------------------------
extern "C" void kernel_launch(void* const* d_in, const int* in_sizes, int n_in,
                              void* d_out, int out_size, void* d_ws, size_t ws_size,
                              hipStream_t stream)
{
    (void)in_sizes; (void)n_in; (void)out_size;
    const float* market = (const float*)d_in[0];
    const float* W_in   = (const float*)d_in[1];
    const float* b_in   = (const float*)d_in[2];
    const float* pos    = (const float*)d_in[3];
    const float* c3w = (const float*)d_in[4];  const float* c3b = (const float*)d_in[5];
    const float* c5w = (const float*)d_in[6];  const float* c5b = (const float*)d_in[7];
    const float* c7w = (const float*)d_in[8];  const float* c7b = (const float*)d_in[9];
    const float* c9w = (const float*)d_in[10]; const float* c9b = (const float*)d_in[11];
    const float* msw = (const float*)d_in[12]; const float* msb = (const float*)d_in[13];
    const float* inw = (const float*)d_in[14]; const float* inb = (const float*)d_in[15];
    const float* aow = (const float*)d_in[16]; const float* aob = (const float*)d_in[17];
    const float* cb  = (const float*)d_in[18]; const float* hw  = (const float*)d_in[19];
    const float* r1w = (const float*)d_in[20]; const float* r1b = (const float*)d_in[21];
    const float* r2w = (const float*)d_in[22]; const float* r2b = (const float*)d_in[23];

    if (ws_size < (size_t)W_END * sizeof(float)) return;

    float* ws = (float*)d_ws;
    unsigned int* xphl   = (unsigned int*)(ws + W_XP);
    unsigned int* cthl   = (unsigned int*)(ws + W_CT);
    unsigned int* projhl = (unsigned int*)(ws + W_PROJ);
    unsigned int* vwbase = (unsigned int*)(ws + W_VW);
    unsigned int* wt3 = vwbase;
    unsigned int* wt5 = wt3 + 512*512*3;
    unsigned int* wt7 = wt5 + 512*512*5;
    unsigned int* wt9 = wt7 + 512*512*7;
    unsigned int* mswhl  = vwbase + 6291456;
    unsigned int* winhl  = mswhl + 1048576;
    unsigned int* inwqhl = winhl + 262144;
    unsigned int* inwkhl = inwqhl + 262144;
    unsigned int* vhl    = vwbase;
    unsigned int* inwvhl = (unsigned int*)(ws + W_HREG);
    unsigned int* aowhl  = inwvhl + 262144;
    float* hregp = ws + W_HREG;
    float* Tp    = ws + W_T;
    int*    idxp  = (int*)(ws + W_IDX);
    double* asump = (double*)(ws + W_ASUM);
    double* cbbp  = (double*)(ws + W_CBB);
    double* lpart = (double*)(ws + W_LPART);
    float*  pbvp  = ws + W_PBV;
    int*    pbip  = (int*)(ws + W_PBI);
    unsigned int* cbhl = (unsigned int*)(ws + W_PROJ + 4194304);
    float* Rp = ws + W_PROJ;

    float* out = (float*)d_out;

    conv_w_tr_r24<3><<<3072, 256, 0, stream>>>(c3w, wt3);
    conv_w_tr_r24<5><<<5120, 256, 0, stream>>>(c5w, wt5);
    conv_w_tr_r24<7><<<7168, 256, 0, stream>>>(c7w, wt7);
    conv_w_tr_r24<9><<<9216, 256, 0, stream>>>(c9w, wt9);
    split_hl_r24<<<32768, 256, 0, stream>>>(market, cthl);
    split_hl_r24<<<1024,  256, 0, stream>>>(W_in, winhl);
    split_hl_r24<<<4096,  256, 0, stream>>>(msw, mswhl);
    split_hl_r24<<<1024,  256, 0, stream>>>(inw,            inwqhl);
    split_hl_r24<<<1024,  256, 0, stream>>>(inw + 262144,   inwkhl);
    split_hl_r24<<<1024,  256, 0, stream>>>(inw + 524288,   inwvhl);
    split_hl_r24<<<1024,  256, 0, stream>>>(aow, aowhl);

    const dim3 gT(128, 4);

    gemm_hl_r24<GF_BIAS|GF_POS><<<gT, 256, 0, stream>>>(cthl, winhl, b_in, pos, nullptr, xphl, 512, 512, 512, 512);

    conv_mfma_r24<3><<<gT, 256, 0, stream>>>(xphl, wt3, c3b, cthl);
    gemm_hl_r24<GF_BIAS><<<gT, 256, 0, stream>>>(cthl, mswhl + 0*512, msb, nullptr, nullptr, projhl, 512, 512, 2048, 512);
    conv_mfma_r24<5><<<gT, 256, 0, stream>>>(xphl, wt5, c5b, cthl);
    gemm_hl_r24<GF_ACCP><<<gT, 256, 0, stream>>>(cthl, mswhl + 1*512, nullptr, nullptr, nullptr, projhl, 512, 512, 2048, 512);
    conv_mfma_r24<7><<<gT, 256, 0, stream>>>(xphl, wt7, c7b, cthl);
    gemm_hl_r24<GF_ACCP><<<gT, 256, 0, stream>>>(cthl, mswhl + 2*512, nullptr, nullptr, nullptr, projhl, 512, 512, 2048, 512);
    conv_mfma_r24<9><<<gT, 256, 0, stream>>>(xphl, wt9, c9b, cthl);
    gemm_hl_r24<GF_ACCP><<<gT, 256, 0, stream>>>(cthl, mswhl + 3*512, nullptr, nullptr, nullptr, projhl, 512, 512, 2048, 512);

    gemm_hl_r24<GF_BIAS><<<gT, 256, 0, stream>>>(projhl, inwkhl, inb + 512,  nullptr, nullptr, cthl, 512, 512, 512, 512);
    gemm_hl_r24<GF_BIAS|GF_QSCALE><<<gT, 256, 0, stream>>>(projhl, inwqhl, inb, nullptr, nullptr, xphl, 512, 512, 512, 512);
    gemm_hl_r24<GF_BIAS><<<gT, 256, 0, stream>>>(projhl, inwvhl, inb + 1024, nullptr, nullptr, vhl, 512, 512, 512, 512);

    attn_mfma_r24<<<2048, 256, 0, stream>>>(xphl, cthl, vhl, xphl);

    gemm_hl_r24<GF_BIAS|GF_ADDP><<<gT, 256, 0, stream>>>(xphl, aowhl, aob, nullptr, projhl, cthl, 512, 512, 512, 512);

    // VQ
    row_sumsq_hl_r24<<<4096, 256, 0, stream>>>(cthl, asump);
    row_sumsq_r24<<<512,  256, 0, stream>>>(cb, cbbp);
    split_cb_r24<<<4096, 256, 0, stream>>>(cb, cbhl);
    vq_argmin_mfma_r24<<<dim3(128, 4), 256, 0, stream>>>(cthl, cbhl, asump, cbbp, pbvp, pbip);
    vq_reduce_r24<<<64, 256, 0, stream>>>(pbvp, pbip, idxp, out);
    vq_loss_partial_r24<<<4096, 256, 0, stream>>>(cthl, cb, idxp, lpart);

    // regime tables
    gemm_bt_r24<GF_BIAS|GF_RELU><<<dim3(16, 2),  256, 0, stream>>>(cb, r1w, r1b, nullptr, nullptr, hregp, 512, 512, 512, 256);
    gemm_bt_r24<GF_BIAS><<<dim3(16, 16), 256, 0, stream>>>(hregp, r2w, r2b, nullptr, nullptr, Rp, 256, 256, 256, 2048);
    softmax_rows_r24<<<2048, 256, 0, stream>>>(Rp);
    hash_table_r24<<<512, 256, 0, stream>>>(cb, hw, Tp);

    // outputs
    write_loss_r24<<<1, 256, 0, stream>>>(lpart, out);
    write_regime_r24<<<131072, 256, 0, stream>>>(Rp, idxp, out);
    write_hash_r24<<<4096, 256, 0, stream>>>(Tp, idxp, out);
    write_quant_r24<<<32768, 256, 0, stream>>>(cb, idxp, out);
}